// Round 1
// baseline (708.145 us; speedup 1.0000x reference)
//
#include <hip/hip_runtime.h>
#include <cstddef>
#include <cstdint>

// MambaDoc fused-chunked SSD implementation (fp32, correctness-first round).
// B=4, L=4096, DI=128, H=2, P=128, N=128, CONV=4, DPROJ=770, DIN=256.
// Chunked scan: Q=128, NC=32 chunks per sequence.

#define LSEQ 4096
#define MTOK 16384   // B*L

__device__ __forceinline__ float silu_f(float x) {
    return x / (1.f + __expf(-x));
}

// ---------------------------------------------------------------------------
// Generic fp32 GEMM: out[m,n] (+)= sum_k A[m,k] * W[n,k] (+ bias[n])
// A: (M,K) row-major, W: (Nout,K) row-major. Grid: (ceil(Nout/64), M/64).
// ---------------------------------------------------------------------------
__global__ __launch_bounds__(256) void gemm_nt_kernel(
    const float* __restrict__ A, const float* __restrict__ W,
    float* __restrict__ out, int M, int Nout, int K,
    const float* __restrict__ bias, int accumulate)
{
    __shared__ float sA[64][68];   // +4 pad: conflict-free, keeps float4 align
    __shared__ float sW[64][68];
    const int n0 = blockIdx.x * 64;
    const int m0 = blockIdx.y * 64;
    const int tid = threadIdx.x;
    const int ty = tid >> 4, tx = tid & 15;
    float acc[4][4] = {{0.f, 0.f, 0.f, 0.f}, {0.f, 0.f, 0.f, 0.f},
                       {0.f, 0.f, 0.f, 0.f}, {0.f, 0.f, 0.f, 0.f}};
    for (int k0 = 0; k0 < K; k0 += 64) {
        for (int off = tid * 4; off < 4096; off += 1024) {
            int r = off >> 6, c = off & 63;
            *(float4*)&sA[r][c] = *(const float4*)&A[(size_t)(m0 + r) * K + k0 + c];
        }
        for (int off = tid * 4; off < 4096; off += 1024) {
            int r = off >> 6, c = off & 63;
            int e = n0 + r;
            float4 v = make_float4(0.f, 0.f, 0.f, 0.f);
            if (e < Nout) v = *(const float4*)&W[(size_t)e * K + k0 + c];
            *(float4*)&sW[r][c] = v;
        }
        __syncthreads();
        #pragma unroll
        for (int k = 0; k < 64; k += 4) {
            float4 av[4], bv[4];
            #pragma unroll
            for (int i = 0; i < 4; i++) av[i] = *(const float4*)&sA[ty + 16 * i][k];
            #pragma unroll
            for (int j = 0; j < 4; j++) bv[j] = *(const float4*)&sW[tx + 16 * j][k];
            #pragma unroll
            for (int i = 0; i < 4; i++) {
                #pragma unroll
                for (int j = 0; j < 4; j++) {
                    acc[i][j] += av[i].x * bv[j].x + av[i].y * bv[j].y
                               + av[i].z * bv[j].z + av[i].w * bv[j].w;
                }
            }
        }
        __syncthreads();
    }
    #pragma unroll
    for (int i = 0; i < 4; i++) {
        int m = m0 + ty + 16 * i;
        #pragma unroll
        for (int j = 0; j < 4; j++) {
            int n = n0 + tx + 16 * j;
            if (n < Nout) {
                size_t o = (size_t)m * Nout + n;
                float v = acc[i][j];
                if (bias) v += bias[n];
                if (accumulate) v += out[o];
                out[o] = v;
            }
        }
    }
}

// ---------------------------------------------------------------------------
// RMSNorm over 128 channels: out = in * rsqrt(mean(in^2)+eps) * w
// ---------------------------------------------------------------------------
__global__ __launch_bounds__(128) void rmsnorm128_kernel(
    const float* __restrict__ in, const float* __restrict__ w,
    float* __restrict__ out)
{
    const int tok = blockIdx.x, d = threadIdx.x;
    float v = in[(size_t)tok * 128 + d];
    float ss = v * v;
    #pragma unroll
    for (int o = 1; o < 64; o <<= 1) ss += __shfl_xor(ss, o);
    __shared__ float sred[2];
    if ((d & 63) == 0) sred[d >> 6] = ss;
    __syncthreads();
    float total = sred[0] + sred[1];
    float rstd = rsqrtf(total * (1.f / 128.f) + 1e-5f);
    out[(size_t)tok * 128 + d] = v * rstd * w[d];
}

// Final norm + outer residual: out = xp + in*rstd*w
__global__ __launch_bounds__(128) void final_norm_kernel(
    const float* __restrict__ in, const float* __restrict__ xp,
    const float* __restrict__ w, float* __restrict__ out)
{
    const int tok = blockIdx.x, d = threadIdx.x;
    float v = in[(size_t)tok * 128 + d];
    float ss = v * v;
    #pragma unroll
    for (int o = 1; o < 64; o <<= 1) ss += __shfl_xor(ss, o);
    __shared__ float sred[2];
    if ((d & 63) == 0) sred[d >> 6] = ss;
    __syncthreads();
    float total = sred[0] + sred[1];
    float rstd = rsqrtf(total * (1.f / 128.f) + 1e-5f);
    out[(size_t)tok * 128 + d] = xp[(size_t)tok * 128 + d] + v * rstd * w[d];
}

// ---------------------------------------------------------------------------
// Causal depthwise conv (4 taps) + silu over the 512 xBC channels.
// Grid: MTOK*2 blocks, 256 threads; each thread one (token, channel).
// ---------------------------------------------------------------------------
__global__ __launch_bounds__(256) void conv_silu_kernel(
    const float* __restrict__ zx, const float* __restrict__ cw,
    const float* __restrict__ cb, float* __restrict__ xc)
{
    const int token = blockIdx.x >> 1;
    const int ch = ((blockIdx.x & 1) << 8) + threadIdx.x;
    const int l = token & (LSEQ - 1);
    float acc = cb[ch];
    #pragma unroll
    for (int k = 0; k < 4; k++) {
        int lk = l + k - 3;
        if (lk >= 0)
            acc += zx[(size_t)(token + k - 3) * 770 + 256 + ch] * cw[ch * 4 + k];
    }
    xc[(size_t)token * 512 + ch] = silu_f(acc);
}

// ---------------------------------------------------------------------------
// dt = softplus(dt_raw + dt_bias); chunk-local inclusive cumsum of A*dt -> S.
// Grid: (NC=32, H=2, B=4), 128 threads (one per token of the chunk).
// ---------------------------------------------------------------------------
__global__ __launch_bounds__(128) void dt_scan_kernel(
    const float* __restrict__ zx, const float* __restrict__ dt_bias,
    const float* __restrict__ A_log, float* __restrict__ dtb,
    float* __restrict__ Sb)
{
    const int c = blockIdx.x, h = blockIdx.y, b = blockIdx.z;
    const int t = threadIdx.x;
    const int tok = b * LSEQ + c * 128 + t;
    float raw = zx[(size_t)tok * 770 + 768 + h] + dt_bias[h];
    float dt = fmaxf(raw, 0.f) + log1pf(__expf(-fabsf(raw)));
    dtb[(size_t)tok * 2 + h] = dt;
    float a = -__expf(A_log[h]);
    __shared__ float s[128];
    s[t] = a * dt;
    __syncthreads();
    for (int off = 1; off < 128; off <<= 1) {
        float add = (t >= off) ? s[t - off] : 0.f;
        __syncthreads();
        s[t] += add;
        __syncthreads();
    }
    Sb[(size_t)tok * 2 + h] = s[t];
}

// ---------------------------------------------------------------------------
// Chunk-local end state: Hloc[p,n] = sum_s exp(S_last - S_s)*dt_s*X[s,p]*B[s,n]
// Grid: (NC, H, B), 256 threads, each an 8x8 (p,n) tile.
// ---------------------------------------------------------------------------
__global__ __launch_bounds__(256) void ssd_chunkstate_kernel(
    const float* __restrict__ xc, const float* __restrict__ dtb,
    const float* __restrict__ Sb, float* __restrict__ Hloc)
{
    const int c = blockIdx.x, h = blockIdx.y, b = blockIdx.z;
    const int tid = threadIdx.x;
    __shared__ float sX[128][132];
    __shared__ float sBm[128][132];
    __shared__ float sw[128];
    const int tok0 = b * LSEQ + c * 128;
    if (tid < 128) {
        float Slast = Sb[(size_t)(tok0 + 127) * 2 + h];
        float Ss = Sb[(size_t)(tok0 + tid) * 2 + h];
        sw[tid] = __expf(Slast - Ss) * dtb[(size_t)(tok0 + tid) * 2 + h];
    }
    __syncthreads();
    for (int off = tid * 4; off < 16384; off += 1024) {
        int r = off >> 7, col = off & 127;
        float w = sw[r];
        float4 v = *(const float4*)&xc[(size_t)(tok0 + r) * 512 + h * 128 + col];
        v.x *= w; v.y *= w; v.z *= w; v.w *= w;
        *(float4*)&sX[r][col] = v;
        *(float4*)&sBm[r][col] = *(const float4*)&xc[(size_t)(tok0 + r) * 512 + 256 + col];
    }
    __syncthreads();
    const int ty = tid >> 4, tx = tid & 15;
    const int pp0 = ty * 8, n0 = tx * 8;
    float acc[8][8];
    #pragma unroll
    for (int i = 0; i < 8; i++) {
        #pragma unroll
        for (int j = 0; j < 8; j++) acc[i][j] = 0.f;
    }
    for (int s = 0; s < 128; s++) {
        float4 xa = *(const float4*)&sX[s][pp0];
        float4 xb = *(const float4*)&sX[s][pp0 + 4];
        float4 ba = *(const float4*)&sBm[s][n0];
        float4 bb = *(const float4*)&sBm[s][n0 + 4];
        float xr[8] = {xa.x, xa.y, xa.z, xa.w, xb.x, xb.y, xb.z, xb.w};
        float br[8] = {ba.x, ba.y, ba.z, ba.w, bb.x, bb.y, bb.z, bb.w};
        #pragma unroll
        for (int i = 0; i < 8; i++) {
            #pragma unroll
            for (int j = 0; j < 8; j++) acc[i][j] += xr[i] * br[j];
        }
    }
    float* Hb = Hloc + (((size_t)((b * 2 + h) * 32 + c)) << 14);
    #pragma unroll
    for (int i = 0; i < 8; i++) {
        *(float4*)&Hb[(size_t)(pp0 + i) * 128 + n0] =
            make_float4(acc[i][0], acc[i][1], acc[i][2], acc[i][3]);
        *(float4*)&Hb[(size_t)(pp0 + i) * 128 + n0 + 4] =
            make_float4(acc[i][4], acc[i][5], acc[i][6], acc[i][7]);
    }
}

// ---------------------------------------------------------------------------
// Inter-chunk combine: in-place turn per-chunk local states into INCOMING
// states. Parallel over state elements; serial only over 32 chunk scalars.
// Grid: (64, H, B), 256 threads, one element each.
// ---------------------------------------------------------------------------
__global__ __launch_bounds__(256) void ssd_statecombine_kernel(
    const float* __restrict__ Sb, float* __restrict__ Hbuf)
{
    const int e = blockIdx.x * 256 + threadIdx.x;
    const int h = blockIdx.y, b = blockIdx.z;
    const size_t base = ((size_t)((b * 2 + h) * 32)) << 14;
    float state = 0.f;
    for (int c = 0; c < 32; c++) {
        size_t idx = base + ((size_t)c << 14) + e;
        float v = Hbuf[idx];
        Hbuf[idx] = state;  // incoming state for chunk c
        float dec = __expf(Sb[(size_t)(b * LSEQ + c * 128 + 127) * 2 + h]);
        state = dec * state + v;
    }
}

// ---------------------------------------------------------------------------
// Per-chunk output: y = exp(S_t)*C_t·H_in + (mask ∘ C·B^T)·X + D*X
// Grid: (NC, H, B), 256 threads. LDS: two 128x132 buffers, triple-reused.
// ---------------------------------------------------------------------------
__global__ __launch_bounds__(256) void ssd_output_kernel(
    const float* __restrict__ xc, const float* __restrict__ dtb,
    const float* __restrict__ Sb, const float* __restrict__ Hst,
    const float* __restrict__ Dp, float* __restrict__ y)
{
    const int c = blockIdx.x, h = blockIdx.y, b = blockIdx.z;
    const int tid = threadIdx.x;
    __shared__ float sC[128][132];   // C, later masked G
    __shared__ float sB[128][132];   // Hin, then B, then X
    __shared__ float sS[128];
    __shared__ float sdt[128];
    const int tok0 = b * LSEQ + c * 128;
    for (int off = tid * 4; off < 16384; off += 1024) {
        int r = off >> 7, col = off & 127;
        *(float4*)&sC[r][col] = *(const float4*)&xc[(size_t)(tok0 + r) * 512 + 384 + col];
    }
    const float* Hbase = Hst + (((size_t)((b * 2 + h) * 32 + c)) << 14);
    for (int off = tid * 4; off < 16384; off += 1024) {
        int r = off >> 7, col = off & 127;
        *(float4*)&sB[r][col] = *(const float4*)&Hbase[off];
    }
    if (tid < 128) {
        sS[tid] = Sb[(size_t)(tok0 + tid) * 2 + h];
        sdt[tid] = dtb[(size_t)(tok0 + tid) * 2 + h];
    }
    __syncthreads();
    const int ty = tid >> 4, tx = tid & 15;
    const int t0 = ty * 8, p0 = tx * 8;
    float acc[8][8];
    #pragma unroll
    for (int i = 0; i < 8; i++) {
        #pragma unroll
        for (int j = 0; j < 8; j++) acc[i][j] = 0.f;
    }
    // ---- state term: acc[t,p] = sum_n C[t,n]*Hin[p,n], scaled by exp(S_t)
    for (int n = 0; n < 128; n += 4) {
        float4 cv[8], hv[8];
        #pragma unroll
        for (int i = 0; i < 8; i++) cv[i] = *(const float4*)&sC[t0 + i][n];
        #pragma unroll
        for (int j = 0; j < 8; j++) hv[j] = *(const float4*)&sB[p0 + j][n];
        #pragma unroll
        for (int i = 0; i < 8; i++) {
            #pragma unroll
            for (int j = 0; j < 8; j++) {
                acc[i][j] += cv[i].x * hv[j].x + cv[i].y * hv[j].y
                           + cv[i].z * hv[j].z + cv[i].w * hv[j].w;
            }
        }
    }
    #pragma unroll
    for (int i = 0; i < 8; i++) {
        float e = __expf(sS[t0 + i]);
        #pragma unroll
        for (int j = 0; j < 8; j++) acc[i][j] *= e;
    }
    __syncthreads();
    // ---- load B (overwrite Hin)
    for (int off = tid * 4; off < 16384; off += 1024) {
        int r = off >> 7, col = off & 127;
        *(float4*)&sB[r][col] = *(const float4*)&xc[(size_t)(tok0 + r) * 512 + 256 + col];
    }
    __syncthreads();
    // ---- G = mask ∘ (C·B^T) into registers (s-tile index = p0 here)
    float g[8][8];
    #pragma unroll
    for (int i = 0; i < 8; i++) {
        #pragma unroll
        for (int j = 0; j < 8; j++) g[i][j] = 0.f;
    }
    if (tx <= ty) {
        for (int n = 0; n < 128; n += 4) {
            float4 cv[8], bv[8];
            #pragma unroll
            for (int i = 0; i < 8; i++) cv[i] = *(const float4*)&sC[t0 + i][n];
            #pragma unroll
            for (int j = 0; j < 8; j++) bv[j] = *(const float4*)&sB[p0 + j][n];
            #pragma unroll
            for (int i = 0; i < 8; i++) {
                #pragma unroll
                for (int j = 0; j < 8; j++) {
                    g[i][j] += cv[i].x * bv[j].x + cv[i].y * bv[j].y
                             + cv[i].z * bv[j].z + cv[i].w * bv[j].w;
                }
            }
        }
        #pragma unroll
        for (int i = 0; i < 8; i++) {
            int t = t0 + i;
            #pragma unroll
            for (int j = 0; j < 8; j++) {
                int s = p0 + j;
                g[i][j] = (s <= t) ? g[i][j] * __expf(sS[t] - sS[s]) * sdt[s] : 0.f;
            }
        }
    }
    __syncthreads();
    // ---- write G over C; load X over B
    #pragma unroll
    for (int i = 0; i < 8; i++) {
        #pragma unroll
        for (int j = 0; j < 8; j++) sC[t0 + i][p0 + j] = g[i][j];
    }
    for (int off = tid * 4; off < 16384; off += 1024) {
        int r = off >> 7, col = off & 127;
        *(float4*)&sB[r][col] = *(const float4*)&xc[(size_t)(tok0 + r) * 512 + h * 128 + col];
    }
    __syncthreads();
    // ---- Y += G @ X
    for (int s4 = 0; s4 < 128; s4 += 4) {
        float4 gv[8];
        #pragma unroll
        for (int i = 0; i < 8; i++) gv[i] = *(const float4*)&sC[t0 + i][s4];
        #pragma unroll
        for (int ss = 0; ss < 4; ss++) {
            float4 xa = *(const float4*)&sB[s4 + ss][p0];
            float4 xb = *(const float4*)&sB[s4 + ss][p0 + 4];
            #pragma unroll
            for (int i = 0; i < 8; i++) {
                float gi = (ss == 0) ? gv[i].x : (ss == 1) ? gv[i].y
                         : (ss == 2) ? gv[i].z : gv[i].w;
                acc[i][0] += gi * xa.x; acc[i][1] += gi * xa.y;
                acc[i][2] += gi * xa.z; acc[i][3] += gi * xa.w;
                acc[i][4] += gi * xb.x; acc[i][5] += gi * xb.y;
                acc[i][6] += gi * xb.z; acc[i][7] += gi * xb.w;
            }
        }
    }
    // ---- D skip + store
    const float dcoef = Dp[h];
    #pragma unroll
    for (int i = 0; i < 8; i++) {
        int t = t0 + i;
        float4 xa = *(const float4*)&sB[t][p0];
        float4 xb = *(const float4*)&sB[t][p0 + 4];
        float4 o0 = make_float4(acc[i][0] + dcoef * xa.x, acc[i][1] + dcoef * xa.y,
                                acc[i][2] + dcoef * xa.z, acc[i][3] + dcoef * xa.w);
        float4 o1 = make_float4(acc[i][4] + dcoef * xb.x, acc[i][5] + dcoef * xb.y,
                                acc[i][6] + dcoef * xb.z, acc[i][7] + dcoef * xb.w);
        float* yr = &y[(size_t)(tok0 + t) * 256 + h * 128 + p0];
        *(float4*)yr = o0;
        *(float4*)(yr + 4) = o1;
    }
}

// ---------------------------------------------------------------------------
// Gated RMSNorm: y = rms(y * silu(z)) * w   (norm over 256 channels)
// ---------------------------------------------------------------------------
__global__ __launch_bounds__(256) void gatenorm_kernel(
    const float* __restrict__ zx, const float* __restrict__ w,
    float* __restrict__ y)
{
    const int tok = blockIdx.x, e = threadIdx.x;
    float yv = y[(size_t)tok * 256 + e];
    float zv = zx[(size_t)tok * 770 + e];
    float gval = yv * silu_f(zv);
    float ss = gval * gval;
    #pragma unroll
    for (int o = 1; o < 64; o <<= 1) ss += __shfl_xor(ss, o);
    __shared__ float sred[4];
    if ((e & 63) == 0) sred[e >> 6] = ss;
    __syncthreads();
    float total = sred[0] + sred[1] + sred[2] + sred[3];
    float rstd = rsqrtf(total * (1.f / 256.f) + 1e-5f);
    y[(size_t)tok * 256 + e] = gval * rstd * w[e];
}

// ---------------------------------------------------------------------------
extern "C" void kernel_launch(void* const* d_in, const int* in_sizes, int n_in,
                              void* d_out, int out_size, void* d_ws, size_t ws_size,
                              hipStream_t stream)
{
    (void)in_sizes; (void)n_in; (void)out_size; (void)ws_size;
    const float* x       = (const float*)d_in[0];   // (4,4096,64)
    const float* in_w    = (const float*)d_in[1];   // (128,64)
    const float* in_b    = (const float*)d_in[2];   // (128)
    const float* out_w   = (const float*)d_in[3];   // (64,128)
    const float* out_b   = (const float*)d_in[4];   // (64)
    const float* l_rms_w = (const float*)d_in[5];   // (2,128)
    const float* l_in_w  = (const float*)d_in[6];   // (2,770,128)
    const float* conv_w  = (const float*)d_in[7];   // (2,512,4)
    const float* conv_b  = (const float*)d_in[8];   // (2,512)
    const float* dt_bias = (const float*)d_in[9];   // (2,2)
    const float* A_log   = (const float*)d_in[10];  // (2,2)
    const float* D_p     = (const float*)d_in[11];  // (2,2)
    const float* gnorm_w = (const float*)d_in[12];  // (2,256)
    const float* l_out_w = (const float*)d_in[13];  // (2,128,256)
    const float* fnorm_w = (const float*)d_in[14];  // (128)

    float* ws  = (float*)d_ws;
    float* xp  = ws;                     // 16384*128
    float* h   = xp  + (size_t)MTOK * 128;
    float* hn  = h   + (size_t)MTOK * 128;
    float* zx  = hn  + (size_t)MTOK * 128;   // 16384*770
    float* xc  = zx  + (size_t)MTOK * 770;   // 16384*512
    float* dtb = xc  + (size_t)MTOK * 512;   // 16384*2
    float* Sb  = dtb + (size_t)MTOK * 2;     // 16384*2
    float* Hb  = Sb  + (size_t)MTOK * 2;     // 4*2*32*128*128
    float* y   = Hb  + (size_t)4 * 2 * 32 * 128 * 128;  // 16384*256

    // xp = x @ in_w^T + in_b ; h = xp
    gemm_nt_kernel<<<dim3(2, 256), 256, 0, stream>>>(x, in_w, xp, MTOK, 128, 64, in_b, 0);
    hipMemcpyAsync(h, xp, (size_t)MTOK * 128 * sizeof(float),
                   hipMemcpyDeviceToDevice, stream);

    for (int i = 0; i < 2; i++) {
        rmsnorm128_kernel<<<MTOK, 128, 0, stream>>>(h, l_rms_w + i * 128, hn);
        gemm_nt_kernel<<<dim3(13, 256), 256, 0, stream>>>(
            hn, l_in_w + (size_t)i * 770 * 128, zx, MTOK, 770, 128, nullptr, 0);
        conv_silu_kernel<<<MTOK * 2, 256, 0, stream>>>(
            zx, conv_w + i * 2048, conv_b + i * 512, xc);
        dt_scan_kernel<<<dim3(32, 2, 4), 128, 0, stream>>>(
            zx, dt_bias + i * 2, A_log + i * 2, dtb, Sb);
        ssd_chunkstate_kernel<<<dim3(32, 2, 4), 256, 0, stream>>>(xc, dtb, Sb, Hb);
        ssd_statecombine_kernel<<<dim3(64, 2, 4), 256, 0, stream>>>(Sb, Hb);
        ssd_output_kernel<<<dim3(32, 2, 4), 256, 0, stream>>>(
            xc, dtb, Sb, Hb, D_p + i * 2, y);
        gatenorm_kernel<<<MTOK, 256, 0, stream>>>(zx, gnorm_w + i * 256, y);
        gemm_nt_kernel<<<dim3(2, 256), 256, 0, stream>>>(
            y, l_out_w + (size_t)i * 128 * 256, h, MTOK, 128, 256, nullptr, 1);
    }

    final_norm_kernel<<<MTOK, 128, 0, stream>>>(h, xp, fnorm_w, hn);
    gemm_nt_kernel<<<dim3(1, 256), 256, 0, stream>>>(
        hn, out_w, (float*)d_out, MTOK, 64, 128, out_b, 0);
}

// Round 4
// 392.336 us; speedup vs baseline: 1.8049x; 1.8049x over previous
//
#include <hip/hip_runtime.h>
#include <cstddef>
#include <cstdint>

// MambaDoc — round 4: split hi/lo bf16 projections, fixed operand layouts.
// Activations (A operand): row = [hi | lo | hi]; Weights (W operand):
// row = [hi | hi | lo]  =>  dot = A_hi·W_hi + A_lo·W_hi + A_hi·W_lo (~fp32).
// SSD internals single-bf16; mixer output y fp32.

#define LSEQ 4096
#define MTOK 16384

typedef unsigned short u16;
typedef __bf16 bf16_t;
typedef bf16_t bf16x8 __attribute__((ext_vector_type(8)));
typedef float f32x4 __attribute__((ext_vector_type(4)));

__device__ __forceinline__ u16 f2b(float x) {
    return __builtin_bit_cast(u16, (bf16_t)x);
}
__device__ __forceinline__ float b2f(u16 u) {
    return (float)__builtin_bit_cast(bf16_t, u);
}
__device__ __forceinline__ float silu_f(float x) { return x / (1.f + __expf(-x)); }

__device__ __forceinline__ void async_lds16(const void* g, void* l) {
    __builtin_amdgcn_global_load_lds(
        (const __attribute__((address_space(1))) unsigned int*)g,
        (__attribute__((address_space(3))) unsigned int*)l, 16, 0, 0);
}

// ---------------------------------------------------------------------------
// fp32 (R,K) -> bf16 (R,3K) split.
// mode 0 (activation): row = [hi | lo | hi]
// mode 1 (weight):     row = [hi | hi | lo]
// n4 = R*K/4; K multiple of 4.
// ---------------------------------------------------------------------------
__global__ __launch_bounds__(256) void cvt_split3_kernel(
    const float* __restrict__ in, u16* __restrict__ out, int K, int n4, int mode)
{
    int i = blockIdx.x * 256 + threadIdx.x;
    if (i >= n4) return;
    int e0 = i * 4;
    int r = e0 / K, k = e0 - r * K;
    float4 v = *(const float4*)&in[(size_t)e0];
    float vv[4] = {v.x, v.y, v.z, v.w};
    union { u16 u[4]; uint2 q; } hi, lo;
    #pragma unroll
    for (int j = 0; j < 4; j++) {
        hi.u[j] = f2b(vv[j]);
        lo.u[j] = f2b(vv[j] - b2f(hi.u[j]));
    }
    u16* row = out + (size_t)r * 3 * K;
    *(uint2*)&row[k] = hi.q;
    if (mode == 0) {
        *(uint2*)&row[K + k] = lo.q;
        *(uint2*)&row[2 * K + k] = hi.q;
    } else {
        *(uint2*)&row[K + k] = hi.q;
        *(uint2*)&row[2 * K + k] = lo.q;
    }
}

// ---------------------------------------------------------------------------
// bf16 MFMA GEMM: out[m,n] (+)= sum_k A[m,k]*W[n,k] (+bias). fp32 out.
// BM=128, BN=128, BK=64. K multiple of 64, M multiple of 128, N arbitrary.
// ---------------------------------------------------------------------------
__global__ __launch_bounds__(256) void gemm_bf16_kernel(
    const u16* __restrict__ A, const u16* __restrict__ W,
    float* __restrict__ out, float* __restrict__ out2,
    const float* __restrict__ bias, int M, int N, int K, int accumulate)
{
    __shared__ u16 sA[128 * 64];
    __shared__ u16 sW[128 * 64];
    const int n0 = blockIdx.x * 128, m0 = blockIdx.y * 128;
    const int tid = threadIdx.x, wid = tid >> 6, lane = tid & 63;
    const int wm = (wid >> 1) * 64, wn = (wid & 1) * 64;
    const int quad = lane >> 4, cl = lane & 15;
    f32x4 acc[4][4];
    #pragma unroll
    for (int i = 0; i < 4; i++)
        #pragma unroll
        for (int j = 0; j < 4; j++) acc[i][j] = f32x4{0.f, 0.f, 0.f, 0.f};

    for (int k0 = 0; k0 < K; k0 += 64) {
        #pragma unroll
        for (int i = 0; i < 4; i++) {
            int ck = i * 256 + tid;
            int r = ck >> 3, cc = ck & 7;
            int csw = (cc ^ (r & 7)) << 3;
            async_lds16(A + (size_t)(m0 + r) * K + k0 + csw,
                        (void*)(sA + (i * 256 + (tid & ~63)) * 8));
            int rr = n0 + r; if (rr >= N) rr = N - 1;
            async_lds16(W + (size_t)rr * K + k0 + csw,
                        (void*)(sW + (i * 256 + (tid & ~63)) * 8));
        }
        __syncthreads();
        #pragma unroll
        for (int ks = 0; ks < 2; ks++) {
            bf16x8 af[4], wf[4];
            int kc = ks * 4 + quad;
            #pragma unroll
            for (int i = 0; i < 4; i++) {
                int r = wm + i * 16 + cl;
                af[i] = *(const bf16x8*)&sA[r * 64 + ((kc ^ (r & 7)) << 3)];
            }
            #pragma unroll
            for (int j = 0; j < 4; j++) {
                int r = wn + j * 16 + cl;
                wf[j] = *(const bf16x8*)&sW[r * 64 + ((kc ^ (r & 7)) << 3)];
            }
            #pragma unroll
            for (int i = 0; i < 4; i++)
                #pragma unroll
                for (int j = 0; j < 4; j++)
                    acc[i][j] = __builtin_amdgcn_mfma_f32_16x16x32_bf16(
                        af[i], wf[j], acc[i][j], 0, 0, 0);
        }
        __syncthreads();
    }
    #pragma unroll
    for (int i = 0; i < 4; i++) {
        int m = m0 + wm + i * 16 + quad * 4;
        #pragma unroll
        for (int j = 0; j < 4; j++) {
            int n = n0 + wn + j * 16 + cl;
            if (n < N) {
                float bv = bias ? bias[n] : 0.f;
                #pragma unroll
                for (int r = 0; r < 4; r++) {
                    size_t o = (size_t)(m + r) * N + n;
                    float v = acc[i][j][r] + bv;
                    if (accumulate) v += out[o];
                    out[o] = v;
                    if (out2) out2[o] = v;
                }
            }
        }
    }
}

// ---------------------------------------------------------------------------
// RMSNorm over 128 ch -> split bf16 activation row [hi|lo|hi] (stride 384)
// ---------------------------------------------------------------------------
__global__ __launch_bounds__(128) void rmsnorm128_kernel(
    const float* __restrict__ in, const float* __restrict__ w,
    u16* __restrict__ out)
{
    const int tok = blockIdx.x, d = threadIdx.x;
    float v = in[(size_t)tok * 128 + d];
    float ss = v * v;
    #pragma unroll
    for (int o = 1; o < 64; o <<= 1) ss += __shfl_xor(ss, o);
    __shared__ float sred[2];
    if ((d & 63) == 0) sred[d >> 6] = ss;
    __syncthreads();
    float rstd = rsqrtf((sred[0] + sred[1]) * (1.f / 128.f) + 1e-5f);
    float val = v * rstd * w[d];
    u16 hi = f2b(val);
    u16 lo = f2b(val - b2f(hi));
    u16* row = out + (size_t)tok * 384;
    row[d] = hi; row[128 + d] = lo; row[256 + d] = hi;
}

// Final norm + outer residual -> split bf16 activation row (stride 384)
__global__ __launch_bounds__(128) void final_norm_kernel(
    const float* __restrict__ in, const float* __restrict__ xp,
    const float* __restrict__ w, u16* __restrict__ out)
{
    const int tok = blockIdx.x, d = threadIdx.x;
    float v = in[(size_t)tok * 128 + d];
    float ss = v * v;
    #pragma unroll
    for (int o = 1; o < 64; o <<= 1) ss += __shfl_xor(ss, o);
    __shared__ float sred[2];
    if ((d & 63) == 0) sred[d >> 6] = ss;
    __syncthreads();
    float rstd = rsqrtf((sred[0] + sred[1]) * (1.f / 128.f) + 1e-5f);
    float val = xp[(size_t)tok * 128 + d] + v * rstd * w[d];
    u16 hi = f2b(val);
    u16 lo = f2b(val - b2f(hi));
    u16* row = out + (size_t)tok * 384;
    row[d] = hi; row[128 + d] = lo; row[256 + d] = hi;
}

// ---------------------------------------------------------------------------
// dt = softplus(dt_raw + bias); chunk-local inclusive cumsum of A*dt -> Sb.
// ---------------------------------------------------------------------------
__global__ __launch_bounds__(128) void dt_scan_kernel(
    const float* __restrict__ zx, const float* __restrict__ dt_bias,
    const float* __restrict__ A_log, float* __restrict__ dtb,
    float* __restrict__ Sb)
{
    const int c = blockIdx.x, h = blockIdx.y, b = blockIdx.z;
    const int t = threadIdx.x;
    const int tok = b * LSEQ + c * 128 + t;
    float raw = zx[(size_t)tok * 770 + 768 + h] + dt_bias[h];
    float dt = fmaxf(raw, 0.f) + log1pf(__expf(-fabsf(raw)));
    dtb[(size_t)tok * 2 + h] = dt;
    float a = -__expf(A_log[h]);
    __shared__ float s[128];
    s[t] = a * dt;
    __syncthreads();
    for (int off = 1; off < 128; off <<= 1) {
        float add = (t >= off) ? s[t - off] : 0.f;
        __syncthreads();
        s[t] += add;
        __syncthreads();
    }
    Sb[(size_t)tok * 2 + h] = s[t];
}

// ---------------------------------------------------------------------------
// Causal conv(4)+silu over 512 xBC channels, tiled 64 tok x 64 ch.
// Writes xc (bf16 [tok][512]), xT ([p][s] per chunk), bT (w_s-scaled B^T).
// ---------------------------------------------------------------------------
__global__ __launch_bounds__(256) void conv_tile_kernel(
    const float* __restrict__ zx, const float* __restrict__ cw,
    const float* __restrict__ cb, const float* __restrict__ dtb,
    const float* __restrict__ Sb, u16* __restrict__ xc,
    u16* __restrict__ xT, u16* __restrict__ bT)
{
    __shared__ float sZ[67][68];
    __shared__ float sT[64][65];
    __shared__ float sw[2][64];
    const int tid = threadIdx.x;
    const int tok0 = blockIdx.x * 64;
    const int cg = blockIdx.y;
    const int cgb = cg * 64;
    const int l0 = tok0 & (LSEQ - 1);
    for (int idx = tid; idx < 67 * 32; idx += 256) {
        int row = idx >> 5, c2 = (idx & 31) * 2;
        int lr = l0 + row - 3;
        float2 v = make_float2(0.f, 0.f);
        if (lr >= 0)
            v = *(const float2*)&zx[(size_t)(tok0 + row - 3) * 770 + 256 + cgb + c2];
        sZ[row][c2] = v.x; sZ[row][c2 + 1] = v.y;
    }
    if ((cg == 4 || cg == 5) && tid < 128) {
        int hh = tid >> 6, j = tid & 63;
        int tokL = (tok0 & ~127) + 127;
        sw[hh][j] = __expf(Sb[(size_t)tokL * 2 + hh] - Sb[(size_t)(tok0 + j) * 2 + hh])
                    * dtb[(size_t)(tok0 + j) * 2 + hh];
    }
    const int ch = tid & 63;
    const int chg = cgb + ch;
    const float w0 = cw[chg * 4], w1 = cw[chg * 4 + 1];
    const float w2 = cw[chg * 4 + 2], w3 = cw[chg * 4 + 3];
    const float cbv = cb[chg];
    __syncthreads();
    #pragma unroll
    for (int k = 0; k < 16; k++) {
        int tokr = k * 4 + (tid >> 6);
        float a = cbv + sZ[tokr][ch] * w0 + sZ[tokr + 1][ch] * w1
                + sZ[tokr + 2][ch] * w2 + sZ[tokr + 3][ch] * w3;
        float v = silu_f(a);
        xc[(size_t)(tok0 + tokr) * 512 + chg] = f2b(v);
        sT[ch][tokr] = v;
    }
    __syncthreads();
    const int b = tok0 >> 12;
    const int c = (tok0 & (LSEQ - 1)) >> 7;
    const int s0 = tok0 & 127;
    if (cg < 4) {
        int hh = cg >> 1;
        int pbase = (cg & 1) * 64;
        u16* base = xT + (((size_t)((b * 2 + hh) * 32 + c)) << 14);
        for (int idx = tid; idx < 512; idx += 256) {
            int pr = idx >> 3, sc = (idx & 7) * 8;
            union { u16 u[8]; uint4 q; } pk;
            #pragma unroll
            for (int j = 0; j < 8; j++) pk.u[j] = f2b(sT[pr][sc + j]);
            *(uint4*)&base[(size_t)(pbase + pr) * 128 + s0 + sc] = pk.q;
        }
    } else if (cg < 6) {
        int nbase = (cg - 4) * 64;
        for (int hh = 0; hh < 2; hh++) {
            u16* base = bT + (((size_t)((b * 2 + hh) * 32 + c)) << 14);
            for (int idx = tid; idx < 512; idx += 256) {
                int nr = idx >> 3, sc = (idx & 7) * 8;
                union { u16 u[8]; uint4 q; } pk;
                #pragma unroll
                for (int j = 0; j < 8; j++)
                    pk.u[j] = f2b(sT[nr][sc + j] * sw[hh][sc + j]);
                *(uint4*)&base[(size_t)(nbase + nr) * 128 + s0 + sc] = pk.q;
            }
        }
    }
}

// ---------------------------------------------------------------------------
// Chunk-local end state via MFMA: Hloc[p,n] = sum_s X^T[p,s]*(w_s B)[s,n].
// ---------------------------------------------------------------------------
__global__ __launch_bounds__(256) void chunkstate_kernel(
    const u16* __restrict__ xT, const u16* __restrict__ bT,
    float* __restrict__ Hb)
{
    __shared__ u16 sX[128 * 128];
    __shared__ u16 sB[128 * 128];
    const int c = blockIdx.x, h = blockIdx.y, b = blockIdx.z;
    const int tid = threadIdx.x, wid = tid >> 6, lane = tid & 63;
    const size_t blk = ((size_t)((b * 2 + h) * 32 + c)) << 14;
    #pragma unroll
    for (int i = 0; i < 8; i++) {
        int ck = i * 256 + tid;
        int r = ck >> 4, cc = ck & 15;
        size_t g = (size_t)r * 128 + ((cc ^ (r & 15)) << 3);
        async_lds16(xT + blk + g, (void*)(sX + (i * 256 + (tid & ~63)) * 8));
        async_lds16(bT + blk + g, (void*)(sB + (i * 256 + (tid & ~63)) * 8));
    }
    __syncthreads();
    const int wm = (wid >> 1) * 64, wn = (wid & 1) * 64;
    const int quad = lane >> 4, cl = lane & 15;
    f32x4 acc[4][4];
    #pragma unroll
    for (int i = 0; i < 4; i++)
        #pragma unroll
        for (int j = 0; j < 4; j++) acc[i][j] = f32x4{0.f, 0.f, 0.f, 0.f};
    #pragma unroll
    for (int ks = 0; ks < 4; ks++) {
        bf16x8 xa[4], bb[4];
        int kc = ks * 4 + quad;
        #pragma unroll
        for (int i = 0; i < 4; i++) {
            int r = wm + i * 16 + cl;
            xa[i] = *(const bf16x8*)&sX[r * 128 + ((kc ^ (r & 15)) << 3)];
        }
        #pragma unroll
        for (int j = 0; j < 4; j++) {
            int r = wn + j * 16 + cl;
            bb[j] = *(const bf16x8*)&sB[r * 128 + ((kc ^ (r & 15)) << 3)];
        }
        #pragma unroll
        for (int i = 0; i < 4; i++)
            #pragma unroll
            for (int j = 0; j < 4; j++)
                acc[i][j] = __builtin_amdgcn_mfma_f32_16x16x32_bf16(
                    xa[i], bb[j], acc[i][j], 0, 0, 0);
    }
    float* out = Hb + blk;
    #pragma unroll
    for (int i = 0; i < 4; i++)
        #pragma unroll
        for (int j = 0; j < 4; j++)
            #pragma unroll
            for (int r = 0; r < 4; r++)
                out[(size_t)(wm + i * 16 + quad * 4 + r) * 128 + wn + j * 16 + cl]
                    = acc[i][j][r];
}

// ---------------------------------------------------------------------------
// Inter-chunk combine; writes INCOMING state per chunk as bf16.
// ---------------------------------------------------------------------------
__global__ __launch_bounds__(256) void statecombine_kernel(
    const float* __restrict__ Sb, const float* __restrict__ Hb,
    u16* __restrict__ Hbf)
{
    const int e = blockIdx.x * 256 + threadIdx.x;
    const int h = blockIdx.y, b = blockIdx.z;
    const size_t base = ((size_t)((b * 2 + h) * 32)) << 14;
    float state = 0.f;
    for (int c = 0; c < 32; c++) {
        size_t idx = base + ((size_t)c << 14) + e;
        float v = Hb[idx];
        Hbf[idx] = f2b(state);
        float dec = __expf(Sb[(size_t)(b * LSEQ + c * 128 + 127) * 2 + h]);
        state = dec * state + v;
    }
}

// ---------------------------------------------------------------------------
// Per-chunk output via MFMA, 3 GEMMs. Output y fp32.
// ---------------------------------------------------------------------------
__global__ __launch_bounds__(256) void ssd_output_kernel(
    const u16* __restrict__ xc, const u16* __restrict__ xT,
    const u16* __restrict__ Hbf, const float* __restrict__ dtb,
    const float* __restrict__ Sb, float* __restrict__ y)
{
    __shared__ u16 bufA[128 * 128];
    __shared__ u16 bufB[128 * 128];
    const int c = blockIdx.x, h = blockIdx.y, b = blockIdx.z;
    const int tid = threadIdx.x, wid = tid >> 6, lane = tid & 63;
    const int tok0 = b * LSEQ + c * 128;
    const size_t blk = ((size_t)((b * 2 + h) * 32 + c)) << 14;
    #pragma unroll
    for (int i = 0; i < 8; i++) {
        int ck = i * 256 + tid;
        int r = ck >> 4, cc = ck & 15;
        int csw = (cc ^ (r & 15)) << 3;
        async_lds16(xc + (size_t)(tok0 + r) * 512 + 384 + csw,
                    (void*)(bufA + (i * 256 + (tid & ~63)) * 8));
        async_lds16(Hbf + blk + (size_t)r * 128 + csw,
                    (void*)(bufB + (i * 256 + (tid & ~63)) * 8));
    }
    const int wm = (wid >> 1) * 64, wn = (wid & 1) * 64;
    const int quad = lane >> 4, cl = lane & 15;
    float St[16], Ss[4], dts[4];
    #pragma unroll
    for (int i = 0; i < 4; i++)
        #pragma unroll
        for (int r = 0; r < 4; r++)
            St[i * 4 + r] = Sb[(size_t)(tok0 + wm + i * 16 + quad * 4 + r) * 2 + h];
    #pragma unroll
    for (int j = 0; j < 4; j++) {
        int s = wn + j * 16 + cl;
        Ss[j] = Sb[(size_t)(tok0 + s) * 2 + h];
        dts[j] = dtb[(size_t)(tok0 + s) * 2 + h];
    }
    __syncthreads();
    f32x4 acc[4][4];
    #pragma unroll
    for (int i = 0; i < 4; i++)
        #pragma unroll
        for (int j = 0; j < 4; j++) acc[i][j] = f32x4{0.f, 0.f, 0.f, 0.f};
    // phase 1: C @ Hin^T, scaled by exp(S_t)
    #pragma unroll
    for (int ks = 0; ks < 4; ks++) {
        bf16x8 ca[4], hb[4];
        int kc = ks * 4 + quad;
        #pragma unroll
        for (int i = 0; i < 4; i++) {
            int r = wm + i * 16 + cl;
            ca[i] = *(const bf16x8*)&bufA[r * 128 + ((kc ^ (r & 15)) << 3)];
        }
        #pragma unroll
        for (int j = 0; j < 4; j++) {
            int r = wn + j * 16 + cl;
            hb[j] = *(const bf16x8*)&bufB[r * 128 + ((kc ^ (r & 15)) << 3)];
        }
        #pragma unroll
        for (int i = 0; i < 4; i++)
            #pragma unroll
            for (int j = 0; j < 4; j++)
                acc[i][j] = __builtin_amdgcn_mfma_f32_16x16x32_bf16(
                    ca[i], hb[j], acc[i][j], 0, 0, 0);
    }
    #pragma unroll
    for (int i = 0; i < 4; i++)
        #pragma unroll
        for (int r = 0; r < 4; r++) {
            float e = __expf(St[i * 4 + r]);
            #pragma unroll
            for (int j = 0; j < 4; j++) acc[i][j][r] *= e;
        }
    __syncthreads();
    // phase 2: stage B; S = C @ B^T
    #pragma unroll
    for (int i = 0; i < 8; i++) {
        int ck = i * 256 + tid;
        int r = ck >> 4, cc = ck & 15;
        int csw = (cc ^ (r & 15)) << 3;
        async_lds16(xc + (size_t)(tok0 + r) * 512 + 256 + csw,
                    (void*)(bufB + (i * 256 + (tid & ~63)) * 8));
    }
    __syncthreads();
    f32x4 sacc[4][4];
    #pragma unroll
    for (int i = 0; i < 4; i++)
        #pragma unroll
        for (int j = 0; j < 4; j++) sacc[i][j] = f32x4{0.f, 0.f, 0.f, 0.f};
    #pragma unroll
    for (int ks = 0; ks < 4; ks++) {
        bf16x8 ca[4], bb[4];
        int kc = ks * 4 + quad;
        #pragma unroll
        for (int i = 0; i < 4; i++) {
            int r = wm + i * 16 + cl;
            ca[i] = *(const bf16x8*)&bufA[r * 128 + ((kc ^ (r & 15)) << 3)];
        }
        #pragma unroll
        for (int j = 0; j < 4; j++) {
            int r = wn + j * 16 + cl;
            bb[j] = *(const bf16x8*)&bufB[r * 128 + ((kc ^ (r & 15)) << 3)];
        }
        #pragma unroll
        for (int i = 0; i < 4; i++)
            #pragma unroll
            for (int j = 0; j < 4; j++)
                if (wm + i * 16 + 15 >= wn + j * 16)
                    sacc[i][j] = __builtin_amdgcn_mfma_f32_16x16x32_bf16(
                        ca[i], bb[j], sacc[i][j], 0, 0, 0);
    }
    __syncthreads();
    // G = mask ∘ S ∘ exp(St-Ss) ∘ dt_s -> bufA ; stage X^T -> bufB
    #pragma unroll
    for (int i = 0; i < 8; i++) {
        int ck = i * 256 + tid;
        int r = ck >> 4, cc = ck & 15;
        int csw = (cc ^ (r & 15)) << 3;
        async_lds16(xT + blk + (size_t)r * 128 + csw,
                    (void*)(bufB + (i * 256 + (tid & ~63)) * 8));
    }
    #pragma unroll
    for (int i = 0; i < 4; i++)
        #pragma unroll
        for (int r = 0; r < 4; r++) {
            int t = wm + i * 16 + quad * 4 + r;
            float Stv = St[i * 4 + r];
            #pragma unroll
            for (int j = 0; j < 4; j++) {
                int s = wn + j * 16 + cl;
                float gv = 0.f;
                if (s <= t) gv = sacc[i][j][r] * __expf(Stv - Ss[j]) * dts[j];
                bufA[t * 128 + (((s >> 3) ^ (t & 15)) << 3) + (s & 7)] = f2b(gv);
            }
        }
    __syncthreads();
    // phase 3: Y += G @ X
    #pragma unroll
    for (int ks = 0; ks < 4; ks++) {
        bf16x8 ga[4], xb[4];
        int kc = ks * 4 + quad;
        #pragma unroll
        for (int i = 0; i < 4; i++) {
            int r = wm + i * 16 + cl;
            ga[i] = *(const bf16x8*)&bufA[r * 128 + ((kc ^ (r & 15)) << 3)];
        }
        #pragma unroll
        for (int j = 0; j < 4; j++) {
            int r = wn + j * 16 + cl;
            xb[j] = *(const bf16x8*)&bufB[r * 128 + ((kc ^ (r & 15)) << 3)];
        }
        #pragma unroll
        for (int i = 0; i < 4; i++)
            #pragma unroll
            for (int j = 0; j < 4; j++)
                acc[i][j] = __builtin_amdgcn_mfma_f32_16x16x32_bf16(
                    ga[i], xb[j], acc[i][j], 0, 0, 0);
    }
    // store y fp32
    #pragma unroll
    for (int i = 0; i < 4; i++)
        #pragma unroll
        for (int r = 0; r < 4; r++) {
            int t = wm + i * 16 + quad * 4 + r;
            #pragma unroll
            for (int j = 0; j < 4; j++) {
                int p = wn + j * 16 + cl;
                y[(size_t)(tok0 + t) * 256 + h * 128 + p] = acc[i][j][r];
            }
        }
}

// ---------------------------------------------------------------------------
// Gated RMSNorm (+ D-skip): g = (y + D*x)*silu(z); out = rms(g)*w
// -> split bf16 activation row [hi|lo|hi] stride 768.
// ---------------------------------------------------------------------------
__global__ __launch_bounds__(256) void gatenorm_kernel(
    const float* __restrict__ zx, const u16* __restrict__ xc,
    const float* __restrict__ gnw, const float* __restrict__ Dp,
    const float* __restrict__ y, u16* __restrict__ ysplit)
{
    const int tok = blockIdx.x, e = threadIdx.x;
    const int h = e >> 7;
    float yv = y[(size_t)tok * 256 + e] + Dp[h] * b2f(xc[(size_t)tok * 512 + e]);
    float zv = zx[(size_t)tok * 770 + e];
    float g = yv * silu_f(zv);
    float ss = g * g;
    #pragma unroll
    for (int o = 1; o < 64; o <<= 1) ss += __shfl_xor(ss, o);
    __shared__ float sred[4];
    if ((e & 63) == 0) sred[e >> 6] = ss;
    __syncthreads();
    float total = sred[0] + sred[1] + sred[2] + sred[3];
    float rstd = rsqrtf(total * (1.f / 256.f) + 1e-5f);
    float val = g * rstd * gnw[e];
    u16 hi = f2b(val);
    u16 lo = f2b(val - b2f(hi));
    u16* row = ysplit + (size_t)tok * 768;
    row[e] = hi; row[256 + e] = lo; row[512 + e] = hi;
}

// ---------------------------------------------------------------------------
extern "C" void kernel_launch(void* const* d_in, const int* in_sizes, int n_in,
                              void* d_out, int out_size, void* d_ws, size_t ws_size,
                              hipStream_t stream)
{
    (void)in_sizes; (void)n_in; (void)out_size; (void)ws_size;
    const float* x       = (const float*)d_in[0];
    const float* in_w    = (const float*)d_in[1];
    const float* in_b    = (const float*)d_in[2];
    const float* out_w   = (const float*)d_in[3];
    const float* out_b   = (const float*)d_in[4];
    const float* l_rms_w = (const float*)d_in[5];
    const float* l_in_w  = (const float*)d_in[6];
    const float* conv_w  = (const float*)d_in[7];
    const float* conv_b  = (const float*)d_in[8];
    const float* dt_bias = (const float*)d_in[9];
    const float* A_log   = (const float*)d_in[10];
    const float* D_p     = (const float*)d_in[11];
    const float* gnorm_w = (const float*)d_in[12];
    const float* l_out_w = (const float*)d_in[13];
    const float* fnorm_w = (const float*)d_in[14];

    char* w = (char*)d_ws;
    float* xp    = (float*)(w);                    // 8 MB
    float* hbuf  = (float*)(w + 8388608);          // 8 MB
    float* zx    = (float*)(w + 16777216);         // 50.46 MB
    float* dtb   = (float*)(w + 67239936);         // 128 KB
    float* Sb    = (float*)(w + 67371008);         // 128 KB
    float* Hb    = (float*)(w + 67502080);         // 16 MB fp32 chunk states
    float* yf32  = (float*)(w + 67502080);         //   alias Hb (dead by then)
    u16*   hnspl = (u16*)(w + 84279296);           // 12 MB (16384 x 384)
    u16*   xspl  = hnspl;                          //   alias (16384 x 192, dead early)
    u16*   xc    = (u16*)(w + 96862208);           // 16 MB
    u16*   xT    = (u16*)(w + 113639424);          // 8 MB
    u16*   bT    = (u16*)(w + 122028032);          // 8 MB
    u16*   Hbf   = (u16*)(w + 130416640);          // 8 MB
    u16*   yspl  = xT;                             //   alias xT|bT|Hbf (24 MB)
    u16*   wspl  = (u16*)(w + 138805248);          // ~1.7 MB
    u16* in_w_s    = wspl;                           // 128 x 192  = 24576
    u16* l_in_w_s  = wspl + 24576;                   // 1540 x 384 = 591360
    u16* l_out_w_s = wspl + 24576 + 591360;          // 256 x 768  = 196608
    u16* out_w_s   = wspl + 24576 + 591360 + 196608; // 64 x 384   = 24576

    // split conversions: x as ACTIVATION (mode 0), weights as WEIGHT (mode 1)
    cvt_split3_kernel<<<1024, 256, 0, stream>>>(x, xspl, 64, 262144, 0);
    cvt_split3_kernel<<<8, 256, 0, stream>>>(in_w, in_w_s, 64, 2048, 1);
    cvt_split3_kernel<<<193, 256, 0, stream>>>(l_in_w, l_in_w_s, 128, 49280, 1);
    cvt_split3_kernel<<<64, 256, 0, stream>>>(l_out_w, l_out_w_s, 256, 16384, 1);
    cvt_split3_kernel<<<8, 256, 0, stream>>>(out_w, out_w_s, 128, 2048, 1);

    // xp = x @ in_w^T + in_b ; duplicate into hbuf   (K = 3*64 = 192)
    gemm_bf16_kernel<<<dim3(1, 128), 256, 0, stream>>>(
        xspl, in_w_s, xp, hbuf, in_b, MTOK, 128, 192, 0);

    for (int i = 0; i < 2; i++) {
        rmsnorm128_kernel<<<MTOK, 128, 0, stream>>>(hbuf, l_rms_w + i * 128, hnspl);
        gemm_bf16_kernel<<<dim3(7, 128), 256, 0, stream>>>(        // K = 3*128
            hnspl, l_in_w_s + (size_t)i * 770 * 384, zx, nullptr, nullptr,
            MTOK, 770, 384, 0);
        dt_scan_kernel<<<dim3(32, 2, 4), 128, 0, stream>>>(
            zx, dt_bias + i * 2, A_log + i * 2, dtb, Sb);
        conv_tile_kernel<<<dim3(256, 8), 256, 0, stream>>>(
            zx, conv_w + i * 2048, conv_b + i * 512, dtb, Sb, xc, xT, bT);
        chunkstate_kernel<<<dim3(32, 2, 4), 256, 0, stream>>>(xT, bT, Hb);
        statecombine_kernel<<<dim3(64, 2, 4), 256, 0, stream>>>(Sb, Hb, Hbf);
        ssd_output_kernel<<<dim3(32, 2, 4), 256, 0, stream>>>(
            xc, xT, Hbf, dtb, Sb, yf32);
        gatenorm_kernel<<<MTOK, 256, 0, stream>>>(
            zx, xc, gnorm_w + i * 256, D_p + i * 2, yf32, yspl);
        gemm_bf16_kernel<<<dim3(1, 128), 256, 0, stream>>>(       // K = 3*256
            yspl, l_out_w_s + (size_t)i * 128 * 768, hbuf, nullptr, nullptr,
            MTOK, 128, 768, 1);
    }

    final_norm_kernel<<<MTOK, 128, 0, stream>>>(hbuf, xp, fnorm_w, hnspl);
    gemm_bf16_kernel<<<dim3(1, 128), 256, 0, stream>>>(           // K = 3*128
        hnspl, out_w_s, (float*)d_out, nullptr, out_b, MTOK, 64, 384, 0);
}

// Round 5
// 334.498 us; speedup vs baseline: 2.1170x; 1.1729x over previous
//
#include <hip/hip_runtime.h>
#include <cstddef>
#include <cstdint>

// MambaDoc — round 5:
//  * SSD internals fp16 (mfma_f32_16x16x32_f16) — ~8x less rounding than bf16
//  * zx stored fp16 (25 MB, stride 768) directly from in_proj GEMM epilogue;
//    dt softplus+cumsum fused into the in_proj dt-column block (x==6)
//  * RMSNorm / final-norm fused into the N=128 GEMM epilogues
//  * single combined convert kernel for x + all weights
// Projections stay split hi/lo bf16 (3-term ~fp32). 16 launches/iter.

#define LSEQ 4096
#define MTOK 16384

typedef unsigned short u16;
typedef __bf16 bf16_t;
typedef bf16_t bf16x8 __attribute__((ext_vector_type(8)));
typedef _Float16 f16x8 __attribute__((ext_vector_type(8)));
typedef float f32x4 __attribute__((ext_vector_type(4)));

__device__ __forceinline__ u16 f2b(float x) {
    return __builtin_bit_cast(u16, (bf16_t)x);
}
__device__ __forceinline__ float b2f(u16 u) {
    return (float)__builtin_bit_cast(bf16_t, u);
}
__device__ __forceinline__ u16 f2h(float x) {
    return __builtin_bit_cast(u16, (_Float16)x);
}
__device__ __forceinline__ float h2f(u16 u) {
    return (float)__builtin_bit_cast(_Float16, u);
}
__device__ __forceinline__ float silu_f(float x) { return x / (1.f + __expf(-x)); }

__device__ __forceinline__ void async_lds16(const void* g, void* l) {
    __builtin_amdgcn_global_load_lds(
        (const __attribute__((address_space(1))) unsigned int*)g,
        (__attribute__((address_space(3))) unsigned int*)l, 16, 0, 0);
}

// ---------------------------------------------------------------------------
// Combined fp32 -> split-bf16 conversion for x + all weights.
// mode 0 (activation): row = [hi | lo | hi]; mode 1 (weight): [hi | hi | lo].
// ---------------------------------------------------------------------------
__device__ __forceinline__ void split_store(
    const float* __restrict__ in, u16* __restrict__ out, int K, int g, int mode)
{
    int e0 = g * 4;
    int r = e0 / K, k = e0 - r * K;
    float4 v = *(const float4*)&in[(size_t)e0];
    float vv[4] = {v.x, v.y, v.z, v.w};
    union { u16 u[4]; uint2 q; } hi, lo;
    #pragma unroll
    for (int j = 0; j < 4; j++) {
        hi.u[j] = f2b(vv[j]);
        lo.u[j] = f2b(vv[j] - b2f(hi.u[j]));
    }
    u16* row = out + (size_t)r * 3 * K;
    *(uint2*)&row[k] = hi.q;
    if (mode == 0) {
        *(uint2*)&row[K + k] = lo.q;
        *(uint2*)&row[2 * K + k] = hi.q;
    } else {
        *(uint2*)&row[K + k] = hi.q;
        *(uint2*)&row[2 * K + k] = lo.q;
    }
}

__global__ __launch_bounds__(256) void cvt_all_kernel(
    const float* __restrict__ x, u16* __restrict__ xspl,
    const float* __restrict__ in_w, u16* __restrict__ in_w_s,
    const float* __restrict__ l_in_w, u16* __restrict__ l_in_w_s,
    const float* __restrict__ l_out_w, u16* __restrict__ l_out_w_s,
    const float* __restrict__ out_w, u16* __restrict__ out_w_s)
{
    int g = blockIdx.x * 256 + threadIdx.x;
    if (g < 262144) { split_store(x, xspl, 64, g, 0); return; }
    g -= 262144;
    if (g < 2048) { split_store(in_w, in_w_s, 64, g, 1); return; }
    g -= 2048;
    if (g < 49280) { split_store(l_in_w, l_in_w_s, 128, g, 1); return; }
    g -= 49280;
    if (g < 16384) { split_store(l_out_w, l_out_w_s, 256, g, 1); return; }
    g -= 16384;
    if (g < 2048) { split_store(out_w, out_w_s, 128, g, 1); return; }
}

// ---------------------------------------------------------------------------
// Generic bf16 MFMA GEMM (used only for the final 64-wide projection).
// out[m,n] = sum_k A[m,k]*W[n,k] + bias[n]. fp32 out. N arbitrary.
// ---------------------------------------------------------------------------
__global__ __launch_bounds__(256) void gemm_bf16_kernel(
    const u16* __restrict__ A, const u16* __restrict__ W,
    float* __restrict__ out, const float* __restrict__ bias,
    int M, int N, int K)
{
    __shared__ u16 sA[128 * 64];
    __shared__ u16 sW[128 * 64];
    const int n0 = blockIdx.x * 128, m0 = blockIdx.y * 128;
    const int tid = threadIdx.x, wid = tid >> 6, lane = tid & 63;
    const int wm = (wid >> 1) * 64, wn = (wid & 1) * 64;
    const int quad = lane >> 4, cl = lane & 15;
    f32x4 acc[4][4];
    #pragma unroll
    for (int i = 0; i < 4; i++)
        #pragma unroll
        for (int j = 0; j < 4; j++) acc[i][j] = f32x4{0.f, 0.f, 0.f, 0.f};

    for (int k0 = 0; k0 < K; k0 += 64) {
        #pragma unroll
        for (int i = 0; i < 4; i++) {
            int ck = i * 256 + tid;
            int r = ck >> 3, cc = ck & 7;
            int csw = (cc ^ (r & 7)) << 3;
            async_lds16(A + (size_t)(m0 + r) * K + k0 + csw,
                        (void*)(sA + (i * 256 + (tid & ~63)) * 8));
            int rr = n0 + r; if (rr >= N) rr = N - 1;
            async_lds16(W + (size_t)rr * K + k0 + csw,
                        (void*)(sW + (i * 256 + (tid & ~63)) * 8));
        }
        __syncthreads();
        #pragma unroll
        for (int ks = 0; ks < 2; ks++) {
            bf16x8 af[4], wf[4];
            int kc = ks * 4 + quad;
            #pragma unroll
            for (int i = 0; i < 4; i++) {
                int r = wm + i * 16 + cl;
                af[i] = *(const bf16x8*)&sA[r * 64 + ((kc ^ (r & 7)) << 3)];
            }
            #pragma unroll
            for (int j = 0; j < 4; j++) {
                int r = wn + j * 16 + cl;
                wf[j] = *(const bf16x8*)&sW[r * 64 + ((kc ^ (r & 7)) << 3)];
            }
            #pragma unroll
            for (int i = 0; i < 4; i++)
                #pragma unroll
                for (int j = 0; j < 4; j++)
                    acc[i][j] = __builtin_amdgcn_mfma_f32_16x16x32_bf16(
                        af[i], wf[j], acc[i][j], 0, 0, 0);
        }
        __syncthreads();
    }
    #pragma unroll
    for (int i = 0; i < 4; i++) {
        int m = m0 + wm + i * 16 + quad * 4;
        #pragma unroll
        for (int j = 0; j < 4; j++) {
            int n = n0 + wn + j * 16 + cl;
            if (n < N) {
                float bv = bias ? bias[n] : 0.f;
                #pragma unroll
                for (int r = 0; r < 4; r++)
                    out[(size_t)(m + r) * N + n] = acc[i][j][r] + bv;
            }
        }
    }
}

// ---------------------------------------------------------------------------
// in_proj GEMM: A (split act, K=384) x W (770 rows split weight).
// Blocks x<6: write zx fp16 (stride 768). Block x==6: dt columns 768/769 ->
// softplus + chunk-local cumsum in LDS -> dtb, Sb. Grid (7, 128).
// ---------------------------------------------------------------------------
__global__ __launch_bounds__(256) void gemm_inproj_kernel(
    const u16* __restrict__ A, const u16* __restrict__ W,
    u16* __restrict__ zx16, float* __restrict__ dtb, float* __restrict__ Sb,
    const float* __restrict__ dt_bias, const float* __restrict__ A_log)
{
    __shared__ u16 sA[128 * 64];
    __shared__ u16 sW[128 * 64];
    __shared__ float sdt[2][128];
    const int K = 384, N = 770;
    const int n0 = blockIdx.x * 128, m0 = blockIdx.y * 128;
    const int tid = threadIdx.x, wid = tid >> 6, lane = tid & 63;
    const int wm = (wid >> 1) * 64, wn = (wid & 1) * 64;
    const int quad = lane >> 4, cl = lane & 15;
    f32x4 acc[4][4];
    #pragma unroll
    for (int i = 0; i < 4; i++)
        #pragma unroll
        for (int j = 0; j < 4; j++) acc[i][j] = f32x4{0.f, 0.f, 0.f, 0.f};

    for (int k0 = 0; k0 < K; k0 += 64) {
        #pragma unroll
        for (int i = 0; i < 4; i++) {
            int ck = i * 256 + tid;
            int r = ck >> 3, cc = ck & 7;
            int csw = (cc ^ (r & 7)) << 3;
            async_lds16(A + (size_t)(m0 + r) * K + k0 + csw,
                        (void*)(sA + (i * 256 + (tid & ~63)) * 8));
            int rr = n0 + r; if (rr >= N) rr = N - 1;
            async_lds16(W + (size_t)rr * K + k0 + csw,
                        (void*)(sW + (i * 256 + (tid & ~63)) * 8));
        }
        __syncthreads();
        #pragma unroll
        for (int ks = 0; ks < 2; ks++) {
            bf16x8 af[4], wf[4];
            int kc = ks * 4 + quad;
            #pragma unroll
            for (int i = 0; i < 4; i++) {
                int r = wm + i * 16 + cl;
                af[i] = *(const bf16x8*)&sA[r * 64 + ((kc ^ (r & 7)) << 3)];
            }
            #pragma unroll
            for (int j = 0; j < 4; j++) {
                int r = wn + j * 16 + cl;
                wf[j] = *(const bf16x8*)&sW[r * 64 + ((kc ^ (r & 7)) << 3)];
            }
            #pragma unroll
            for (int i = 0; i < 4; i++)
                #pragma unroll
                for (int j = 0; j < 4; j++)
                    acc[i][j] = __builtin_amdgcn_mfma_f32_16x16x32_bf16(
                        af[i], wf[j], acc[i][j], 0, 0, 0);
        }
        __syncthreads();
    }
    if (blockIdx.x < 6) {
        #pragma unroll
        for (int i = 0; i < 4; i++) {
            int m = m0 + wm + i * 16 + quad * 4;
            #pragma unroll
            for (int j = 0; j < 4; j++) {
                int n = n0 + wn + j * 16 + cl;
                #pragma unroll
                for (int r = 0; r < 4; r++)
                    zx16[(size_t)(m + r) * 768 + n] = f2h(acc[i][j][r]);
            }
        }
    } else {
        // dt columns: n = 768 + cl for (wid&1)==0, j==0, cl<2
        if ((wid & 1) == 0 && cl < 2) {
            #pragma unroll
            for (int i = 0; i < 4; i++)
                #pragma unroll
                for (int r = 0; r < 4; r++)
                    sdt[cl][wm + i * 16 + quad * 4 + r] = acc[i][0][r];
        }
        __syncthreads();
        const int hh = tid >> 7, t = tid & 127;
        float raw = sdt[hh][t] + dt_bias[hh];
        float dt = fmaxf(raw, 0.f) + log1pf(__expf(-fabsf(raw)));
        dtb[(size_t)(m0 + t) * 2 + hh] = dt;
        float ad = -__expf(A_log[hh]) * dt;
        __syncthreads();
        sdt[hh][t] = ad;
        __syncthreads();
        for (int off = 1; off < 128; off <<= 1) {
            float add = (t >= off) ? sdt[hh][t - off] : 0.f;
            __syncthreads();
            sdt[hh][t] += add;
            __syncthreads();
        }
        Sb[(size_t)(m0 + t) * 2 + hh] = sdt[hh][t];
    }
}

// ---------------------------------------------------------------------------
// N=128 GEMM with fused residual + RMSNorm epilogue. Grid (1, 128).
// mode 0: v = acc+bias; xp=v; hbuf=v; hn = split(rms(v)*rmsw)
// mode 1: v = acc+hbuf;  hbuf=v;      hn = split(rms(v)*rmsw)
// mode 2: v = acc+hbuf;               hn = split(xp + rms(v)*rmsw)
// ---------------------------------------------------------------------------
__global__ __launch_bounds__(256) void gemm128_rms_kernel(
    const u16* __restrict__ A, const u16* __restrict__ W,
    const float* __restrict__ bias, const float* __restrict__ rmsw,
    float* __restrict__ xp, float* __restrict__ hbuf,
    u16* __restrict__ hn, int K, int mode)
{
    __shared__ u16 sA[128 * 64];
    __shared__ u16 sW[128 * 64];
    __shared__ float red[128][33];
    __shared__ float srstd[128];
    const int m0 = blockIdx.y * 128;
    const int tid = threadIdx.x, wid = tid >> 6, lane = tid & 63;
    const int wm = (wid >> 1) * 64, wn = (wid & 1) * 64;
    const int quad = lane >> 4, cl = lane & 15;
    f32x4 acc[4][4];
    #pragma unroll
    for (int i = 0; i < 4; i++)
        #pragma unroll
        for (int j = 0; j < 4; j++) acc[i][j] = f32x4{0.f, 0.f, 0.f, 0.f};

    for (int k0 = 0; k0 < K; k0 += 64) {
        #pragma unroll
        for (int i = 0; i < 4; i++) {
            int ck = i * 256 + tid;
            int r = ck >> 3, cc = ck & 7;
            int csw = (cc ^ (r & 7)) << 3;
            async_lds16(A + (size_t)(m0 + r) * K + k0 + csw,
                        (void*)(sA + (i * 256 + (tid & ~63)) * 8));
            async_lds16(W + (size_t)r * K + k0 + csw,
                        (void*)(sW + (i * 256 + (tid & ~63)) * 8));
        }
        __syncthreads();
        #pragma unroll
        for (int ks = 0; ks < 2; ks++) {
            bf16x8 af[4], wf[4];
            int kc = ks * 4 + quad;
            #pragma unroll
            for (int i = 0; i < 4; i++) {
                int r = wm + i * 16 + cl;
                af[i] = *(const bf16x8*)&sA[r * 64 + ((kc ^ (r & 7)) << 3)];
            }
            #pragma unroll
            for (int j = 0; j < 4; j++) {
                int r = wn + j * 16 + cl;
                wf[j] = *(const bf16x8*)&sW[r * 64 + ((kc ^ (r & 7)) << 3)];
            }
            #pragma unroll
            for (int i = 0; i < 4; i++)
                #pragma unroll
                for (int j = 0; j < 4; j++)
                    acc[i][j] = __builtin_amdgcn_mfma_f32_16x16x32_bf16(
                        af[i], wf[j], acc[i][j], 0, 0, 0);
        }
        __syncthreads();
    }
    // residual / bias; keep v in acc; partial sum-of-squares per owned row
    const int slot = (wid & 1) * 16 + cl;
    #pragma unroll
    for (int i = 0; i < 4; i++) {
        #pragma unroll
        for (int r = 0; r < 4; r++) {
            int t = wm + i * 16 + quad * 4 + r;
            size_t ob = (size_t)(m0 + t) * 128;
            float ssp = 0.f;
            #pragma unroll
            for (int j = 0; j < 4; j++) {
                int n = wn + j * 16 + cl;
                float v = acc[i][j][r];
                if (mode == 0) v += bias[n];
                else v += hbuf[ob + n];
                acc[i][j][r] = v;
                ssp += v * v;
            }
            red[t][slot] = ssp;
        }
    }
    __syncthreads();
    if (tid < 128) {
        float s = 0.f;
        #pragma unroll
        for (int sl = 0; sl < 32; sl++) s += red[tid][sl];
        srstd[tid] = rsqrtf(s * (1.f / 128.f) + 1e-5f);
    }
    __syncthreads();
    #pragma unroll
    for (int i = 0; i < 4; i++) {
        #pragma unroll
        for (int r = 0; r < 4; r++) {
            int t = wm + i * 16 + quad * 4 + r;
            size_t ob = (size_t)(m0 + t) * 128;
            u16* row = hn + (size_t)(m0 + t) * 384;
            float rstd = srstd[t];
            #pragma unroll
            for (int j = 0; j < 4; j++) {
                int n = wn + j * 16 + cl;
                float v = acc[i][j][r];
                if (mode == 0) { xp[ob + n] = v; hbuf[ob + n] = v; }
                else if (mode == 1) hbuf[ob + n] = v;
                float val = v * rstd * rmsw[n];
                if (mode == 2) val += xp[ob + n];
                u16 hi = f2b(val);
                u16 lo = f2b(val - b2f(hi));
                row[n] = hi; row[128 + n] = lo; row[256 + n] = hi;
            }
        }
    }
}

// ---------------------------------------------------------------------------
// Causal conv(4)+silu over 512 xBC channels (fp16 in, stride 768).
// Writes xc (fp16 [tok][512]), xT ([p][s] per chunk), bT (w_s-scaled B^T).
// Grid (256, 8), 256 thr.
// ---------------------------------------------------------------------------
__global__ __launch_bounds__(256) void conv_tile_kernel(
    const u16* __restrict__ zx16, const float* __restrict__ cw,
    const float* __restrict__ cb, const float* __restrict__ dtb,
    const float* __restrict__ Sb, u16* __restrict__ xc,
    u16* __restrict__ xT, u16* __restrict__ bT)
{
    __shared__ float sZ[67][68];
    __shared__ float sT[64][65];
    __shared__ float sw[2][64];
    const int tid = threadIdx.x;
    const int tok0 = blockIdx.x * 64;
    const int cg = blockIdx.y;
    const int cgb = cg * 64;
    const int l0 = tok0 & (LSEQ - 1);
    for (int idx = tid; idx < 67 * 16; idx += 256) {
        int row = idx >> 4, c4 = (idx & 15) * 4;
        int lr = l0 + row - 3;
        union { u16 u[4]; uint2 q; } ld;
        ld.q = make_uint2(0u, 0u);
        if (lr >= 0)
            ld.q = *(const uint2*)&zx16[(size_t)(tok0 + row - 3) * 768 + 256 + cgb + c4];
        #pragma unroll
        for (int j = 0; j < 4; j++) sZ[row][c4 + j] = h2f(ld.u[j]);
    }
    if ((cg == 4 || cg == 5) && tid < 128) {
        int hh = tid >> 6, j = tid & 63;
        int tokL = (tok0 & ~127) + 127;
        sw[hh][j] = __expf(Sb[(size_t)tokL * 2 + hh] - Sb[(size_t)(tok0 + j) * 2 + hh])
                    * dtb[(size_t)(tok0 + j) * 2 + hh];
    }
    const int ch = tid & 63;
    const int chg = cgb + ch;
    const float w0 = cw[chg * 4], w1 = cw[chg * 4 + 1];
    const float w2 = cw[chg * 4 + 2], w3 = cw[chg * 4 + 3];
    const float cbv = cb[chg];
    __syncthreads();
    #pragma unroll
    for (int k = 0; k < 16; k++) {
        int tokr = k * 4 + (tid >> 6);
        float a = cbv + sZ[tokr][ch] * w0 + sZ[tokr + 1][ch] * w1
                + sZ[tokr + 2][ch] * w2 + sZ[tokr + 3][ch] * w3;
        float v = silu_f(a);
        xc[(size_t)(tok0 + tokr) * 512 + chg] = f2h(v);
        sT[ch][tokr] = v;
    }
    __syncthreads();
    const int b = tok0 >> 12;
    const int c = (tok0 & (LSEQ - 1)) >> 7;
    const int s0 = tok0 & 127;
    if (cg < 4) {
        int hh = cg >> 1;
        int pbase = (cg & 1) * 64;
        u16* base = xT + (((size_t)((b * 2 + hh) * 32 + c)) << 14);
        for (int idx = tid; idx < 512; idx += 256) {
            int pr = idx >> 3, sc = (idx & 7) * 8;
            union { u16 u[8]; uint4 q; } pk;
            #pragma unroll
            for (int j = 0; j < 8; j++) pk.u[j] = f2h(sT[pr][sc + j]);
            *(uint4*)&base[(size_t)(pbase + pr) * 128 + s0 + sc] = pk.q;
        }
    } else if (cg < 6) {
        int nbase = (cg - 4) * 64;
        for (int hh = 0; hh < 2; hh++) {
            u16* base = bT + (((size_t)((b * 2 + hh) * 32 + c)) << 14);
            for (int idx = tid; idx < 512; idx += 256) {
                int nr = idx >> 3, sc = (idx & 7) * 8;
                union { u16 u[8]; uint4 q; } pk;
                #pragma unroll
                for (int j = 0; j < 8; j++)
                    pk.u[j] = f2h(sT[nr][sc + j] * sw[hh][sc + j]);
                *(uint4*)&base[(size_t)(nbase + nr) * 128 + s0 + sc] = pk.q;
            }
        }
    }
}

// ---------------------------------------------------------------------------
// Chunk-local end state via fp16 MFMA: Hloc[p,n] = sum_s X^T[p,s]*(w_s B)[s,n]
// ---------------------------------------------------------------------------
__global__ __launch_bounds__(256) void chunkstate_kernel(
    const u16* __restrict__ xT, const u16* __restrict__ bT,
    float* __restrict__ Hb)
{
    __shared__ u16 sX[128 * 128];
    __shared__ u16 sB[128 * 128];
    const int c = blockIdx.x, h = blockIdx.y, b = blockIdx.z;
    const int tid = threadIdx.x, wid = tid >> 6, lane = tid & 63;
    const size_t blk = ((size_t)((b * 2 + h) * 32 + c)) << 14;
    #pragma unroll
    for (int i = 0; i < 8; i++) {
        int ck = i * 256 + tid;
        int r = ck >> 4, cc = ck & 15;
        size_t g = (size_t)r * 128 + ((cc ^ (r & 15)) << 3);
        async_lds16(xT + blk + g, (void*)(sX + (i * 256 + (tid & ~63)) * 8));
        async_lds16(bT + blk + g, (void*)(sB + (i * 256 + (tid & ~63)) * 8));
    }
    __syncthreads();
    const int wm = (wid >> 1) * 64, wn = (wid & 1) * 64;
    const int quad = lane >> 4, cl = lane & 15;
    f32x4 acc[4][4];
    #pragma unroll
    for (int i = 0; i < 4; i++)
        #pragma unroll
        for (int j = 0; j < 4; j++) acc[i][j] = f32x4{0.f, 0.f, 0.f, 0.f};
    #pragma unroll
    for (int ks = 0; ks < 4; ks++) {
        f16x8 xa[4], bb[4];
        int kc = ks * 4 + quad;
        #pragma unroll
        for (int i = 0; i < 4; i++) {
            int r = wm + i * 16 + cl;
            xa[i] = *(const f16x8*)&sX[r * 128 + ((kc ^ (r & 15)) << 3)];
        }
        #pragma unroll
        for (int j = 0; j < 4; j++) {
            int r = wn + j * 16 + cl;
            bb[j] = *(const f16x8*)&sB[r * 128 + ((kc ^ (r & 15)) << 3)];
        }
        #pragma unroll
        for (int i = 0; i < 4; i++)
            #pragma unroll
            for (int j = 0; j < 4; j++)
                acc[i][j] = __builtin_amdgcn_mfma_f32_16x16x32_f16(
                    xa[i], bb[j], acc[i][j], 0, 0, 0);
    }
    float* out = Hb + blk;
    #pragma unroll
    for (int i = 0; i < 4; i++)
        #pragma unroll
        for (int j = 0; j < 4; j++)
            #pragma unroll
            for (int r = 0; r < 4; r++)
                out[(size_t)(wm + i * 16 + quad * 4 + r) * 128 + wn + j * 16 + cl]
                    = acc[i][j][r];
}

// ---------------------------------------------------------------------------
// Inter-chunk combine; writes INCOMING state per chunk as fp16.
// ---------------------------------------------------------------------------
__global__ __launch_bounds__(256) void statecombine_kernel(
    const float* __restrict__ Sb, const float* __restrict__ Hb,
    u16* __restrict__ Hbf)
{
    const int e = blockIdx.x * 256 + threadIdx.x;
    const int h = blockIdx.y, b = blockIdx.z;
    const size_t base = ((size_t)((b * 2 + h) * 32)) << 14;
    float state = 0.f;
    for (int c = 0; c < 32; c++) {
        size_t idx = base + ((size_t)c << 14) + e;
        float v = Hb[idx];
        Hbf[idx] = f2h(state);
        float dec = __expf(Sb[(size_t)(b * LSEQ + c * 128 + 127) * 2 + h]);
        state = dec * state + v;
    }
}

// ---------------------------------------------------------------------------
// Per-chunk output via fp16 MFMA, 3 GEMMs. Output y fp32.
// ---------------------------------------------------------------------------
__global__ __launch_bounds__(256) void ssd_output_kernel(
    const u16* __restrict__ xc, const u16* __restrict__ xT,
    const u16* __restrict__ Hbf, const float* __restrict__ dtb,
    const float* __restrict__ Sb, float* __restrict__ y)
{
    __shared__ u16 bufA[128 * 128];
    __shared__ u16 bufB[128 * 128];
    const int c = blockIdx.x, h = blockIdx.y, b = blockIdx.z;
    const int tid = threadIdx.x, wid = tid >> 6, lane = tid & 63;
    const int tok0 = b * LSEQ + c * 128;
    const size_t blk = ((size_t)((b * 2 + h) * 32 + c)) << 14;
    #pragma unroll
    for (int i = 0; i < 8; i++) {
        int ck = i * 256 + tid;
        int r = ck >> 4, cc = ck & 15;
        int csw = (cc ^ (r & 15)) << 3;
        async_lds16(xc + (size_t)(tok0 + r) * 512 + 384 + csw,
                    (void*)(bufA + (i * 256 + (tid & ~63)) * 8));
        async_lds16(Hbf + blk + (size_t)r * 128 + csw,
                    (void*)(bufB + (i * 256 + (tid & ~63)) * 8));
    }
    const int wm = (wid >> 1) * 64, wn = (wid & 1) * 64;
    const int quad = lane >> 4, cl = lane & 15;
    float St[16], Ss[4], dts[4];
    #pragma unroll
    for (int i = 0; i < 4; i++)
        #pragma unroll
        for (int r = 0; r < 4; r++)
            St[i * 4 + r] = Sb[(size_t)(tok0 + wm + i * 16 + quad * 4 + r) * 2 + h];
    #pragma unroll
    for (int j = 0; j < 4; j++) {
        int s = wn + j * 16 + cl;
        Ss[j] = Sb[(size_t)(tok0 + s) * 2 + h];
        dts[j] = dtb[(size_t)(tok0 + s) * 2 + h];
    }
    __syncthreads();
    f32x4 acc[4][4];
    #pragma unroll
    for (int i = 0; i < 4; i++)
        #pragma unroll
        for (int j = 0; j < 4; j++) acc[i][j] = f32x4{0.f, 0.f, 0.f, 0.f};
    // phase 1: C @ Hin^T, scaled by exp(S_t)
    #pragma unroll
    for (int ks = 0; ks < 4; ks++) {
        f16x8 ca[4], hb[4];
        int kc = ks * 4 + quad;
        #pragma unroll
        for (int i = 0; i < 4; i++) {
            int r = wm + i * 16 + cl;
            ca[i] = *(const f16x8*)&bufA[r * 128 + ((kc ^ (r & 15)) << 3)];
        }
        #pragma unroll
        for (int j = 0; j < 4; j++) {
            int r = wn + j * 16 + cl;
            hb[j] = *(const f16x8*)&bufB[r * 128 + ((kc ^ (r & 15)) << 3)];
        }
        #pragma unroll
        for (int i = 0; i < 4; i++)
            #pragma unroll
            for (int j = 0; j < 4; j++)
                acc[i][j] = __builtin_amdgcn_mfma_f32_16x16x32_f16(
                    ca[i], hb[j], acc[i][j], 0, 0, 0);
    }
    #pragma unroll
    for (int i = 0; i < 4; i++)
        #pragma unroll
        for (int r = 0; r < 4; r++) {
            float e = __expf(St[i * 4 + r]);
            #pragma unroll
            for (int j = 0; j < 4; j++) acc[i][j][r] *= e;
        }
    __syncthreads();
    // phase 2: stage B; S = C @ B^T
    #pragma unroll
    for (int i = 0; i < 8; i++) {
        int ck = i * 256 + tid;
        int r = ck >> 4, cc = ck & 15;
        int csw = (cc ^ (r & 15)) << 3;
        async_lds16(xc + (size_t)(tok0 + r) * 512 + 256 + csw,
                    (void*)(bufB + (i * 256 + (tid & ~63)) * 8));
    }
    __syncthreads();
    f32x4 sacc[4][4];
    #pragma unroll
    for (int i = 0; i < 4; i++)
        #pragma unroll
        for (int j = 0; j < 4; j++) sacc[i][j] = f32x4{0.f, 0.f, 0.f, 0.f};
    #pragma unroll
    for (int ks = 0; ks < 4; ks++) {
        f16x8 ca[4], bb[4];
        int kc = ks * 4 + quad;
        #pragma unroll
        for (int i = 0; i < 4; i++) {
            int r = wm + i * 16 + cl;
            ca[i] = *(const f16x8*)&bufA[r * 128 + ((kc ^ (r & 15)) << 3)];
        }
        #pragma unroll
        for (int j = 0; j < 4; j++) {
            int r = wn + j * 16 + cl;
            bb[j] = *(const f16x8*)&bufB[r * 128 + ((kc ^ (r & 15)) << 3)];
        }
        #pragma unroll
        for (int i = 0; i < 4; i++)
            #pragma unroll
            for (int j = 0; j < 4; j++)
                if (wm + i * 16 + 15 >= wn + j * 16)
                    sacc[i][j] = __builtin_amdgcn_mfma_f32_16x16x32_f16(
                        ca[i], bb[j], sacc[i][j], 0, 0, 0);
    }
    __syncthreads();
    // G = mask ∘ S ∘ exp(St-Ss) ∘ dt_s -> bufA ; stage X^T -> bufB
    #pragma unroll
    for (int i = 0; i < 8; i++) {
        int ck = i * 256 + tid;
        int r = ck >> 4, cc = ck & 15;
        int csw = (cc ^ (r & 15)) << 3;
        async_lds16(xT + blk + (size_t)r * 128 + csw,
                    (void*)(bufB + (i * 256 + (tid & ~63)) * 8));
    }
    #pragma unroll
    for (int i = 0; i < 4; i++)
        #pragma unroll
        for (int r = 0; r < 4; r++) {
            int t = wm + i * 16 + quad * 4 + r;
            float Stv = St[i * 4 + r];
            #pragma unroll
            for (int j = 0; j < 4; j++) {
                int s = wn + j * 16 + cl;
                float gv = 0.f;
                if (s <= t) gv = sacc[i][j][r] * __expf(Stv - Ss[j]) * dts[j];
                bufA[t * 128 + (((s >> 3) ^ (t & 15)) << 3) + (s & 7)] = f2h(gv);
            }
        }
    __syncthreads();
    // phase 3: Y += G @ X
    #pragma unroll
    for (int ks = 0; ks < 4; ks++) {
        f16x8 ga[4], xb[4];
        int kc = ks * 4 + quad;
        #pragma unroll
        for (int i = 0; i < 4; i++) {
            int r = wm + i * 16 + cl;
            ga[i] = *(const f16x8*)&bufA[r * 128 + ((kc ^ (r & 15)) << 3)];
        }
        #pragma unroll
        for (int j = 0; j < 4; j++) {
            int r = wn + j * 16 + cl;
            xb[j] = *(const f16x8*)&bufB[r * 128 + ((kc ^ (r & 15)) << 3)];
        }
        #pragma unroll
        for (int i = 0; i < 4; i++)
            #pragma unroll
            for (int j = 0; j < 4; j++)
                acc[i][j] = __builtin_amdgcn_mfma_f32_16x16x32_f16(
                    ga[i], xb[j], acc[i][j], 0, 0, 0);
    }
    #pragma unroll
    for (int i = 0; i < 4; i++)
        #pragma unroll
        for (int r = 0; r < 4; r++) {
            int t = wm + i * 16 + quad * 4 + r;
            #pragma unroll
            for (int j = 0; j < 4; j++) {
                int p = wn + j * 16 + cl;
                y[(size_t)(tok0 + t) * 256 + h * 128 + p] = acc[i][j][r];
            }
        }
}

// ---------------------------------------------------------------------------
// Gated RMSNorm (+ D-skip): g = (y + D*x)*silu(z); out = rms(g)*w
// -> split bf16 activation row [hi|lo|hi] stride 768.
// ---------------------------------------------------------------------------
__global__ __launch_bounds__(256) void gatenorm_kernel(
    const u16* __restrict__ zx16, const u16* __restrict__ xc,
    const float* __restrict__ gnw, const float* __restrict__ Dp,
    const float* __restrict__ y, u16* __restrict__ ysplit)
{
    const int tok = blockIdx.x, e = threadIdx.x;
    const int h = e >> 7;
    float yv = y[(size_t)tok * 256 + e] + Dp[h] * h2f(xc[(size_t)tok * 512 + e]);
    float zv = h2f(zx16[(size_t)tok * 768 + e]);
    float g = yv * silu_f(zv);
    float ss = g * g;
    #pragma unroll
    for (int o = 1; o < 64; o <<= 1) ss += __shfl_xor(ss, o);
    __shared__ float sred[4];
    if ((e & 63) == 0) sred[e >> 6] = ss;
    __syncthreads();
    float total = sred[0] + sred[1] + sred[2] + sred[3];
    float rstd = rsqrtf(total * (1.f / 256.f) + 1e-5f);
    float val = g * rstd * gnw[e];
    u16 hi = f2b(val);
    u16 lo = f2b(val - b2f(hi));
    u16* row = ysplit + (size_t)tok * 768;
    row[e] = hi; row[256 + e] = lo; row[512 + e] = hi;
}

// ---------------------------------------------------------------------------
extern "C" void kernel_launch(void* const* d_in, const int* in_sizes, int n_in,
                              void* d_out, int out_size, void* d_ws, size_t ws_size,
                              hipStream_t stream)
{
    (void)in_sizes; (void)n_in; (void)out_size; (void)ws_size;
    const float* x       = (const float*)d_in[0];
    const float* in_w    = (const float*)d_in[1];
    const float* in_b    = (const float*)d_in[2];
    const float* out_w   = (const float*)d_in[3];
    const float* out_b   = (const float*)d_in[4];
    const float* l_rms_w = (const float*)d_in[5];
    const float* l_in_w  = (const float*)d_in[6];
    const float* conv_w  = (const float*)d_in[7];
    const float* conv_b  = (const float*)d_in[8];
    const float* dt_bias = (const float*)d_in[9];
    const float* A_log   = (const float*)d_in[10];
    const float* D_p     = (const float*)d_in[11];
    const float* gnorm_w = (const float*)d_in[12];
    const float* l_out_w = (const float*)d_in[13];
    const float* fnorm_w = (const float*)d_in[14];

    char* w = (char*)d_ws;
    float* xp    = (float*)(w);                    // 8.39 MB
    float* hbuf  = (float*)(w + 8388608);          // 8.39 MB
    u16*   xspl  = (u16*)(w + 16777216);           // 6.29 MB (16384 x 192)
    u16*   hnspl = (u16*)(w + 23068672);           // 12.58 MB (16384 x 384)
    u16*   zx16  = (u16*)(w + 35651584);           // 25.17 MB (16384 x 768 fp16)
    float* dtb   = (float*)(w + 60817408);         // 131 KB
    float* Sb    = (float*)(w + 60948480);         // 131 KB
    float* Hb    = (float*)(w + 61079552);         // 16.78 MB fp32 chunk states
    float* yf32  = (float*)(w + 61079552);         //   alias Hb (dead by then)
    u16*   xc    = (u16*)(w + 77856768);           // 16.78 MB fp16
    u16*   xT    = (u16*)(w + 94633984);           // 8.39 MB fp16
    u16*   bT    = (u16*)(w + 103022592);          // 8.39 MB fp16
    u16*   Hbf   = (u16*)(w + 111411200);          // 8.39 MB fp16
    u16*   yspl  = xT;                             //   alias xT|bT|Hbf (25.17 MB)
    u16*   wspl  = (u16*)(w + 119799808);
    u16* in_w_s    = wspl;                           // 128 x 192
    u16* l_in_w_s  = wspl + 24576;                   // 1540 x 384
    u16* l_out_w_s = wspl + 24576 + 591360;          // 256 x 768
    u16* out_w_s   = wspl + 24576 + 591360 + 196608; // 64 x 384

    // one conversion kernel: x (activation split) + all weights (weight split)
    cvt_all_kernel<<<1297, 256, 0, stream>>>(
        x, xspl, in_w, in_w_s, l_in_w, l_in_w_s, l_out_w, l_out_w_s,
        out_w, out_w_s);

    // initial in-proj + fused RMS of layer 0 (mode 0)
    gemm128_rms_kernel<<<dim3(1, 128), 256, 0, stream>>>(
        xspl, in_w_s, in_b, l_rms_w, xp, hbuf, hnspl, 192, 0);

    for (int i = 0; i < 2; i++) {
        gemm_inproj_kernel<<<dim3(7, 128), 256, 0, stream>>>(
            hnspl, l_in_w_s + (size_t)i * 770 * 384, zx16, dtb, Sb,
            dt_bias + i * 2, A_log + i * 2);
        conv_tile_kernel<<<dim3(256, 8), 256, 0, stream>>>(
            zx16, conv_w + i * 2048, conv_b + i * 512, dtb, Sb, xc, xT, bT);
        chunkstate_kernel<<<dim3(32, 2, 4), 256, 0, stream>>>(xT, bT, Hb);
        statecombine_kernel<<<dim3(64, 2, 4), 256, 0, stream>>>(Sb, Hb, Hbf);
        ssd_output_kernel<<<dim3(32, 2, 4), 256, 0, stream>>>(
            xc, xT, Hbf, dtb, Sb, yf32);
        gatenorm_kernel<<<MTOK, 256, 0, stream>>>(
            zx16, xc, gnorm_w + i * 256, D_p + i * 2, yf32, yspl);
        // out-proj + residual + fused next norm:
        //   i==0 -> RMS with l_rms_w[1] (mode 1); i==1 -> final norm (mode 2)
        gemm128_rms_kernel<<<dim3(1, 128), 256, 0, stream>>>(
            yspl, l_out_w_s + (size_t)i * 128 * 768, nullptr,
            (i == 0) ? (l_rms_w + 128) : fnorm_w, xp, hbuf, hnspl, 768,
            (i == 0) ? 1 : 2);
    }

    // final projection (N=64)
    gemm_bf16_kernel<<<dim3(1, 128), 256, 0, stream>>>(
        hnspl, out_w_s, (float*)d_out, out_b, MTOK, 64, 384);
}

// Round 6
// 323.462 us; speedup vs baseline: 2.1893x; 1.0341x over previous
//
#include <hip/hip_runtime.h>
#include <cstddef>
#include <cstdint>

// MambaDoc — round 6:
//  * ssd_output + gatenorm fused into one kernel (both heads per block; G=1
//    means B/C shared across heads -> C@B^T computed once; gate+RMS in-block;
//    writes yspl directly). 512 thr, ~133 KB LDS, grid (32,4).
//  * N=128 fused-RMS GEMMs use BM=64 -> 256 blocks (full CU coverage).
//  * yspl aliases dead Hb|bT region. Projections split hi/lo bf16; SSD fp16.

#define LSEQ 4096
#define MTOK 16384

typedef unsigned short u16;
typedef __bf16 bf16_t;
typedef bf16_t bf16x8 __attribute__((ext_vector_type(8)));
typedef _Float16 f16x8 __attribute__((ext_vector_type(8)));
typedef float f32x4 __attribute__((ext_vector_type(4)));

__device__ __forceinline__ u16 f2b(float x) {
    return __builtin_bit_cast(u16, (bf16_t)x);
}
__device__ __forceinline__ float b2f(u16 u) {
    return (float)__builtin_bit_cast(bf16_t, u);
}
__device__ __forceinline__ u16 f2h(float x) {
    return __builtin_bit_cast(u16, (_Float16)x);
}
__device__ __forceinline__ float h2f(u16 u) {
    return (float)__builtin_bit_cast(_Float16, u);
}
__device__ __forceinline__ float silu_f(float x) { return x / (1.f + __expf(-x)); }

__device__ __forceinline__ void async_lds16(const void* g, void* l) {
    __builtin_amdgcn_global_load_lds(
        (const __attribute__((address_space(1))) unsigned int*)g,
        (__attribute__((address_space(3))) unsigned int*)l, 16, 0, 0);
}

// ---------------------------------------------------------------------------
// Combined fp32 -> split-bf16 conversion for x + all weights.
// mode 0 (activation): row = [hi | lo | hi]; mode 1 (weight): [hi | hi | lo].
// ---------------------------------------------------------------------------
__device__ __forceinline__ void split_store(
    const float* __restrict__ in, u16* __restrict__ out, int K, int g, int mode)
{
    int e0 = g * 4;
    int r = e0 / K, k = e0 - r * K;
    float4 v = *(const float4*)&in[(size_t)e0];
    float vv[4] = {v.x, v.y, v.z, v.w};
    union { u16 u[4]; uint2 q; } hi, lo;
    #pragma unroll
    for (int j = 0; j < 4; j++) {
        hi.u[j] = f2b(vv[j]);
        lo.u[j] = f2b(vv[j] - b2f(hi.u[j]));
    }
    u16* row = out + (size_t)r * 3 * K;
    *(uint2*)&row[k] = hi.q;
    if (mode == 0) {
        *(uint2*)&row[K + k] = lo.q;
        *(uint2*)&row[2 * K + k] = hi.q;
    } else {
        *(uint2*)&row[K + k] = hi.q;
        *(uint2*)&row[2 * K + k] = lo.q;
    }
}

__global__ __launch_bounds__(256) void cvt_all_kernel(
    const float* __restrict__ x, u16* __restrict__ xspl,
    const float* __restrict__ in_w, u16* __restrict__ in_w_s,
    const float* __restrict__ l_in_w, u16* __restrict__ l_in_w_s,
    const float* __restrict__ l_out_w, u16* __restrict__ l_out_w_s,
    const float* __restrict__ out_w, u16* __restrict__ out_w_s)
{
    int g = blockIdx.x * 256 + threadIdx.x;
    if (g < 262144) { split_store(x, xspl, 64, g, 0); return; }
    g -= 262144;
    if (g < 2048) { split_store(in_w, in_w_s, 64, g, 1); return; }
    g -= 2048;
    if (g < 49280) { split_store(l_in_w, l_in_w_s, 128, g, 1); return; }
    g -= 49280;
    if (g < 16384) { split_store(l_out_w, l_out_w_s, 256, g, 1); return; }
    g -= 16384;
    if (g < 2048) { split_store(out_w, out_w_s, 128, g, 1); return; }
}

// ---------------------------------------------------------------------------
// Generic bf16 MFMA GEMM (final 64-wide projection). BM=128, BN=128.
// ---------------------------------------------------------------------------
__global__ __launch_bounds__(256) void gemm_bf16_kernel(
    const u16* __restrict__ A, const u16* __restrict__ W,
    float* __restrict__ out, const float* __restrict__ bias,
    int M, int N, int K)
{
    __shared__ u16 sA[128 * 64];
    __shared__ u16 sW[128 * 64];
    const int n0 = blockIdx.x * 128, m0 = blockIdx.y * 128;
    const int tid = threadIdx.x, wid = tid >> 6, lane = tid & 63;
    const int wm = (wid >> 1) * 64, wn = (wid & 1) * 64;
    const int quad = lane >> 4, cl = lane & 15;
    f32x4 acc[4][4];
    #pragma unroll
    for (int i = 0; i < 4; i++)
        #pragma unroll
        for (int j = 0; j < 4; j++) acc[i][j] = f32x4{0.f, 0.f, 0.f, 0.f};

    for (int k0 = 0; k0 < K; k0 += 64) {
        #pragma unroll
        for (int i = 0; i < 4; i++) {
            int ck = i * 256 + tid;
            int r = ck >> 3, cc = ck & 7;
            int csw = (cc ^ (r & 7)) << 3;
            async_lds16(A + (size_t)(m0 + r) * K + k0 + csw,
                        (void*)(sA + (i * 256 + (tid & ~63)) * 8));
            int rr = n0 + r; if (rr >= N) rr = N - 1;
            async_lds16(W + (size_t)rr * K + k0 + csw,
                        (void*)(sW + (i * 256 + (tid & ~63)) * 8));
        }
        __syncthreads();
        #pragma unroll
        for (int ks = 0; ks < 2; ks++) {
            bf16x8 af[4], wf[4];
            int kc = ks * 4 + quad;
            #pragma unroll
            for (int i = 0; i < 4; i++) {
                int r = wm + i * 16 + cl;
                af[i] = *(const bf16x8*)&sA[r * 64 + ((kc ^ (r & 7)) << 3)];
            }
            #pragma unroll
            for (int j = 0; j < 4; j++) {
                int r = wn + j * 16 + cl;
                wf[j] = *(const bf16x8*)&sW[r * 64 + ((kc ^ (r & 7)) << 3)];
            }
            #pragma unroll
            for (int i = 0; i < 4; i++)
                #pragma unroll
                for (int j = 0; j < 4; j++)
                    acc[i][j] = __builtin_amdgcn_mfma_f32_16x16x32_bf16(
                        af[i], wf[j], acc[i][j], 0, 0, 0);
        }
        __syncthreads();
    }
    #pragma unroll
    for (int i = 0; i < 4; i++) {
        int m = m0 + wm + i * 16 + quad * 4;
        #pragma unroll
        for (int j = 0; j < 4; j++) {
            int n = n0 + wn + j * 16 + cl;
            if (n < N) {
                float bv = bias ? bias[n] : 0.f;
                #pragma unroll
                for (int r = 0; r < 4; r++)
                    out[(size_t)(m + r) * N + n] = acc[i][j][r] + bv;
            }
        }
    }
}

// ---------------------------------------------------------------------------
// in_proj GEMM (BM=128): blocks x<6 write zx fp16 (stride 768); block x==6
// does dt softplus + chunk-local cumsum -> dtb, Sb. Grid (7, 128).
// ---------------------------------------------------------------------------
__global__ __launch_bounds__(256) void gemm_inproj_kernel(
    const u16* __restrict__ A, const u16* __restrict__ W,
    u16* __restrict__ zx16, float* __restrict__ dtb, float* __restrict__ Sb,
    const float* __restrict__ dt_bias, const float* __restrict__ A_log)
{
    __shared__ u16 sA[128 * 64];
    __shared__ u16 sW[128 * 64];
    __shared__ float sdt[2][128];
    const int K = 384, N = 770;
    const int n0 = blockIdx.x * 128, m0 = blockIdx.y * 128;
    const int tid = threadIdx.x, wid = tid >> 6, lane = tid & 63;
    const int wm = (wid >> 1) * 64, wn = (wid & 1) * 64;
    const int quad = lane >> 4, cl = lane & 15;
    f32x4 acc[4][4];
    #pragma unroll
    for (int i = 0; i < 4; i++)
        #pragma unroll
        for (int j = 0; j < 4; j++) acc[i][j] = f32x4{0.f, 0.f, 0.f, 0.f};

    for (int k0 = 0; k0 < K; k0 += 64) {
        #pragma unroll
        for (int i = 0; i < 4; i++) {
            int ck = i * 256 + tid;
            int r = ck >> 3, cc = ck & 7;
            int csw = (cc ^ (r & 7)) << 3;
            async_lds16(A + (size_t)(m0 + r) * K + k0 + csw,
                        (void*)(sA + (i * 256 + (tid & ~63)) * 8));
            int rr = n0 + r; if (rr >= N) rr = N - 1;
            async_lds16(W + (size_t)rr * K + k0 + csw,
                        (void*)(sW + (i * 256 + (tid & ~63)) * 8));
        }
        __syncthreads();
        #pragma unroll
        for (int ks = 0; ks < 2; ks++) {
            bf16x8 af[4], wf[4];
            int kc = ks * 4 + quad;
            #pragma unroll
            for (int i = 0; i < 4; i++) {
                int r = wm + i * 16 + cl;
                af[i] = *(const bf16x8*)&sA[r * 64 + ((kc ^ (r & 7)) << 3)];
            }
            #pragma unroll
            for (int j = 0; j < 4; j++) {
                int r = wn + j * 16 + cl;
                wf[j] = *(const bf16x8*)&sW[r * 64 + ((kc ^ (r & 7)) << 3)];
            }
            #pragma unroll
            for (int i = 0; i < 4; i++)
                #pragma unroll
                for (int j = 0; j < 4; j++)
                    acc[i][j] = __builtin_amdgcn_mfma_f32_16x16x32_bf16(
                        af[i], wf[j], acc[i][j], 0, 0, 0);
        }
        __syncthreads();
    }
    if (blockIdx.x < 6) {
        #pragma unroll
        for (int i = 0; i < 4; i++) {
            int m = m0 + wm + i * 16 + quad * 4;
            #pragma unroll
            for (int j = 0; j < 4; j++) {
                int n = n0 + wn + j * 16 + cl;
                #pragma unroll
                for (int r = 0; r < 4; r++)
                    zx16[(size_t)(m + r) * 768 + n] = f2h(acc[i][j][r]);
            }
        }
    } else {
        if ((wid & 1) == 0 && cl < 2) {
            #pragma unroll
            for (int i = 0; i < 4; i++)
                #pragma unroll
                for (int r = 0; r < 4; r++)
                    sdt[cl][wm + i * 16 + quad * 4 + r] = acc[i][0][r];
        }
        __syncthreads();
        const int hh = tid >> 7, t = tid & 127;
        float raw = sdt[hh][t] + dt_bias[hh];
        float dt = fmaxf(raw, 0.f) + log1pf(__expf(-fabsf(raw)));
        dtb[(size_t)(m0 + t) * 2 + hh] = dt;
        float ad = -__expf(A_log[hh]) * dt;
        __syncthreads();
        sdt[hh][t] = ad;
        __syncthreads();
        for (int off = 1; off < 128; off <<= 1) {
            float add = (t >= off) ? sdt[hh][t - off] : 0.f;
            __syncthreads();
            sdt[hh][t] += add;
            __syncthreads();
        }
        Sb[(size_t)(m0 + t) * 2 + hh] = sdt[hh][t];
    }
}

// ---------------------------------------------------------------------------
// N=128 GEMM (BM=64) with fused residual + RMSNorm epilogue. Grid (1, 256).
// mode 0: v = acc+bias; xp=v; hbuf=v; hn = split(rms(v)*rmsw)
// mode 1: v = acc+hbuf;  hbuf=v;      hn = split(rms(v)*rmsw)
// mode 2: v = acc+hbuf;               hn = split(xp + rms(v)*rmsw)
// ---------------------------------------------------------------------------
__global__ __launch_bounds__(256) void gemm128_rms_kernel(
    const u16* __restrict__ A, const u16* __restrict__ W,
    const float* __restrict__ bias, const float* __restrict__ rmsw,
    float* __restrict__ xp, float* __restrict__ hbuf,
    u16* __restrict__ hn, int K, int mode)
{
    __shared__ u16 sA[64 * 64];
    __shared__ u16 sW[128 * 64];
    __shared__ float red[64][33];
    __shared__ float srstd[64];
    const int m0 = blockIdx.y * 64;
    const int tid = threadIdx.x, wid = tid >> 6, lane = tid & 63;
    const int wm = (wid >> 1) * 32, wn = (wid & 1) * 64;
    const int quad = lane >> 4, cl = lane & 15;
    f32x4 acc[2][4];
    #pragma unroll
    for (int i = 0; i < 2; i++)
        #pragma unroll
        for (int j = 0; j < 4; j++) acc[i][j] = f32x4{0.f, 0.f, 0.f, 0.f};

    for (int k0 = 0; k0 < K; k0 += 64) {
        #pragma unroll
        for (int i = 0; i < 2; i++) {
            int ck = i * 256 + tid;
            int r = ck >> 3, cc = ck & 7;
            int csw = (cc ^ (r & 7)) << 3;
            async_lds16(A + (size_t)(m0 + r) * K + k0 + csw,
                        (void*)(sA + (i * 256 + (tid & ~63)) * 8));
        }
        #pragma unroll
        for (int i = 0; i < 4; i++) {
            int ck = i * 256 + tid;
            int r = ck >> 3, cc = ck & 7;
            int csw = (cc ^ (r & 7)) << 3;
            async_lds16(W + (size_t)r * K + k0 + csw,
                        (void*)(sW + (i * 256 + (tid & ~63)) * 8));
        }
        __syncthreads();
        #pragma unroll
        for (int ks = 0; ks < 2; ks++) {
            bf16x8 af[2], wf[4];
            int kc = ks * 4 + quad;
            #pragma unroll
            for (int i = 0; i < 2; i++) {
                int r = wm + i * 16 + cl;
                af[i] = *(const bf16x8*)&sA[r * 64 + ((kc ^ (r & 7)) << 3)];
            }
            #pragma unroll
            for (int j = 0; j < 4; j++) {
                int r = wn + j * 16 + cl;
                wf[j] = *(const bf16x8*)&sW[r * 64 + ((kc ^ (r & 7)) << 3)];
            }
            #pragma unroll
            for (int i = 0; i < 2; i++)
                #pragma unroll
                for (int j = 0; j < 4; j++)
                    acc[i][j] = __builtin_amdgcn_mfma_f32_16x16x32_bf16(
                        af[i], wf[j], acc[i][j], 0, 0, 0);
        }
        __syncthreads();
    }
    const int slot = (wid & 1) * 16 + cl;
    #pragma unroll
    for (int i = 0; i < 2; i++) {
        #pragma unroll
        for (int r = 0; r < 4; r++) {
            int t = wm + i * 16 + quad * 4 + r;
            size_t ob = (size_t)(m0 + t) * 128;
            float ssp = 0.f;
            #pragma unroll
            for (int j = 0; j < 4; j++) {
                int n = wn + j * 16 + cl;
                float v = acc[i][j][r];
                if (mode == 0) v += bias[n];
                else v += hbuf[ob + n];
                acc[i][j][r] = v;
                ssp += v * v;
            }
            red[t][slot] = ssp;
        }
    }
    __syncthreads();
    if (tid < 64) {
        float s = 0.f;
        #pragma unroll
        for (int sl = 0; sl < 32; sl++) s += red[tid][sl];
        srstd[tid] = rsqrtf(s * (1.f / 128.f) + 1e-5f);
    }
    __syncthreads();
    #pragma unroll
    for (int i = 0; i < 2; i++) {
        #pragma unroll
        for (int r = 0; r < 4; r++) {
            int t = wm + i * 16 + quad * 4 + r;
            size_t ob = (size_t)(m0 + t) * 128;
            u16* row = hn + (size_t)(m0 + t) * 384;
            float rstd = srstd[t];
            #pragma unroll
            for (int j = 0; j < 4; j++) {
                int n = wn + j * 16 + cl;
                float v = acc[i][j][r];
                if (mode == 0) { xp[ob + n] = v; hbuf[ob + n] = v; }
                else if (mode == 1) hbuf[ob + n] = v;
                float val = v * rstd * rmsw[n];
                if (mode == 2) val += xp[ob + n];
                u16 hi = f2b(val);
                u16 lo = f2b(val - b2f(hi));
                row[n] = hi; row[128 + n] = lo; row[256 + n] = hi;
            }
        }
    }
}

// ---------------------------------------------------------------------------
// Causal conv(4)+silu over 512 xBC channels (fp16 in, stride 768).
// Writes xc (fp16 [tok][512]), xT ([p][s] per chunk), bT (w_s-scaled B^T).
// Grid (256, 8), 256 thr.
// ---------------------------------------------------------------------------
__global__ __launch_bounds__(256) void conv_tile_kernel(
    const u16* __restrict__ zx16, const float* __restrict__ cw,
    const float* __restrict__ cb, const float* __restrict__ dtb,
    const float* __restrict__ Sb, u16* __restrict__ xc,
    u16* __restrict__ xT, u16* __restrict__ bT)
{
    __shared__ float sZ[67][68];
    __shared__ float sT[64][65];
    __shared__ float sw[2][64];
    const int tid = threadIdx.x;
    const int tok0 = blockIdx.x * 64;
    const int cg = blockIdx.y;
    const int cgb = cg * 64;
    const int l0 = tok0 & (LSEQ - 1);
    for (int idx = tid; idx < 67 * 16; idx += 256) {
        int row = idx >> 4, c4 = (idx & 15) * 4;
        int lr = l0 + row - 3;
        union { u16 u[4]; uint2 q; } ld;
        ld.q = make_uint2(0u, 0u);
        if (lr >= 0)
            ld.q = *(const uint2*)&zx16[(size_t)(tok0 + row - 3) * 768 + 256 + cgb + c4];
        #pragma unroll
        for (int j = 0; j < 4; j++) sZ[row][c4 + j] = h2f(ld.u[j]);
    }
    if ((cg == 4 || cg == 5) && tid < 128) {
        int hh = tid >> 6, j = tid & 63;
        int tokL = (tok0 & ~127) + 127;
        sw[hh][j] = __expf(Sb[(size_t)tokL * 2 + hh] - Sb[(size_t)(tok0 + j) * 2 + hh])
                    * dtb[(size_t)(tok0 + j) * 2 + hh];
    }
    const int ch = tid & 63;
    const int chg = cgb + ch;
    const float w0 = cw[chg * 4], w1 = cw[chg * 4 + 1];
    const float w2 = cw[chg * 4 + 2], w3 = cw[chg * 4 + 3];
    const float cbv = cb[chg];
    __syncthreads();
    #pragma unroll
    for (int k = 0; k < 16; k++) {
        int tokr = k * 4 + (tid >> 6);
        float a = cbv + sZ[tokr][ch] * w0 + sZ[tokr + 1][ch] * w1
                + sZ[tokr + 2][ch] * w2 + sZ[tokr + 3][ch] * w3;
        float v = silu_f(a);
        xc[(size_t)(tok0 + tokr) * 512 + chg] = f2h(v);
        sT[ch][tokr] = v;
    }
    __syncthreads();
    const int b = tok0 >> 12;
    const int c = (tok0 & (LSEQ - 1)) >> 7;
    const int s0 = tok0 & 127;
    if (cg < 4) {
        int hh = cg >> 1;
        int pbase = (cg & 1) * 64;
        u16* base = xT + (((size_t)((b * 2 + hh) * 32 + c)) << 14);
        for (int idx = tid; idx < 512; idx += 256) {
            int pr = idx >> 3, sc = (idx & 7) * 8;
            union { u16 u[8]; uint4 q; } pk;
            #pragma unroll
            for (int j = 0; j < 8; j++) pk.u[j] = f2h(sT[pr][sc + j]);
            *(uint4*)&base[(size_t)(pbase + pr) * 128 + s0 + sc] = pk.q;
        }
    } else if (cg < 6) {
        int nbase = (cg - 4) * 64;
        for (int hh = 0; hh < 2; hh++) {
            u16* base = bT + (((size_t)((b * 2 + hh) * 32 + c)) << 14);
            for (int idx = tid; idx < 512; idx += 256) {
                int nr = idx >> 3, sc = (idx & 7) * 8;
                union { u16 u[8]; uint4 q; } pk;
                #pragma unroll
                for (int j = 0; j < 8; j++)
                    pk.u[j] = f2h(sT[nr][sc + j] * sw[hh][sc + j]);
                *(uint4*)&base[(size_t)(nbase + nr) * 128 + s0 + sc] = pk.q;
            }
        }
    }
}

// ---------------------------------------------------------------------------
// Chunk-local end state via fp16 MFMA: Hloc[p,n] = sum_s X^T[p,s]*(w_s B)[s,n]
// ---------------------------------------------------------------------------
__global__ __launch_bounds__(256) void chunkstate_kernel(
    const u16* __restrict__ xT, const u16* __restrict__ bT,
    float* __restrict__ Hb)
{
    __shared__ u16 sX[128 * 128];
    __shared__ u16 sB[128 * 128];
    const int c = blockIdx.x, h = blockIdx.y, b = blockIdx.z;
    const int tid = threadIdx.x, wid = tid >> 6, lane = tid & 63;
    const size_t blk = ((size_t)((b * 2 + h) * 32 + c)) << 14;
    #pragma unroll
    for (int i = 0; i < 8; i++) {
        int ck = i * 256 + tid;
        int r = ck >> 4, cc = ck & 15;
        size_t g = (size_t)r * 128 + ((cc ^ (r & 15)) << 3);
        async_lds16(xT + blk + g, (void*)(sX + (i * 256 + (tid & ~63)) * 8));
        async_lds16(bT + blk + g, (void*)(sB + (i * 256 + (tid & ~63)) * 8));
    }
    __syncthreads();
    const int wm = (wid >> 1) * 64, wn = (wid & 1) * 64;
    const int quad = lane >> 4, cl = lane & 15;
    f32x4 acc[4][4];
    #pragma unroll
    for (int i = 0; i < 4; i++)
        #pragma unroll
        for (int j = 0; j < 4; j++) acc[i][j] = f32x4{0.f, 0.f, 0.f, 0.f};
    #pragma unroll
    for (int ks = 0; ks < 4; ks++) {
        f16x8 xa[4], bb[4];
        int kc = ks * 4 + quad;
        #pragma unroll
        for (int i = 0; i < 4; i++) {
            int r = wm + i * 16 + cl;
            xa[i] = *(const f16x8*)&sX[r * 128 + ((kc ^ (r & 15)) << 3)];
        }
        #pragma unroll
        for (int j = 0; j < 4; j++) {
            int r = wn + j * 16 + cl;
            bb[j] = *(const f16x8*)&sB[r * 128 + ((kc ^ (r & 15)) << 3)];
        }
        #pragma unroll
        for (int i = 0; i < 4; i++)
            #pragma unroll
            for (int j = 0; j < 4; j++)
                acc[i][j] = __builtin_amdgcn_mfma_f32_16x16x32_f16(
                    xa[i], bb[j], acc[i][j], 0, 0, 0);
    }
    float* out = Hb + blk;
    #pragma unroll
    for (int i = 0; i < 4; i++)
        #pragma unroll
        for (int j = 0; j < 4; j++)
            #pragma unroll
            for (int r = 0; r < 4; r++)
                out[(size_t)(wm + i * 16 + quad * 4 + r) * 128 + wn + j * 16 + cl]
                    = acc[i][j][r];
}

// ---------------------------------------------------------------------------
// Inter-chunk combine; writes INCOMING state per chunk as fp16.
// ---------------------------------------------------------------------------
__global__ __launch_bounds__(256) void statecombine_kernel(
    const float* __restrict__ Sb, const float* __restrict__ Hb,
    u16* __restrict__ Hbf)
{
    const int e = blockIdx.x * 256 + threadIdx.x;
    const int h = blockIdx.y, b = blockIdx.z;
    const size_t base = ((size_t)((b * 2 + h) * 32)) << 14;
    float state = 0.f;
    for (int c = 0; c < 32; c++) {
        size_t idx = base + ((size_t)c << 14) + e;
        float v = Hb[idx];
        Hbf[idx] = f2h(state);
        float dec = __expf(Sb[(size_t)(b * LSEQ + c * 128 + 127) * 2 + h]);
        state = dec * state + v;
    }
}

// ---------------------------------------------------------------------------
// Fused SSD output + D-skip + silu gate + 256-ch RMSNorm, both heads/block.
// G=1: B and C shared across heads -> C@B^T computed once.
// Grid (32, 4), 512 threads, ~133 KB LDS (1 block/CU, 8 waves).
// ---------------------------------------------------------------------------
__global__ __launch_bounds__(512, 2) void ssd_fused_kernel(
    const u16* __restrict__ xc, const u16* __restrict__ xT,
    const u16* __restrict__ Hbf, const float* __restrict__ dtb,
    const float* __restrict__ Sb, const u16* __restrict__ zx16,
    const float* __restrict__ gnw, const float* __restrict__ Dp,
    u16* __restrict__ ysplit)
{
    __shared__ u16 bufCW[2][128 * 128];  // [0]=C -> G0, [1]=B -> G1
    __shared__ u16 bufH[2][128 * 128];   // [h]=Hin_h -> X_h
    __shared__ float sS[2][128], sdt[2][128];
    __shared__ float red[128][5];
    __shared__ float srstd[128];
    const int c = blockIdx.x, b = blockIdx.y;
    const int tid = threadIdx.x, wid = tid >> 6, lane = tid & 63;
    const int quad = lane >> 4, cl = lane & 15;
    const int tok0 = b * LSEQ + c * 128;
    const size_t blk0 = ((size_t)((b * 2 + 0) * 32 + c)) << 14;
    const size_t blk1 = ((size_t)((b * 2 + 1) * 32 + c)) << 14;
    // stage C, B, Hin0, Hin1
    #pragma unroll
    for (int i = 0; i < 4; i++) {
        int ck = i * 512 + tid;
        int r = ck >> 4, cc = ck & 15;
        int csw = (cc ^ (r & 15)) << 3;
        int ldst = (i * 512 + (tid & ~63)) * 8;
        async_lds16(xc + (size_t)(tok0 + r) * 512 + 384 + csw, (void*)(&bufCW[0][0] + ldst));
        async_lds16(xc + (size_t)(tok0 + r) * 512 + 256 + csw, (void*)(&bufCW[1][0] + ldst));
        async_lds16(Hbf + blk0 + (size_t)r * 128 + csw, (void*)(&bufH[0][0] + ldst));
        async_lds16(Hbf + blk1 + (size_t)r * 128 + csw, (void*)(&bufH[1][0] + ldst));
    }
    if (tid < 256) {
        int hh = tid >> 7, t = tid & 127;
        sS[hh][t] = Sb[(size_t)(tok0 + t) * 2 + hh];
        sdt[hh][t] = dtb[(size_t)(tok0 + t) * 2 + hh];
    }
    __syncthreads();
    // ---- phase 1: Y_h = C @ Hin_h^T (waves 0-3: h=0; 4-7: h=1)
    const int h = wid >> 2, w2 = wid & 3;
    const int wm = (w2 >> 1) * 64, wn = (w2 & 1) * 64;
    f32x4 acc[4][4];
    #pragma unroll
    for (int i = 0; i < 4; i++)
        #pragma unroll
        for (int j = 0; j < 4; j++) acc[i][j] = f32x4{0.f, 0.f, 0.f, 0.f};
    #pragma unroll
    for (int ks = 0; ks < 4; ks++) {
        f16x8 ca[4], hb[4];
        int kc = ks * 4 + quad;
        #pragma unroll
        for (int i = 0; i < 4; i++) {
            int r = wm + i * 16 + cl;
            ca[i] = *(const f16x8*)&bufCW[0][r * 128 + ((kc ^ (r & 15)) << 3)];
        }
        #pragma unroll
        for (int j = 0; j < 4; j++) {
            int r = wn + j * 16 + cl;
            hb[j] = *(const f16x8*)&bufH[h][r * 128 + ((kc ^ (r & 15)) << 3)];
        }
        #pragma unroll
        for (int i = 0; i < 4; i++)
            #pragma unroll
            for (int j = 0; j < 4; j++)
                acc[i][j] = __builtin_amdgcn_mfma_f32_16x16x32_f16(
                    ca[i], hb[j], acc[i][j], 0, 0, 0);
    }
    #pragma unroll
    for (int i = 0; i < 4; i++)
        #pragma unroll
        for (int r = 0; r < 4; r++) {
            float e = __expf(sS[h][wm + i * 16 + quad * 4 + r]);
            #pragma unroll
            for (int j = 0; j < 4; j++) acc[i][j][r] *= e;
        }
    // ---- phase 2: S = C @ B^T (all 8 waves; 32x64 tiles)
    const int sm0 = (wid >> 1) * 32, sn0 = (wid & 1) * 64;
    f32x4 sacc[2][4];
    #pragma unroll
    for (int i = 0; i < 2; i++)
        #pragma unroll
        for (int j = 0; j < 4; j++) sacc[i][j] = f32x4{0.f, 0.f, 0.f, 0.f};
    #pragma unroll
    for (int ks = 0; ks < 4; ks++) {
        f16x8 cs[2], bs[4];
        int kc = ks * 4 + quad;
        #pragma unroll
        for (int i2 = 0; i2 < 2; i2++) {
            int r = sm0 + i2 * 16 + cl;
            cs[i2] = *(const f16x8*)&bufCW[0][r * 128 + ((kc ^ (r & 15)) << 3)];
        }
        #pragma unroll
        for (int j = 0; j < 4; j++) {
            int r = sn0 + j * 16 + cl;
            bs[j] = *(const f16x8*)&bufCW[1][r * 128 + ((kc ^ (r & 15)) << 3)];
        }
        #pragma unroll
        for (int i2 = 0; i2 < 2; i2++)
            #pragma unroll
            for (int j = 0; j < 4; j++)
                if (sm0 + i2 * 16 + 15 >= sn0 + j * 16)
                    sacc[i2][j] = __builtin_amdgcn_mfma_f32_16x16x32_f16(
                        cs[i2], bs[j], sacc[i2][j], 0, 0, 0);
    }
    __syncthreads();   // all reads of C, B, Hin done
    // stage X0, X1 (async) over bufH while computing/writing G
    #pragma unroll
    for (int i = 0; i < 4; i++) {
        int ck = i * 512 + tid;
        int r = ck >> 4, cc = ck & 15;
        int csw = (cc ^ (r & 15)) << 3;
        int ldst = (i * 512 + (tid & ~63)) * 8;
        async_lds16(xT + blk0 + (size_t)r * 128 + csw, (void*)(&bufH[0][0] + ldst));
        async_lds16(xT + blk1 + (size_t)r * 128 + csw, (void*)(&bufH[1][0] + ldst));
    }
    // G_h = mask ∘ S ∘ exp(St-Ss) ∘ dt_s  -> bufCW[h] (swizzled)
    #pragma unroll
    for (int hh = 0; hh < 2; hh++)
        #pragma unroll
        for (int i2 = 0; i2 < 2; i2++)
            #pragma unroll
            for (int r = 0; r < 4; r++) {
                int t = sm0 + i2 * 16 + quad * 4 + r;
                float Stv = sS[hh][t];
                #pragma unroll
                for (int j = 0; j < 4; j++) {
                    int s = sn0 + j * 16 + cl;
                    float gv = 0.f;
                    if (s <= t)
                        gv = sacc[i2][j][r] * __expf(Stv - sS[hh][s]) * sdt[hh][s];
                    bufCW[hh][t * 128 + (((s >> 3) ^ (t & 15)) << 3) + (s & 7)] = f2h(gv);
                }
            }
    __syncthreads();
    // ---- phase 3: Y_h += G_h @ X_h
    #pragma unroll
    for (int ks = 0; ks < 4; ks++) {
        f16x8 ga[4], xb[4];
        int kc = ks * 4 + quad;
        #pragma unroll
        for (int i = 0; i < 4; i++) {
            int r = wm + i * 16 + cl;
            ga[i] = *(const f16x8*)&bufCW[h][r * 128 + ((kc ^ (r & 15)) << 3)];
        }
        #pragma unroll
        for (int j = 0; j < 4; j++) {
            int r = wn + j * 16 + cl;
            xb[j] = *(const f16x8*)&bufH[h][r * 128 + ((kc ^ (r & 15)) << 3)];
        }
        #pragma unroll
        for (int i = 0; i < 4; i++)
            #pragma unroll
            for (int j = 0; j < 4; j++)
                acc[i][j] = __builtin_amdgcn_mfma_f32_16x16x32_f16(
                    ga[i], xb[j], acc[i][j], 0, 0, 0);
    }
    // ---- epilogue: D-skip + silu gate, per-token sum of squares
    const float dco = Dp[h];
    #pragma unroll
    for (int i = 0; i < 4; i++)
        #pragma unroll
        for (int r = 0; r < 4; r++) {
            int t = wm + i * 16 + quad * 4 + r;
            float ssp = 0.f;
            #pragma unroll
            for (int j = 0; j < 4; j++) {
                int p = wn + j * 16 + cl;
                float xv = h2f(bufH[h][p * 128 + (((t >> 3) ^ (p & 15)) << 3) + (t & 7)]);
                float zv = h2f(zx16[(size_t)(tok0 + t) * 768 + h * 128 + p]);
                float g = (acc[i][j][r] + dco * xv) * silu_f(zv);
                acc[i][j][r] = g;
                ssp += g * g;
            }
            ssp += __shfl_xor(ssp, 1);
            ssp += __shfl_xor(ssp, 2);
            ssp += __shfl_xor(ssp, 4);
            ssp += __shfl_xor(ssp, 8);
            if (cl == 0) red[t][h * 2 + (wn >> 6)] = ssp;
        }
    __syncthreads();
    if (tid < 128)
        srstd[tid] = rsqrtf((red[tid][0] + red[tid][1] + red[tid][2] + red[tid][3])
                            * (1.f / 256.f) + 1e-5f);
    __syncthreads();
    #pragma unroll
    for (int i = 0; i < 4; i++)
        #pragma unroll
        for (int r = 0; r < 4; r++) {
            int t = wm + i * 16 + quad * 4 + r;
            float rstd = srstd[t];
            u16* row = ysplit + (size_t)(tok0 + t) * 768;
            #pragma unroll
            for (int j = 0; j < 4; j++) {
                int p = wn + j * 16 + cl;
                int e = h * 128 + p;
                float val = acc[i][j][r] * rstd * gnw[e];
                u16 hi = f2b(val);
                u16 lo = f2b(val - b2f(hi));
                row[e] = hi; row[256 + e] = lo; row[512 + e] = hi;
            }
        }
}

// ---------------------------------------------------------------------------
extern "C" void kernel_launch(void* const* d_in, const int* in_sizes, int n_in,
                              void* d_out, int out_size, void* d_ws, size_t ws_size,
                              hipStream_t stream)
{
    (void)in_sizes; (void)n_in; (void)out_size; (void)ws_size;
    const float* x       = (const float*)d_in[0];
    const float* in_w    = (const float*)d_in[1];
    const float* in_b    = (const float*)d_in[2];
    const float* out_w   = (const float*)d_in[3];
    const float* out_b   = (const float*)d_in[4];
    const float* l_rms_w = (const float*)d_in[5];
    const float* l_in_w  = (const float*)d_in[6];
    const float* conv_w  = (const float*)d_in[7];
    const float* conv_b  = (const float*)d_in[8];
    const float* dt_bias = (const float*)d_in[9];
    const float* A_log   = (const float*)d_in[10];
    const float* D_p     = (const float*)d_in[11];
    const float* gnorm_w = (const float*)d_in[12];
    const float* l_out_w = (const float*)d_in[13];
    const float* fnorm_w = (const float*)d_in[14];

    char* w = (char*)d_ws;
    float* xp    = (float*)(w);                    // 8.39 MB
    float* hbuf  = (float*)(w + 8388608);          // 8.39 MB
    u16*   xspl  = (u16*)(w + 16777216);           // 6.29 MB
    u16*   hnspl = (u16*)(w + 23068672);           // 12.58 MB
    u16*   zx16  = (u16*)(w + 35651584);           // 25.17 MB
    float* dtb   = (float*)(w + 60817408);         // 131 KB
    float* Sb    = (float*)(w + 60948480);         // 131 KB
    float* Hb    = (float*)(w + 61079552);         // 16.78 MB fp32 chunk states
    u16*   bT    = (u16*)(w + 77856768);           // 8.39 MB (contiguous after Hb)
    u16*   yspl  = (u16*)(w + 61079552);           //   alias Hb|bT (25.17 MB, both
                                                   //   dead when ssd_fused writes)
    u16*   xc    = (u16*)(w + 86245376);           // 16.78 MB fp16
    u16*   xT    = (u16*)(w + 103022592);          // 8.39 MB fp16
    u16*   Hbf   = (u16*)(w + 111411200);          // 8.39 MB fp16
    u16*   wspl  = (u16*)(w + 119799808);
    u16* in_w_s    = wspl;                           // 128 x 192
    u16* l_in_w_s  = wspl + 24576;                   // 1540 x 384
    u16* l_out_w_s = wspl + 24576 + 591360;          // 256 x 768
    u16* out_w_s   = wspl + 24576 + 591360 + 196608; // 64 x 384

    cvt_all_kernel<<<1297, 256, 0, stream>>>(
        x, xspl, in_w, in_w_s, l_in_w, l_in_w_s, l_out_w, l_out_w_s,
        out_w, out_w_s);

    // initial in-proj + fused RMS of layer 0 (mode 0), BM=64
    gemm128_rms_kernel<<<dim3(1, 256), 256, 0, stream>>>(
        xspl, in_w_s, in_b, l_rms_w, xp, hbuf, hnspl, 192, 0);

    for (int i = 0; i < 2; i++) {
        gemm_inproj_kernel<<<dim3(7, 128), 256, 0, stream>>>(
            hnspl, l_in_w_s + (size_t)i * 770 * 384, zx16, dtb, Sb,
            dt_bias + i * 2, A_log + i * 2);
        conv_tile_kernel<<<dim3(256, 8), 256, 0, stream>>>(
            zx16, conv_w + i * 2048, conv_b + i * 512, dtb, Sb, xc, xT, bT);
        chunkstate_kernel<<<dim3(32, 2, 4), 256, 0, stream>>>(xT, bT, Hb);
        statecombine_kernel<<<dim3(64, 2, 4), 256, 0, stream>>>(Sb, Hb, Hbf);
        ssd_fused_kernel<<<dim3(32, 4), 512, 0, stream>>>(
            xc, xT, Hbf, dtb, Sb, zx16, gnorm_w + i * 256, D_p + i * 2, yspl);
        gemm128_rms_kernel<<<dim3(1, 256), 256, 0, stream>>>(
            yspl, l_out_w_s + (size_t)i * 128 * 768, nullptr,
            (i == 0) ? (l_rms_w + 128) : fnorm_w, xp, hbuf, hnspl, 768,
            (i == 0) ? 1 : 2);
    }

    gemm_bf16_kernel<<<dim3(1, 128), 256, 0, stream>>>(
        hnspl, out_w_s, (float*)d_out, out_b, MTOK, 64, 384);
}

// Round 7
// 255.269 us; speedup vs baseline: 2.7741x; 1.2671x over previous
//
#include <hip/hip_runtime.h>
#include <cstddef>
#include <cstdint>

// MambaDoc — round 7: single-fp16 projections everywhere (error budget allows
// it: fp16 inputs + fp32 MFMA accumulate ~2^-11 rel; measured floor 0.031 vs
// threshold 0.19). Split hi/lo bf16 machinery removed. Hb chunk states fp16.
// 13 launches. SSD structure unchanged from round 6.

#define LSEQ 4096
#define MTOK 16384

typedef unsigned short u16;
typedef _Float16 f16x8 __attribute__((ext_vector_type(8)));
typedef float f32x4 __attribute__((ext_vector_type(4)));

__device__ __forceinline__ u16 f2h(float x) {
    return __builtin_bit_cast(u16, (_Float16)x);
}
__device__ __forceinline__ float h2f(u16 u) {
    return (float)__builtin_bit_cast(_Float16, u);
}
__device__ __forceinline__ float silu_f(float x) { return x / (1.f + __expf(-x)); }

__device__ __forceinline__ void async_lds16(const void* g, void* l) {
    __builtin_amdgcn_global_load_lds(
        (const __attribute__((address_space(1))) unsigned int*)g,
        (__attribute__((address_space(3))) unsigned int*)l, 16, 0, 0);
}

// ---------------------------------------------------------------------------
// Flat fp32 -> fp16 convert for x + all projection weights.
// ---------------------------------------------------------------------------
__device__ __forceinline__ void cvt16(
    const float* __restrict__ in, u16* __restrict__ out, int g)
{
    float4 v = *(const float4*)&in[(size_t)g * 4];
    union { u16 u[4]; uint2 q; } pk;
    pk.u[0] = f2h(v.x); pk.u[1] = f2h(v.y);
    pk.u[2] = f2h(v.z); pk.u[3] = f2h(v.w);
    *(uint2*)&out[(size_t)g * 4] = pk.q;
}

__global__ __launch_bounds__(256) void cvt_all_kernel(
    const float* __restrict__ x, u16* __restrict__ xh,
    const float* __restrict__ in_w, u16* __restrict__ in_w16,
    const float* __restrict__ l_in_w, u16* __restrict__ l_in_w16,
    const float* __restrict__ l_out_w, u16* __restrict__ l_out_w16,
    const float* __restrict__ out_w, u16* __restrict__ out_w16)
{
    int g = blockIdx.x * 256 + threadIdx.x;
    if (g < 262144) { cvt16(x, xh, g); return; }
    g -= 262144;
    if (g < 2048) { cvt16(in_w, in_w16, g); return; }
    g -= 2048;
    if (g < 49280) { cvt16(l_in_w, l_in_w16, g); return; }
    g -= 49280;
    if (g < 16384) { cvt16(l_out_w, l_out_w16, g); return; }
    g -= 16384;
    if (g < 2048) { cvt16(out_w, out_w16, g); return; }
}

// ---------------------------------------------------------------------------
// in_proj GEMM fp16 (BM=128, BN=128, K=128): blocks x<6 write zx fp16
// (stride 768); block x==6 computes dt softplus + chunk-local cumsum.
// Grid (7, 128), 256 thr.
// ---------------------------------------------------------------------------
__global__ __launch_bounds__(256) void gemm_inproj_kernel(
    const u16* __restrict__ A, const u16* __restrict__ W,
    u16* __restrict__ zx16, float* __restrict__ dtb, float* __restrict__ Sb,
    const float* __restrict__ dt_bias, const float* __restrict__ A_log)
{
    __shared__ u16 sA[128 * 64];
    __shared__ u16 sW[128 * 64];
    __shared__ float sdt[2][128];
    const int K = 128, N = 770;
    const int n0 = blockIdx.x * 128, m0 = blockIdx.y * 128;
    const int tid = threadIdx.x, wid = tid >> 6, lane = tid & 63;
    const int wm = (wid >> 1) * 64, wn = (wid & 1) * 64;
    const int quad = lane >> 4, cl = lane & 15;
    f32x4 acc[4][4];
    #pragma unroll
    for (int i = 0; i < 4; i++)
        #pragma unroll
        for (int j = 0; j < 4; j++) acc[i][j] = f32x4{0.f, 0.f, 0.f, 0.f};

    for (int k0 = 0; k0 < K; k0 += 64) {
        #pragma unroll
        for (int i = 0; i < 4; i++) {
            int ck = i * 256 + tid;
            int r = ck >> 3, cc = ck & 7;
            int csw = (cc ^ (r & 7)) << 3;
            async_lds16(A + (size_t)(m0 + r) * K + k0 + csw,
                        (void*)(sA + (i * 256 + (tid & ~63)) * 8));
            int rr = n0 + r; if (rr >= N) rr = N - 1;
            async_lds16(W + (size_t)rr * K + k0 + csw,
                        (void*)(sW + (i * 256 + (tid & ~63)) * 8));
        }
        __syncthreads();
        #pragma unroll
        for (int ks = 0; ks < 2; ks++) {
            f16x8 af[4], wf[4];
            int kc = ks * 4 + quad;
            #pragma unroll
            for (int i = 0; i < 4; i++) {
                int r = wm + i * 16 + cl;
                af[i] = *(const f16x8*)&sA[r * 64 + ((kc ^ (r & 7)) << 3)];
            }
            #pragma unroll
            for (int j = 0; j < 4; j++) {
                int r = wn + j * 16 + cl;
                wf[j] = *(const f16x8*)&sW[r * 64 + ((kc ^ (r & 7)) << 3)];
            }
            #pragma unroll
            for (int i = 0; i < 4; i++)
                #pragma unroll
                for (int j = 0; j < 4; j++)
                    acc[i][j] = __builtin_amdgcn_mfma_f32_16x16x32_f16(
                        af[i], wf[j], acc[i][j], 0, 0, 0);
        }
        __syncthreads();
    }
    if (blockIdx.x < 6) {
        #pragma unroll
        for (int i = 0; i < 4; i++) {
            int m = m0 + wm + i * 16 + quad * 4;
            #pragma unroll
            for (int j = 0; j < 4; j++) {
                int n = n0 + wn + j * 16 + cl;
                #pragma unroll
                for (int r = 0; r < 4; r++)
                    zx16[(size_t)(m + r) * 768 + n] = f2h(acc[i][j][r]);
            }
        }
    } else {
        if ((wid & 1) == 0 && cl < 2) {
            #pragma unroll
            for (int i = 0; i < 4; i++)
                #pragma unroll
                for (int r = 0; r < 4; r++)
                    sdt[cl][wm + i * 16 + quad * 4 + r] = acc[i][0][r];
        }
        __syncthreads();
        const int hh = tid >> 7, t = tid & 127;
        float raw = sdt[hh][t] + dt_bias[hh];
        float dt = fmaxf(raw, 0.f) + log1pf(__expf(-fabsf(raw)));
        dtb[(size_t)(m0 + t) * 2 + hh] = dt;
        float ad = -__expf(A_log[hh]) * dt;
        __syncthreads();
        sdt[hh][t] = ad;
        __syncthreads();
        for (int off = 1; off < 128; off <<= 1) {
            float add = (t >= off) ? sdt[hh][t - off] : 0.f;
            __syncthreads();
            sdt[hh][t] += add;
            __syncthreads();
        }
        Sb[(size_t)(m0 + t) * 2 + hh] = sdt[hh][t];
    }
}

// ---------------------------------------------------------------------------
// N=128 GEMM fp16 (BM=64) with fused residual + RMSNorm epilogue. Grid (1,256).
// mode 0: v = acc+bias; xp=v; hbuf=v; hn = fp16(rms(v)*rmsw)
// mode 1: v = acc+hbuf;  hbuf=v;      hn = fp16(rms(v)*rmsw)
// mode 2: v = acc+hbuf;               hn = fp16(xp + rms(v)*rmsw)
// ---------------------------------------------------------------------------
__global__ __launch_bounds__(256) void gemm128_rms_kernel(
    const u16* __restrict__ A, const u16* __restrict__ W,
    const float* __restrict__ bias, const float* __restrict__ rmsw,
    float* __restrict__ xp, float* __restrict__ hbuf,
    u16* __restrict__ hn, int K, int mode)
{
    __shared__ u16 sA[64 * 64];
    __shared__ u16 sW[128 * 64];
    __shared__ float red[64][33];
    __shared__ float srstd[64];
    const int m0 = blockIdx.y * 64;
    const int tid = threadIdx.x, wid = tid >> 6, lane = tid & 63;
    const int wm = (wid >> 1) * 32, wn = (wid & 1) * 64;
    const int quad = lane >> 4, cl = lane & 15;
    f32x4 acc[2][4];
    #pragma unroll
    for (int i = 0; i < 2; i++)
        #pragma unroll
        for (int j = 0; j < 4; j++) acc[i][j] = f32x4{0.f, 0.f, 0.f, 0.f};

    for (int k0 = 0; k0 < K; k0 += 64) {
        #pragma unroll
        for (int i = 0; i < 2; i++) {
            int ck = i * 256 + tid;
            int r = ck >> 3, cc = ck & 7;
            int csw = (cc ^ (r & 7)) << 3;
            async_lds16(A + (size_t)(m0 + r) * K + k0 + csw,
                        (void*)(sA + (i * 256 + (tid & ~63)) * 8));
        }
        #pragma unroll
        for (int i = 0; i < 4; i++) {
            int ck = i * 256 + tid;
            int r = ck >> 3, cc = ck & 7;
            int csw = (cc ^ (r & 7)) << 3;
            async_lds16(W + (size_t)r * K + k0 + csw,
                        (void*)(sW + (i * 256 + (tid & ~63)) * 8));
        }
        __syncthreads();
        #pragma unroll
        for (int ks = 0; ks < 2; ks++) {
            f16x8 af[2], wf[4];
            int kc = ks * 4 + quad;
            #pragma unroll
            for (int i = 0; i < 2; i++) {
                int r = wm + i * 16 + cl;
                af[i] = *(const f16x8*)&sA[r * 64 + ((kc ^ (r & 7)) << 3)];
            }
            #pragma unroll
            for (int j = 0; j < 4; j++) {
                int r = wn + j * 16 + cl;
                wf[j] = *(const f16x8*)&sW[r * 64 + ((kc ^ (r & 7)) << 3)];
            }
            #pragma unroll
            for (int i = 0; i < 2; i++)
                #pragma unroll
                for (int j = 0; j < 4; j++)
                    acc[i][j] = __builtin_amdgcn_mfma_f32_16x16x32_f16(
                        af[i], wf[j], acc[i][j], 0, 0, 0);
        }
        __syncthreads();
    }
    const int slot = (wid & 1) * 16 + cl;
    #pragma unroll
    for (int i = 0; i < 2; i++) {
        #pragma unroll
        for (int r = 0; r < 4; r++) {
            int t = wm + i * 16 + quad * 4 + r;
            size_t ob = (size_t)(m0 + t) * 128;
            float ssp = 0.f;
            #pragma unroll
            for (int j = 0; j < 4; j++) {
                int n = wn + j * 16 + cl;
                float v = acc[i][j][r];
                if (mode == 0) v += bias[n];
                else v += hbuf[ob + n];
                acc[i][j][r] = v;
                ssp += v * v;
            }
            red[t][slot] = ssp;
        }
    }
    __syncthreads();
    if (tid < 64) {
        float s = 0.f;
        #pragma unroll
        for (int sl = 0; sl < 32; sl++) s += red[tid][sl];
        srstd[tid] = rsqrtf(s * (1.f / 128.f) + 1e-5f);
    }
    __syncthreads();
    #pragma unroll
    for (int i = 0; i < 2; i++) {
        #pragma unroll
        for (int r = 0; r < 4; r++) {
            int t = wm + i * 16 + quad * 4 + r;
            size_t ob = (size_t)(m0 + t) * 128;
            u16* row = hn + (size_t)(m0 + t) * 128;
            float rstd = srstd[t];
            #pragma unroll
            for (int j = 0; j < 4; j++) {
                int n = wn + j * 16 + cl;
                float v = acc[i][j][r];
                if (mode == 0) { xp[ob + n] = v; hbuf[ob + n] = v; }
                else if (mode == 1) hbuf[ob + n] = v;
                float val = v * rstd * rmsw[n];
                if (mode == 2) val += xp[ob + n];
                row[n] = f2h(val);
            }
        }
    }
}

// ---------------------------------------------------------------------------
// Final projection: out(16384x64) = hn(16384x128) @ out_w(64x128)^T + bias.
// fp16 MFMA, BM=64, BN=64. Grid (1, 256).
// ---------------------------------------------------------------------------
__global__ __launch_bounds__(256) void gemm_final_kernel(
    const u16* __restrict__ A, const u16* __restrict__ W,
    float* __restrict__ out, const float* __restrict__ bias)
{
    __shared__ u16 sA[64 * 64];
    __shared__ u16 sW[64 * 64];
    const int K = 128;
    const int m0 = blockIdx.y * 64;
    const int tid = threadIdx.x, wid = tid >> 6, lane = tid & 63;
    const int wm = (wid >> 1) * 32, wn = (wid & 1) * 32;
    const int quad = lane >> 4, cl = lane & 15;
    f32x4 acc[2][2];
    #pragma unroll
    for (int i = 0; i < 2; i++)
        #pragma unroll
        for (int j = 0; j < 2; j++) acc[i][j] = f32x4{0.f, 0.f, 0.f, 0.f};

    for (int k0 = 0; k0 < K; k0 += 64) {
        #pragma unroll
        for (int i = 0; i < 2; i++) {
            int ck = i * 256 + tid;
            int r = ck >> 3, cc = ck & 7;
            int csw = (cc ^ (r & 7)) << 3;
            async_lds16(A + (size_t)(m0 + r) * K + k0 + csw,
                        (void*)(sA + (i * 256 + (tid & ~63)) * 8));
            async_lds16(W + (size_t)r * K + k0 + csw,
                        (void*)(sW + (i * 256 + (tid & ~63)) * 8));
        }
        __syncthreads();
        #pragma unroll
        for (int ks = 0; ks < 2; ks++) {
            f16x8 af[2], wf[2];
            int kc = ks * 4 + quad;
            #pragma unroll
            for (int i = 0; i < 2; i++) {
                int r = wm + i * 16 + cl;
                af[i] = *(const f16x8*)&sA[r * 64 + ((kc ^ (r & 7)) << 3)];
            }
            #pragma unroll
            for (int j = 0; j < 2; j++) {
                int r = wn + j * 16 + cl;
                wf[j] = *(const f16x8*)&sW[r * 64 + ((kc ^ (r & 7)) << 3)];
            }
            #pragma unroll
            for (int i = 0; i < 2; i++)
                #pragma unroll
                for (int j = 0; j < 2; j++)
                    acc[i][j] = __builtin_amdgcn_mfma_f32_16x16x32_f16(
                        af[i], wf[j], acc[i][j], 0, 0, 0);
        }
        __syncthreads();
    }
    #pragma unroll
    for (int i = 0; i < 2; i++) {
        int m = m0 + wm + i * 16 + quad * 4;
        #pragma unroll
        for (int j = 0; j < 2; j++) {
            int n = wn + j * 16 + cl;
            float bv = bias[n];
            #pragma unroll
            for (int r = 0; r < 4; r++)
                out[(size_t)(m + r) * 64 + n] = acc[i][j][r] + bv;
        }
    }
}

// ---------------------------------------------------------------------------
// Causal conv(4)+silu over 512 xBC channels (fp16 in, stride 768).
// Writes xc (fp16 [tok][512]), xT ([p][s] per chunk), bT (w_s-scaled B^T).
// Grid (256, 8), 256 thr.
// ---------------------------------------------------------------------------
__global__ __launch_bounds__(256) void conv_tile_kernel(
    const u16* __restrict__ zx16, const float* __restrict__ cw,
    const float* __restrict__ cb, const float* __restrict__ dtb,
    const float* __restrict__ Sb, u16* __restrict__ xc,
    u16* __restrict__ xT, u16* __restrict__ bT)
{
    __shared__ float sZ[67][68];
    __shared__ float sT[64][65];
    __shared__ float sw[2][64];
    const int tid = threadIdx.x;
    const int tok0 = blockIdx.x * 64;
    const int cg = blockIdx.y;
    const int cgb = cg * 64;
    const int l0 = tok0 & (LSEQ - 1);
    for (int idx = tid; idx < 67 * 16; idx += 256) {
        int row = idx >> 4, c4 = (idx & 15) * 4;
        int lr = l0 + row - 3;
        union { u16 u[4]; uint2 q; } ld;
        ld.q = make_uint2(0u, 0u);
        if (lr >= 0)
            ld.q = *(const uint2*)&zx16[(size_t)(tok0 + row - 3) * 768 + 256 + cgb + c4];
        #pragma unroll
        for (int j = 0; j < 4; j++) sZ[row][c4 + j] = h2f(ld.u[j]);
    }
    if ((cg == 4 || cg == 5) && tid < 128) {
        int hh = tid >> 6, j = tid & 63;
        int tokL = (tok0 & ~127) + 127;
        sw[hh][j] = __expf(Sb[(size_t)tokL * 2 + hh] - Sb[(size_t)(tok0 + j) * 2 + hh])
                    * dtb[(size_t)(tok0 + j) * 2 + hh];
    }
    const int ch = tid & 63;
    const int chg = cgb + ch;
    const float w0 = cw[chg * 4], w1 = cw[chg * 4 + 1];
    const float w2 = cw[chg * 4 + 2], w3 = cw[chg * 4 + 3];
    const float cbv = cb[chg];
    __syncthreads();
    #pragma unroll
    for (int k = 0; k < 16; k++) {
        int tokr = k * 4 + (tid >> 6);
        float a = cbv + sZ[tokr][ch] * w0 + sZ[tokr + 1][ch] * w1
                + sZ[tokr + 2][ch] * w2 + sZ[tokr + 3][ch] * w3;
        float v = silu_f(a);
        xc[(size_t)(tok0 + tokr) * 512 + chg] = f2h(v);
        sT[ch][tokr] = v;
    }
    __syncthreads();
    const int b = tok0 >> 12;
    const int c = (tok0 & (LSEQ - 1)) >> 7;
    const int s0 = tok0 & 127;
    if (cg < 4) {
        int hh = cg >> 1;
        int pbase = (cg & 1) * 64;
        u16* base = xT + (((size_t)((b * 2 + hh) * 32 + c)) << 14);
        for (int idx = tid; idx < 512; idx += 256) {
            int pr = idx >> 3, sc = (idx & 7) * 8;
            union { u16 u[8]; uint4 q; } pk;
            #pragma unroll
            for (int j = 0; j < 8; j++) pk.u[j] = f2h(sT[pr][sc + j]);
            *(uint4*)&base[(size_t)(pbase + pr) * 128 + s0 + sc] = pk.q;
        }
    } else if (cg < 6) {
        int nbase = (cg - 4) * 64;
        for (int hh = 0; hh < 2; hh++) {
            u16* base = bT + (((size_t)((b * 2 + hh) * 32 + c)) << 14);
            for (int idx = tid; idx < 512; idx += 256) {
                int nr = idx >> 3, sc = (idx & 7) * 8;
                union { u16 u[8]; uint4 q; } pk;
                #pragma unroll
                for (int j = 0; j < 8; j++)
                    pk.u[j] = f2h(sT[nr][sc + j] * sw[hh][sc + j]);
                *(uint4*)&base[(size_t)(nbase + nr) * 128 + s0 + sc] = pk.q;
            }
        }
    }
}

// ---------------------------------------------------------------------------
// Chunk-local end state via fp16 MFMA: Hloc[p,n] = sum_s X^T[p,s]*(w_s B)[s,n]
// Output fp16.
// ---------------------------------------------------------------------------
__global__ __launch_bounds__(256) void chunkstate_kernel(
    const u16* __restrict__ xT, const u16* __restrict__ bT,
    u16* __restrict__ Hb)
{
    __shared__ u16 sX[128 * 128];
    __shared__ u16 sB[128 * 128];
    const int c = blockIdx.x, h = blockIdx.y, b = blockIdx.z;
    const int tid = threadIdx.x, wid = tid >> 6, lane = tid & 63;
    const size_t blk = ((size_t)((b * 2 + h) * 32 + c)) << 14;
    #pragma unroll
    for (int i = 0; i < 8; i++) {
        int ck = i * 256 + tid;
        int r = ck >> 4, cc = ck & 15;
        size_t g = (size_t)r * 128 + ((cc ^ (r & 15)) << 3);
        async_lds16(xT + blk + g, (void*)(sX + (i * 256 + (tid & ~63)) * 8));
        async_lds16(bT + blk + g, (void*)(sB + (i * 256 + (tid & ~63)) * 8));
    }
    __syncthreads();
    const int wm = (wid >> 1) * 64, wn = (wid & 1) * 64;
    const int quad = lane >> 4, cl = lane & 15;
    f32x4 acc[4][4];
    #pragma unroll
    for (int i = 0; i < 4; i++)
        #pragma unroll
        for (int j = 0; j < 4; j++) acc[i][j] = f32x4{0.f, 0.f, 0.f, 0.f};
    #pragma unroll
    for (int ks = 0; ks < 4; ks++) {
        f16x8 xa[4], bb[4];
        int kc = ks * 4 + quad;
        #pragma unroll
        for (int i = 0; i < 4; i++) {
            int r = wm + i * 16 + cl;
            xa[i] = *(const f16x8*)&sX[r * 128 + ((kc ^ (r & 15)) << 3)];
        }
        #pragma unroll
        for (int j = 0; j < 4; j++) {
            int r = wn + j * 16 + cl;
            bb[j] = *(const f16x8*)&sB[r * 128 + ((kc ^ (r & 15)) << 3)];
        }
        #pragma unroll
        for (int i = 0; i < 4; i++)
            #pragma unroll
            for (int j = 0; j < 4; j++)
                acc[i][j] = __builtin_amdgcn_mfma_f32_16x16x32_f16(
                    xa[i], bb[j], acc[i][j], 0, 0, 0);
    }
    u16* out = Hb + blk;
    #pragma unroll
    for (int i = 0; i < 4; i++)
        #pragma unroll
        for (int j = 0; j < 4; j++)
            #pragma unroll
            for (int r = 0; r < 4; r++)
                out[(size_t)(wm + i * 16 + quad * 4 + r) * 128 + wn + j * 16 + cl]
                    = f2h(acc[i][j][r]);
}

// ---------------------------------------------------------------------------
// Inter-chunk combine (fp32 accumulate); writes INCOMING state per chunk fp16.
// ---------------------------------------------------------------------------
__global__ __launch_bounds__(256) void statecombine_kernel(
    const float* __restrict__ Sb, const u16* __restrict__ Hb,
    u16* __restrict__ Hbf)
{
    const int e = blockIdx.x * 256 + threadIdx.x;
    const int h = blockIdx.y, b = blockIdx.z;
    const size_t base = ((size_t)((b * 2 + h) * 32)) << 14;
    float state = 0.f;
    for (int c = 0; c < 32; c++) {
        size_t idx = base + ((size_t)c << 14) + e;
        float v = h2f(Hb[idx]);
        Hbf[idx] = f2h(state);
        float dec = __expf(Sb[(size_t)(b * LSEQ + c * 128 + 127) * 2 + h]);
        state = dec * state + v;
    }
}

// ---------------------------------------------------------------------------
// Fused SSD output + D-skip + silu gate + 256-ch RMSNorm, both heads/block.
// G=1: B/C shared across heads -> C@B^T computed once. Writes y16 fp16.
// Grid (32, 4), 512 threads, ~133 KB LDS.
// ---------------------------------------------------------------------------
__global__ __launch_bounds__(512, 2) void ssd_fused_kernel(
    const u16* __restrict__ xc, const u16* __restrict__ xT,
    const u16* __restrict__ Hbf, const float* __restrict__ dtb,
    const float* __restrict__ Sb, const u16* __restrict__ zx16,
    const float* __restrict__ gnw, const float* __restrict__ Dp,
    u16* __restrict__ y16)
{
    __shared__ u16 bufCW[2][128 * 128];  // [0]=C -> G0, [1]=B -> G1
    __shared__ u16 bufH[2][128 * 128];   // [h]=Hin_h -> X_h
    __shared__ float sS[2][128], sdt[2][128];
    __shared__ float red[128][5];
    __shared__ float srstd[128];
    const int c = blockIdx.x, b = blockIdx.y;
    const int tid = threadIdx.x, wid = tid >> 6, lane = tid & 63;
    const int quad = lane >> 4, cl = lane & 15;
    const int tok0 = b * LSEQ + c * 128;
    const size_t blk0 = ((size_t)((b * 2 + 0) * 32 + c)) << 14;
    const size_t blk1 = ((size_t)((b * 2 + 1) * 32 + c)) << 14;
    #pragma unroll
    for (int i = 0; i < 4; i++) {
        int ck = i * 512 + tid;
        int r = ck >> 4, cc = ck & 15;
        int csw = (cc ^ (r & 15)) << 3;
        int ldst = (i * 512 + (tid & ~63)) * 8;
        async_lds16(xc + (size_t)(tok0 + r) * 512 + 384 + csw, (void*)(&bufCW[0][0] + ldst));
        async_lds16(xc + (size_t)(tok0 + r) * 512 + 256 + csw, (void*)(&bufCW[1][0] + ldst));
        async_lds16(Hbf + blk0 + (size_t)r * 128 + csw, (void*)(&bufH[0][0] + ldst));
        async_lds16(Hbf + blk1 + (size_t)r * 128 + csw, (void*)(&bufH[1][0] + ldst));
    }
    if (tid < 256) {
        int hh = tid >> 7, t = tid & 127;
        sS[hh][t] = Sb[(size_t)(tok0 + t) * 2 + hh];
        sdt[hh][t] = dtb[(size_t)(tok0 + t) * 2 + hh];
    }
    __syncthreads();
    // ---- phase 1: Y_h = C @ Hin_h^T (waves 0-3: h=0; 4-7: h=1)
    const int h = wid >> 2, w2 = wid & 3;
    const int wm = (w2 >> 1) * 64, wn = (w2 & 1) * 64;
    f32x4 acc[4][4];
    #pragma unroll
    for (int i = 0; i < 4; i++)
        #pragma unroll
        for (int j = 0; j < 4; j++) acc[i][j] = f32x4{0.f, 0.f, 0.f, 0.f};
    #pragma unroll
    for (int ks = 0; ks < 4; ks++) {
        f16x8 ca[4], hb[4];
        int kc = ks * 4 + quad;
        #pragma unroll
        for (int i = 0; i < 4; i++) {
            int r = wm + i * 16 + cl;
            ca[i] = *(const f16x8*)&bufCW[0][r * 128 + ((kc ^ (r & 15)) << 3)];
        }
        #pragma unroll
        for (int j = 0; j < 4; j++) {
            int r = wn + j * 16 + cl;
            hb[j] = *(const f16x8*)&bufH[h][r * 128 + ((kc ^ (r & 15)) << 3)];
        }
        #pragma unroll
        for (int i = 0; i < 4; i++)
            #pragma unroll
            for (int j = 0; j < 4; j++)
                acc[i][j] = __builtin_amdgcn_mfma_f32_16x16x32_f16(
                    ca[i], hb[j], acc[i][j], 0, 0, 0);
    }
    #pragma unroll
    for (int i = 0; i < 4; i++)
        #pragma unroll
        for (int r = 0; r < 4; r++) {
            float e = __expf(sS[h][wm + i * 16 + quad * 4 + r]);
            #pragma unroll
            for (int j = 0; j < 4; j++) acc[i][j][r] *= e;
        }
    // ---- phase 2: S = C @ B^T (all 8 waves; 32x64 tiles)
    const int sm0 = (wid >> 1) * 32, sn0 = (wid & 1) * 64;
    f32x4 sacc[2][4];
    #pragma unroll
    for (int i = 0; i < 2; i++)
        #pragma unroll
        for (int j = 0; j < 4; j++) sacc[i][j] = f32x4{0.f, 0.f, 0.f, 0.f};
    #pragma unroll
    for (int ks = 0; ks < 4; ks++) {
        f16x8 cs[2], bs[4];
        int kc = ks * 4 + quad;
        #pragma unroll
        for (int i2 = 0; i2 < 2; i2++) {
            int r = sm0 + i2 * 16 + cl;
            cs[i2] = *(const f16x8*)&bufCW[0][r * 128 + ((kc ^ (r & 15)) << 3)];
        }
        #pragma unroll
        for (int j = 0; j < 4; j++) {
            int r = sn0 + j * 16 + cl;
            bs[j] = *(const f16x8*)&bufCW[1][r * 128 + ((kc ^ (r & 15)) << 3)];
        }
        #pragma unroll
        for (int i2 = 0; i2 < 2; i2++)
            #pragma unroll
            for (int j = 0; j < 4; j++)
                if (sm0 + i2 * 16 + 15 >= sn0 + j * 16)
                    sacc[i2][j] = __builtin_amdgcn_mfma_f32_16x16x32_f16(
                        cs[i2], bs[j], sacc[i2][j], 0, 0, 0);
    }
    __syncthreads();
    // stage X0, X1 over bufH while computing/writing G
    #pragma unroll
    for (int i = 0; i < 4; i++) {
        int ck = i * 512 + tid;
        int r = ck >> 4, cc = ck & 15;
        int csw = (cc ^ (r & 15)) << 3;
        int ldst = (i * 512 + (tid & ~63)) * 8;
        async_lds16(xT + blk0 + (size_t)r * 128 + csw, (void*)(&bufH[0][0] + ldst));
        async_lds16(xT + blk1 + (size_t)r * 128 + csw, (void*)(&bufH[1][0] + ldst));
    }
    #pragma unroll
    for (int hh = 0; hh < 2; hh++)
        #pragma unroll
        for (int i2 = 0; i2 < 2; i2++)
            #pragma unroll
            for (int r = 0; r < 4; r++) {
                int t = sm0 + i2 * 16 + quad * 4 + r;
                float Stv = sS[hh][t];
                #pragma unroll
                for (int j = 0; j < 4; j++) {
                    int s = sn0 + j * 16 + cl;
                    float gv = 0.f;
                    if (s <= t)
                        gv = sacc[i2][j][r] * __expf(Stv - sS[hh][s]) * sdt[hh][s];
                    bufCW[hh][t * 128 + (((s >> 3) ^ (t & 15)) << 3) + (s & 7)] = f2h(gv);
                }
            }
    __syncthreads();
    // ---- phase 3: Y_h += G_h @ X_h
    #pragma unroll
    for (int ks = 0; ks < 4; ks++) {
        f16x8 ga[4], xb[4];
        int kc = ks * 4 + quad;
        #pragma unroll
        for (int i = 0; i < 4; i++) {
            int r = wm + i * 16 + cl;
            ga[i] = *(const f16x8*)&bufCW[h][r * 128 + ((kc ^ (r & 15)) << 3)];
        }
        #pragma unroll
        for (int j = 0; j < 4; j++) {
            int r = wn + j * 16 + cl;
            xb[j] = *(const f16x8*)&bufH[h][r * 128 + ((kc ^ (r & 15)) << 3)];
        }
        #pragma unroll
        for (int i = 0; i < 4; i++)
            #pragma unroll
            for (int j = 0; j < 4; j++)
                acc[i][j] = __builtin_amdgcn_mfma_f32_16x16x32_f16(
                    ga[i], xb[j], acc[i][j], 0, 0, 0);
    }
    // ---- epilogue: D-skip + silu gate, per-token sum of squares
    const float dco = Dp[h];
    #pragma unroll
    for (int i = 0; i < 4; i++)
        #pragma unroll
        for (int r = 0; r < 4; r++) {
            int t = wm + i * 16 + quad * 4 + r;
            float ssp = 0.f;
            #pragma unroll
            for (int j = 0; j < 4; j++) {
                int p = wn + j * 16 + cl;
                float xv = h2f(bufH[h][p * 128 + (((t >> 3) ^ (p & 15)) << 3) + (t & 7)]);
                float zv = h2f(zx16[(size_t)(tok0 + t) * 768 + h * 128 + p]);
                float g = (acc[i][j][r] + dco * xv) * silu_f(zv);
                acc[i][j][r] = g;
                ssp += g * g;
            }
            ssp += __shfl_xor(ssp, 1);
            ssp += __shfl_xor(ssp, 2);
            ssp += __shfl_xor(ssp, 4);
            ssp += __shfl_xor(ssp, 8);
            if (cl == 0) red[t][h * 2 + (wn >> 6)] = ssp;
        }
    __syncthreads();
    if (tid < 128)
        srstd[tid] = rsqrtf((red[tid][0] + red[tid][1] + red[tid][2] + red[tid][3])
                            * (1.f / 256.f) + 1e-5f);
    __syncthreads();
    #pragma unroll
    for (int i = 0; i < 4; i++)
        #pragma unroll
        for (int r = 0; r < 4; r++) {
            int t = wm + i * 16 + quad * 4 + r;
            float rstd = srstd[t];
            u16* row = y16 + (size_t)(tok0 + t) * 256;
            #pragma unroll
            for (int j = 0; j < 4; j++) {
                int p = wn + j * 16 + cl;
                int e = h * 128 + p;
                row[e] = f2h(acc[i][j][r] * rstd * gnw[e]);
            }
        }
}

// ---------------------------------------------------------------------------
extern "C" void kernel_launch(void* const* d_in, const int* in_sizes, int n_in,
                              void* d_out, int out_size, void* d_ws, size_t ws_size,
                              hipStream_t stream)
{
    (void)in_sizes; (void)n_in; (void)out_size; (void)ws_size;
    const float* x       = (const float*)d_in[0];
    const float* in_w    = (const float*)d_in[1];
    const float* in_b    = (const float*)d_in[2];
    const float* out_w   = (const float*)d_in[3];
    const float* out_b   = (const float*)d_in[4];
    const float* l_rms_w = (const float*)d_in[5];
    const float* l_in_w  = (const float*)d_in[6];
    const float* conv_w  = (const float*)d_in[7];
    const float* conv_b  = (const float*)d_in[8];
    const float* dt_bias = (const float*)d_in[9];
    const float* A_log   = (const float*)d_in[10];
    const float* D_p     = (const float*)d_in[11];
    const float* gnorm_w = (const float*)d_in[12];
    const float* l_out_w = (const float*)d_in[13];
    const float* fnorm_w = (const float*)d_in[14];

    char* w = (char*)d_ws;
    float* xp    = (float*)(w);                    // 8.39 MB
    float* hbuf  = (float*)(w + 8388608);          // 8.39 MB
    u16*   xh    = (u16*)(w + 16777216);           // 2.10 MB (16384 x 64)
    u16*   hn16  = (u16*)(w + 18874368);           // 4.19 MB (16384 x 128)
    u16*   zx16  = (u16*)(w + 23068672);           // 25.17 MB (16384 x 768)
    float* dtb   = (float*)(w + 48234496);         // 131 KB
    float* Sb    = (float*)(w + 48365568);         // 131 KB
    u16*   Hb    = (u16*)(w + 48496640);           // 8.39 MB fp16 chunk states
    u16*   xc    = (u16*)(w + 56885248);           // 16.78 MB
    u16*   xT    = (u16*)(w + 73662464);           // 8.39 MB
    u16*   bT    = (u16*)(w + 82051072);           // 8.39 MB
    u16*   Hbf   = (u16*)(w + 90439680);           // 8.39 MB
    u16*   y16   = (u16*)(w + 98828288);           // 8.39 MB (16384 x 256)
    u16*   w16   = (u16*)(w + 107216896);
    u16* in_w16    = w16;                            // 128 x 64
    u16* l_in_w16  = w16 + 8192;                     // 2 x 770 x 128
    u16* l_out_w16 = w16 + 8192 + 197120;            // 2 x 128 x 256
    u16* out_w16   = w16 + 8192 + 197120 + 65536;    // 64 x 128

    cvt_all_kernel<<<1297, 256, 0, stream>>>(
        x, xh, in_w, in_w16, l_in_w, l_in_w16, l_out_w, l_out_w16,
        out_w, out_w16);

    // initial in-proj + fused RMS of layer 0 (mode 0), K=64
    gemm128_rms_kernel<<<dim3(1, 256), 256, 0, stream>>>(
        xh, in_w16, in_b, l_rms_w, xp, hbuf, hn16, 64, 0);

    for (int i = 0; i < 2; i++) {
        gemm_inproj_kernel<<<dim3(7, 128), 256, 0, stream>>>(
            hn16, l_in_w16 + (size_t)i * 770 * 128, zx16, dtb, Sb,
            dt_bias + i * 2, A_log + i * 2);
        conv_tile_kernel<<<dim3(256, 8), 256, 0, stream>>>(
            zx16, conv_w + i * 2048, conv_b + i * 512, dtb, Sb, xc, xT, bT);
        chunkstate_kernel<<<dim3(32, 2, 4), 256, 0, stream>>>(xT, bT, Hb);
        statecombine_kernel<<<dim3(64, 2, 4), 256, 0, stream>>>(Sb, Hb, Hbf);
        ssd_fused_kernel<<<dim3(32, 4), 512, 0, stream>>>(
            xc, xT, Hbf, dtb, Sb, zx16, gnorm_w + i * 256, D_p + i * 2, y16);
        gemm128_rms_kernel<<<dim3(1, 256), 256, 0, stream>>>(
            y16, l_out_w16 + (size_t)i * 128 * 256, nullptr,
            (i == 0) ? (l_rms_w + 128) : fnorm_w, xp, hbuf, hn16, 256,
            (i == 0) ? 1 : 2);
    }

    gemm_final_kernel<<<dim3(1, 256), 256, 0, stream>>>(
        hn16, out_w16, (float*)d_out, out_b);
}

// Round 8
// 246.192 us; speedup vs baseline: 2.8764x; 1.0369x over previous
//
#include <hip/hip_runtime.h>
#include <cstddef>
#include <cstdint>

// MambaDoc — round 8: kernel-count attack. 11 launches.
//  * conv_tile deleted: conv+silu inlined into chunkstate (with LDS transpose,
//    emits xT) and into ssd_fused (token-major, no transpose).
//  * cvt_all deleted: GEMMs stage fp32 weights/x with inline fp32->fp16.
//  * gemm_final deleted: fused into mode-3 out-proj epilogue.
//  * residual stream xp/hbuf in fp16.

#define LSEQ 4096
#define MTOK 16384

typedef unsigned short u16;
typedef _Float16 f16x8 __attribute__((ext_vector_type(8)));
typedef float f32x4 __attribute__((ext_vector_type(4)));

__device__ __forceinline__ u16 f2h(float x) {
    return __builtin_bit_cast(u16, (_Float16)x);
}
__device__ __forceinline__ float h2f(u16 u) {
    return (float)__builtin_bit_cast(_Float16, u);
}
__device__ __forceinline__ float silu_f(float x) { return x / (1.f + __expf(-x)); }

__device__ __forceinline__ void async_lds16(const void* g, void* l) {
    __builtin_amdgcn_global_load_lds(
        (const __attribute__((address_space(1))) unsigned int*)g,
        (__attribute__((address_space(3))) unsigned int*)l, 16, 0, 0);
}

// pack 8 fp32 (two float4) -> 8 fp16 in a uint4
__device__ __forceinline__ uint4 cvt8(const float* __restrict__ src) {
    float4 a = *(const float4*)src;
    float4 b = *(const float4*)(src + 4);
    union { u16 u[8]; uint4 q; } pk;
    pk.u[0] = f2h(a.x); pk.u[1] = f2h(a.y); pk.u[2] = f2h(a.z); pk.u[3] = f2h(a.w);
    pk.u[4] = f2h(b.x); pk.u[5] = f2h(b.y); pk.u[6] = f2h(b.z); pk.u[7] = f2h(b.w);
    return pk.q;
}

// ---------------------------------------------------------------------------
// Initial projection + fused RMSNorm (mode-0). A = x fp32 (16384x64),
// W = in_w fp32 (128x64), inline cvt. Writes xp16, hbuf16 (fp16 residual),
// hn16 (normed fp16). BM=64, grid (1,256).
// ---------------------------------------------------------------------------
__global__ __launch_bounds__(256) void gemm_rms0_kernel(
    const float* __restrict__ xf, const float* __restrict__ wf,
    const float* __restrict__ bias, const float* __restrict__ rmsw,
    u16* __restrict__ xp16, u16* __restrict__ hbuf16, u16* __restrict__ hn16)
{
    __shared__ u16 sA[64 * 64];
    __shared__ u16 sW[128 * 64];
    __shared__ float red[64][33];
    __shared__ float srstd[64];
    const int m0 = blockIdx.y * 64;
    const int tid = threadIdx.x, wid = tid >> 6, lane = tid & 63;
    const int wm = (wid >> 1) * 32, wn = (wid & 1) * 64;
    const int quad = lane >> 4, cl = lane & 15;
    // stage A (x fp32 -> fp16): 512 chunks
    #pragma unroll
    for (int i = 0; i < 2; i++) {
        int ck = i * 256 + tid;
        int r = ck >> 3, cc = ck & 7;
        int csw = (cc ^ (r & 7)) << 3;
        *(uint4*)&sA[ck * 8] = cvt8(xf + (size_t)(m0 + r) * 64 + csw);
    }
    // stage W (in_w fp32): 1024 chunks
    #pragma unroll
    for (int i = 0; i < 4; i++) {
        int ck = i * 256 + tid;
        int r = ck >> 3, cc = ck & 7;
        int csw = (cc ^ (r & 7)) << 3;
        *(uint4*)&sW[ck * 8] = cvt8(wf + (size_t)r * 64 + csw);
    }
    __syncthreads();
    f32x4 acc[2][4];
    #pragma unroll
    for (int i = 0; i < 2; i++)
        #pragma unroll
        for (int j = 0; j < 4; j++) acc[i][j] = f32x4{0.f, 0.f, 0.f, 0.f};
    #pragma unroll
    for (int ks = 0; ks < 2; ks++) {
        f16x8 af[2], wv[4];
        int kc = ks * 4 + quad;
        #pragma unroll
        for (int i = 0; i < 2; i++) {
            int r = wm + i * 16 + cl;
            af[i] = *(const f16x8*)&sA[r * 64 + ((kc ^ (r & 7)) << 3)];
        }
        #pragma unroll
        for (int j = 0; j < 4; j++) {
            int r = wn + j * 16 + cl;
            wv[j] = *(const f16x8*)&sW[r * 64 + ((kc ^ (r & 7)) << 3)];
        }
        #pragma unroll
        for (int i = 0; i < 2; i++)
            #pragma unroll
            for (int j = 0; j < 4; j++)
                acc[i][j] = __builtin_amdgcn_mfma_f32_16x16x32_f16(
                    af[i], wv[j], acc[i][j], 0, 0, 0);
    }
    const int slot = (wid & 1) * 16 + cl;
    #pragma unroll
    for (int i = 0; i < 2; i++)
        #pragma unroll
        for (int r = 0; r < 4; r++) {
            int t = wm + i * 16 + quad * 4 + r;
            float ssp = 0.f;
            #pragma unroll
            for (int j = 0; j < 4; j++) {
                int n = wn + j * 16 + cl;
                float v = acc[i][j][r] + bias[n];
                acc[i][j][r] = v;
                ssp += v * v;
            }
            red[t][slot] = ssp;
        }
    __syncthreads();
    if (tid < 64) {
        float s = 0.f;
        #pragma unroll
        for (int sl = 0; sl < 32; sl++) s += red[tid][sl];
        srstd[tid] = rsqrtf(s * (1.f / 128.f) + 1e-5f);
    }
    __syncthreads();
    #pragma unroll
    for (int i = 0; i < 2; i++)
        #pragma unroll
        for (int r = 0; r < 4; r++) {
            int t = wm + i * 16 + quad * 4 + r;
            size_t ob = (size_t)(m0 + t) * 128;
            float rstd = srstd[t];
            #pragma unroll
            for (int j = 0; j < 4; j++) {
                int n = wn + j * 16 + cl;
                float v = acc[i][j][r];
                u16 vh = f2h(v);
                xp16[ob + n] = vh;
                hbuf16[ob + n] = vh;
                hn16[ob + n] = f2h(v * rstd * rmsw[n]);
            }
        }
}

// ---------------------------------------------------------------------------
// in_proj GEMM fp16 (K=128). A = hn16 via async; W = l_in_w fp32 inline cvt.
// Blocks x<6 write zx16 (stride 768); block x==6 computes dt softplus +
// chunk-local cumsum -> dtb, Sb. Grid (7, 128), 256 thr.
// ---------------------------------------------------------------------------
__global__ __launch_bounds__(256) void gemm_inproj_kernel(
    const u16* __restrict__ A, const float* __restrict__ Wf,
    u16* __restrict__ zx16, float* __restrict__ dtb, float* __restrict__ Sb,
    const float* __restrict__ dt_bias, const float* __restrict__ A_log)
{
    __shared__ u16 sA[128 * 64];
    __shared__ u16 sW[128 * 64];
    __shared__ float sdt[2][128];
    const int K = 128, N = 770;
    const int n0 = blockIdx.x * 128, m0 = blockIdx.y * 128;
    const int tid = threadIdx.x, wid = tid >> 6, lane = tid & 63;
    const int wm = (wid >> 1) * 64, wn = (wid & 1) * 64;
    const int quad = lane >> 4, cl = lane & 15;
    f32x4 acc[4][4];
    #pragma unroll
    for (int i = 0; i < 4; i++)
        #pragma unroll
        for (int j = 0; j < 4; j++) acc[i][j] = f32x4{0.f, 0.f, 0.f, 0.f};

    for (int k0 = 0; k0 < K; k0 += 64) {
        #pragma unroll
        for (int i = 0; i < 4; i++) {
            int ck = i * 256 + tid;
            int r = ck >> 3, cc = ck & 7;
            int csw = (cc ^ (r & 7)) << 3;
            async_lds16(A + (size_t)(m0 + r) * K + k0 + csw,
                        (void*)(sA + (i * 256 + (tid & ~63)) * 8));
        }
        #pragma unroll
        for (int i = 0; i < 4; i++) {
            int ck = i * 256 + tid;
            int r = ck >> 3, cc = ck & 7;
            int csw = (cc ^ (r & 7)) << 3;
            int rr = n0 + r; if (rr >= N) rr = N - 1;
            *(uint4*)&sW[ck * 8] = cvt8(Wf + (size_t)rr * K + k0 + csw);
        }
        __syncthreads();
        #pragma unroll
        for (int ks = 0; ks < 2; ks++) {
            f16x8 af[4], wv[4];
            int kc = ks * 4 + quad;
            #pragma unroll
            for (int i = 0; i < 4; i++) {
                int r = wm + i * 16 + cl;
                af[i] = *(const f16x8*)&sA[r * 64 + ((kc ^ (r & 7)) << 3)];
            }
            #pragma unroll
            for (int j = 0; j < 4; j++) {
                int r = wn + j * 16 + cl;
                wv[j] = *(const f16x8*)&sW[r * 64 + ((kc ^ (r & 7)) << 3)];
            }
            #pragma unroll
            for (int i = 0; i < 4; i++)
                #pragma unroll
                for (int j = 0; j < 4; j++)
                    acc[i][j] = __builtin_amdgcn_mfma_f32_16x16x32_f16(
                        af[i], wv[j], acc[i][j], 0, 0, 0);
        }
        __syncthreads();
    }
    if (blockIdx.x < 6) {
        #pragma unroll
        for (int i = 0; i < 4; i++) {
            int m = m0 + wm + i * 16 + quad * 4;
            #pragma unroll
            for (int j = 0; j < 4; j++) {
                int n = n0 + wn + j * 16 + cl;
                #pragma unroll
                for (int r = 0; r < 4; r++)
                    zx16[(size_t)(m + r) * 768 + n] = f2h(acc[i][j][r]);
            }
        }
    } else {
        if ((wid & 1) == 0 && cl < 2) {
            #pragma unroll
            for (int i = 0; i < 4; i++)
                #pragma unroll
                for (int r = 0; r < 4; r++)
                    sdt[cl][wm + i * 16 + quad * 4 + r] = acc[i][0][r];
        }
        __syncthreads();
        const int hh = tid >> 7, t = tid & 127;
        float raw = sdt[hh][t] + dt_bias[hh];
        float dt = fmaxf(raw, 0.f) + log1pf(__expf(-fabsf(raw)));
        dtb[(size_t)(m0 + t) * 2 + hh] = dt;
        float ad = -__expf(A_log[hh]) * dt;
        __syncthreads();
        sdt[hh][t] = ad;
        __syncthreads();
        for (int off = 1; off < 128; off <<= 1) {
            float add = (t >= off) ? sdt[hh][t - off] : 0.f;
            __syncthreads();
            sdt[hh][t] += add;
            __syncthreads();
        }
        Sb[(size_t)(m0 + t) * 2 + hh] = sdt[hh][t];
    }
}

// ---------------------------------------------------------------------------
// chunkstate + inlined conv. Grid (32,2,4), 512 thr.
// Stages raw x_h / B (131 rows w/ halo) from zx16, conv+silu, transposes into
// LDS (X^T unscaled -> also dumped to global xT; B^T scaled by w_s), then
// MFMA Hloc[p,n] = sum_s Xw. Writes Hb fp16.
// ---------------------------------------------------------------------------
__global__ __launch_bounds__(512) void chunkstate_conv_kernel(
    const u16* __restrict__ zx16, const float* __restrict__ cw,
    const float* __restrict__ cb, const float* __restrict__ dtb,
    const float* __restrict__ Sb, u16* __restrict__ xT, u16* __restrict__ Hb)
{
    __shared__ u16 raw[2560 * 8];     // 40 KB staging (131x128 + slack)
    __shared__ u16 XT[128 * 128];
    __shared__ u16 BT[128 * 128];
    __shared__ float scw[2][128][4];  // [0]=x(head h), [1]=B
    __shared__ float scb[2][128];
    __shared__ float ssw[128];
    const int c = blockIdx.x, h = blockIdx.y, b = blockIdx.z;
    const int tid = threadIdx.x, wid = tid >> 6, lane = tid & 63;
    const int quad = lane >> 4, cl = lane & 15;
    const int tok0 = b * LSEQ + c * 128;
    // conv weights + sw
    for (int idx = tid; idx < 256; idx += 512) {
        int grp = idx >> 7, j = idx & 127;
        int ch = grp ? (256 + j) : (128 * h + j);
        float4 w4 = *(const float4*)&cw[ch * 4];
        scw[grp][j][0] = w4.x; scw[grp][j][1] = w4.y;
        scw[grp][j][2] = w4.z; scw[grp][j][3] = w4.w;
        scb[grp][j] = cb[ch];
    }
    if (tid < 128) {
        float Sl = Sb[(size_t)(tok0 + 127) * 2 + h];
        ssw[tid] = __expf(Sl - Sb[(size_t)(tok0 + tid) * 2 + h])
                   * dtb[(size_t)(tok0 + tid) * 2 + h];
    }
    // stage raw X (zx cols 256+128h), rows tok0-3 .. tok0+127
    #pragma unroll
    for (int i = 0; i < 5; i++) {
        int ck = i * 512 + tid;
        int r = ck >> 4; if (r > 130) r = 130;
        int cc = ck & 15;
        int tok = tok0 - 3 + r; if (tok < 0) tok = 0;
        async_lds16(zx16 + (size_t)tok * 768 + 256 + 128 * h + ((cc ^ (r & 15)) << 3),
                    (void*)(raw + (i * 512 + (tid & ~63)) * 8));
    }
    __syncthreads();
    if (c == 0 && tid < 48) *(uint4*)&raw[tid * 8] = make_uint4(0, 0, 0, 0);
    __syncthreads();
    // conv X -> XT (transposed, swizzled)
    #pragma unroll
    for (int it = 0; it < 4; it++) {
        int idx = it * 512 + tid;
        int s = idx & 127, pg = idx >> 7;
        f16x8 v[4];
        #pragma unroll
        for (int k = 0; k < 4; k++) {
            int rr = s + k;
            v[k] = *(const f16x8*)&raw[rr * 128 + ((pg ^ (rr & 15)) << 3)];
        }
        #pragma unroll
        for (int j = 0; j < 8; j++) {
            int p = pg * 8 + j;
            float o = scb[0][p] + (float)v[0][j] * scw[0][p][0]
                    + (float)v[1][j] * scw[0][p][1]
                    + (float)v[2][j] * scw[0][p][2]
                    + (float)v[3][j] * scw[0][p][3];
            o = silu_f(o);
            XT[p * 128 + (((s >> 3) ^ (p & 15)) << 3) + (s & 7)] = f2h(o);
        }
    }
    __syncthreads();  // raw free; XT complete
    // dump XT -> global (unswizzled) ; concurrently stage raw B (zx cols 512)
    const size_t blk = ((size_t)((b * 2 + h) * 32 + c)) << 14;
    #pragma unroll
    for (int i = 0; i < 5; i++) {
        int ck = i * 512 + tid;
        int r = ck >> 4; if (r > 130) r = 130;
        int cc = ck & 15;
        int tok = tok0 - 3 + r; if (tok < 0) tok = 0;
        async_lds16(zx16 + (size_t)tok * 768 + 512 + ((cc ^ (r & 15)) << 3),
                    (void*)(raw + (i * 512 + (tid & ~63)) * 8));
    }
    #pragma unroll
    for (int it = 0; it < 4; it++) {
        int ck = it * 512 + tid;
        int r = ck >> 4, cc = ck & 15;
        uint4 q = *(const uint4*)&XT[r * 128 + ((cc ^ (r & 15)) << 3)];
        *(uint4*)&xT[blk + (size_t)r * 128 + cc * 8] = q;
    }
    __syncthreads();
    if (c == 0 && tid < 48) *(uint4*)&raw[tid * 8] = make_uint4(0, 0, 0, 0);
    __syncthreads();
    // conv B -> BT (transposed, swizzled, scaled by w_s)
    #pragma unroll
    for (int it = 0; it < 4; it++) {
        int idx = it * 512 + tid;
        int s = idx & 127, ng = idx >> 7;
        f16x8 v[4];
        #pragma unroll
        for (int k = 0; k < 4; k++) {
            int rr = s + k;
            v[k] = *(const f16x8*)&raw[rr * 128 + ((ng ^ (rr & 15)) << 3)];
        }
        float wsv = ssw[s];
        #pragma unroll
        for (int j = 0; j < 8; j++) {
            int n = ng * 8 + j;
            float o = scb[1][n] + (float)v[0][j] * scw[1][n][0]
                    + (float)v[1][j] * scw[1][n][1]
                    + (float)v[2][j] * scw[1][n][2]
                    + (float)v[3][j] * scw[1][n][3];
            o = silu_f(o) * wsv;
            BT[n * 128 + (((s >> 3) ^ (n & 15)) << 3) + (s & 7)] = f2h(o);
        }
    }
    __syncthreads();
    // MFMA: Hloc = X^T @ (w B)^T^T  (contract over s)
    const int wm = (wid >> 1) * 32, wn = (wid & 1) * 64;
    f32x4 acc[2][4];
    #pragma unroll
    for (int i = 0; i < 2; i++)
        #pragma unroll
        for (int j = 0; j < 4; j++) acc[i][j] = f32x4{0.f, 0.f, 0.f, 0.f};
    #pragma unroll
    for (int ks = 0; ks < 4; ks++) {
        f16x8 xa[2], bb[4];
        int kc = ks * 4 + quad;
        #pragma unroll
        for (int i = 0; i < 2; i++) {
            int r = wm + i * 16 + cl;
            xa[i] = *(const f16x8*)&XT[r * 128 + ((kc ^ (r & 15)) << 3)];
        }
        #pragma unroll
        for (int j = 0; j < 4; j++) {
            int r = wn + j * 16 + cl;
            bb[j] = *(const f16x8*)&BT[r * 128 + ((kc ^ (r & 15)) << 3)];
        }
        #pragma unroll
        for (int i = 0; i < 2; i++)
            #pragma unroll
            for (int j = 0; j < 4; j++)
                acc[i][j] = __builtin_amdgcn_mfma_f32_16x16x32_f16(
                    xa[i], bb[j], acc[i][j], 0, 0, 0);
    }
    u16* out = Hb + blk;
    #pragma unroll
    for (int i = 0; i < 2; i++)
        #pragma unroll
        for (int j = 0; j < 4; j++)
            #pragma unroll
            for (int r = 0; r < 4; r++)
                out[(size_t)(wm + i * 16 + quad * 4 + r) * 128 + wn + j * 16 + cl]
                    = f2h(acc[i][j][r]);
}

// ---------------------------------------------------------------------------
// Inter-chunk combine (fp32 accumulate); writes INCOMING state per chunk fp16.
// ---------------------------------------------------------------------------
__global__ __launch_bounds__(256) void statecombine_kernel(
    const float* __restrict__ Sb, const u16* __restrict__ Hb,
    u16* __restrict__ Hbf)
{
    const int e = blockIdx.x * 256 + threadIdx.x;
    const int h = blockIdx.y, b = blockIdx.z;
    const size_t base = ((size_t)((b * 2 + h) * 32)) << 14;
    float state = 0.f;
    for (int c = 0; c < 32; c++) {
        size_t idx = base + ((size_t)c << 14) + e;
        float v = h2f(Hb[idx]);
        Hbf[idx] = f2h(state);
        float dec = __expf(Sb[(size_t)(b * LSEQ + c * 128 + 127) * 2 + h]);
        state = dec * state + v;
    }
}

// ---------------------------------------------------------------------------
// Fused SSD output + inlined conv for B/C + D-skip + silu gate + 256-ch RMS.
// Grid (32, 4), 512 threads, ~137 KB LDS.
// ---------------------------------------------------------------------------
__global__ __launch_bounds__(512) void ssd_fused_conv_kernel(
    const u16* __restrict__ zx16, const u16* __restrict__ xT,
    const u16* __restrict__ Hbf, const float* __restrict__ dtb,
    const float* __restrict__ Sb, const float* __restrict__ cw,
    const float* __restrict__ cb, const float* __restrict__ gnw,
    const float* __restrict__ Dp, u16* __restrict__ y16)
{
    __shared__ u16 bufCW[2][128 * 128];  // [0]=C -> G0, [1]=B -> G1
    __shared__ u16 bufH[2][128 * 128];   // scratch for raw conv; then Hin; then X
    __shared__ float sS[2][128], sdt[2][128];
    __shared__ float scw2[2][128][4];    // [0]=C, [1]=B
    __shared__ float scb2[2][128];
    __shared__ float red[128][5];
    __shared__ float srstd[128];
    const int c = blockIdx.x, b = blockIdx.y;
    const int tid = threadIdx.x, wid = tid >> 6, lane = tid & 63;
    const int quad = lane >> 4, cl = lane & 15;
    const int tok0 = b * LSEQ + c * 128;
    const size_t blk0 = ((size_t)((b * 2 + 0) * 32 + c)) << 14;
    const size_t blk1 = ((size_t)((b * 2 + 1) * 32 + c)) << 14;
    u16* scratch = &bufH[0][0];          // 40 KB raw staging overlay
    // conv weights (C: 384+j, B: 256+j), sS/sdt
    for (int idx = tid; idx < 256; idx += 512) {
        int grp = idx >> 7, j = idx & 127;
        int ch = grp ? (256 + j) : (384 + j);
        float4 w4 = *(const float4*)&cw[ch * 4];
        scw2[grp][j][0] = w4.x; scw2[grp][j][1] = w4.y;
        scw2[grp][j][2] = w4.z; scw2[grp][j][3] = w4.w;
        scb2[grp][j] = cb[ch];
    }
    if (tid < 256) {
        int hh = tid >> 7, t = tid & 127;
        sS[hh][t] = Sb[(size_t)(tok0 + t) * 2 + hh];
        sdt[hh][t] = dtb[(size_t)(tok0 + t) * 2 + hh];
    }
    // ---- stage raw C (zx cols 640), conv -> bufCW[0] token-major
    #pragma unroll
    for (int i = 0; i < 5; i++) {
        int ck = i * 512 + tid;
        int r = ck >> 4; if (r > 130) r = 130;
        int cc = ck & 15;
        int tok = tok0 - 3 + r; if (tok < 0) tok = 0;
        async_lds16(zx16 + (size_t)tok * 768 + 640 + ((cc ^ (r & 15)) << 3),
                    (void*)(scratch + (i * 512 + (tid & ~63)) * 8));
    }
    __syncthreads();
    if (c == 0 && tid < 48) *(uint4*)&scratch[tid * 8] = make_uint4(0, 0, 0, 0);
    __syncthreads();
    #pragma unroll
    for (int it = 0; it < 4; it++) {
        int idx = it * 512 + tid;
        int t = idx & 127, ng = idx >> 7;
        f16x8 v[4];
        #pragma unroll
        for (int k = 0; k < 4; k++) {
            int rr = t + k;
            v[k] = *(const f16x8*)&scratch[rr * 128 + ((ng ^ (rr & 15)) << 3)];
        }
        union { u16 u[8]; uint4 q; } pk;
        #pragma unroll
        for (int j = 0; j < 8; j++) {
            int n = ng * 8 + j;
            float o = scb2[0][n] + (float)v[0][j] * scw2[0][n][0]
                    + (float)v[1][j] * scw2[0][n][1]
                    + (float)v[2][j] * scw2[0][n][2]
                    + (float)v[3][j] * scw2[0][n][3];
            pk.u[j] = f2h(silu_f(o));
        }
        *(uint4*)&bufCW[0][t * 128 + ((ng ^ (t & 15)) << 3)] = pk.q;
    }
    __syncthreads();
    // ---- stage raw B (zx cols 512), conv -> bufCW[1] token-major
    #pragma unroll
    for (int i = 0; i < 5; i++) {
        int ck = i * 512 + tid;
        int r = ck >> 4; if (r > 130) r = 130;
        int cc = ck & 15;
        int tok = tok0 - 3 + r; if (tok < 0) tok = 0;
        async_lds16(zx16 + (size_t)tok * 768 + 512 + ((cc ^ (r & 15)) << 3),
                    (void*)(scratch + (i * 512 + (tid & ~63)) * 8));
    }
    __syncthreads();
    if (c == 0 && tid < 48) *(uint4*)&scratch[tid * 8] = make_uint4(0, 0, 0, 0);
    __syncthreads();
    #pragma unroll
    for (int it = 0; it < 4; it++) {
        int idx = it * 512 + tid;
        int t = idx & 127, ng = idx >> 7;
        f16x8 v[4];
        #pragma unroll
        for (int k = 0; k < 4; k++) {
            int rr = t + k;
            v[k] = *(const f16x8*)&scratch[rr * 128 + ((ng ^ (rr & 15)) << 3)];
        }
        union { u16 u[8]; uint4 q; } pk;
        #pragma unroll
        for (int j = 0; j < 8; j++) {
            int n = ng * 8 + j;
            float o = scb2[1][n] + (float)v[0][j] * scw2[1][n][0]
                    + (float)v[1][j] * scw2[1][n][1]
                    + (float)v[2][j] * scw2[1][n][2]
                    + (float)v[3][j] * scw2[1][n][3];
            pk.u[j] = f2h(silu_f(o));
        }
        *(uint4*)&bufCW[1][t * 128 + ((ng ^ (t & 15)) << 3)] = pk.q;
    }
    __syncthreads();  // scratch free; B/C ready
    // ---- stage Hin (both heads) into bufH
    #pragma unroll
    for (int i = 0; i < 4; i++) {
        int ck = i * 512 + tid;
        int r = ck >> 4, cc = ck & 15;
        int csw = (cc ^ (r & 15)) << 3;
        int ldst = (i * 512 + (tid & ~63)) * 8;
        async_lds16(Hbf + blk0 + (size_t)r * 128 + csw, (void*)(&bufH[0][0] + ldst));
        async_lds16(Hbf + blk1 + (size_t)r * 128 + csw, (void*)(&bufH[1][0] + ldst));
    }
    __syncthreads();
    // ---- phase 1: Y_h = C @ Hin_h^T (waves 0-3: h=0; 4-7: h=1)
    const int h = wid >> 2, w2 = wid & 3;
    const int wm = (w2 >> 1) * 64, wn = (w2 & 1) * 64;
    f32x4 acc[4][4];
    #pragma unroll
    for (int i = 0; i < 4; i++)
        #pragma unroll
        for (int j = 0; j < 4; j++) acc[i][j] = f32x4{0.f, 0.f, 0.f, 0.f};
    #pragma unroll
    for (int ks = 0; ks < 4; ks++) {
        f16x8 ca[4], hb[4];
        int kc = ks * 4 + quad;
        #pragma unroll
        for (int i = 0; i < 4; i++) {
            int r = wm + i * 16 + cl;
            ca[i] = *(const f16x8*)&bufCW[0][r * 128 + ((kc ^ (r & 15)) << 3)];
        }
        #pragma unroll
        for (int j = 0; j < 4; j++) {
            int r = wn + j * 16 + cl;
            hb[j] = *(const f16x8*)&bufH[h][r * 128 + ((kc ^ (r & 15)) << 3)];
        }
        #pragma unroll
        for (int i = 0; i < 4; i++)
            #pragma unroll
            for (int j = 0; j < 4; j++)
                acc[i][j] = __builtin_amdgcn_mfma_f32_16x16x32_f16(
                    ca[i], hb[j], acc[i][j], 0, 0, 0);
    }
    #pragma unroll
    for (int i = 0; i < 4; i++)
        #pragma unroll
        for (int r = 0; r < 4; r++) {
            float e = __expf(sS[h][wm + i * 16 + quad * 4 + r]);
            #pragma unroll
            for (int j = 0; j < 4; j++) acc[i][j][r] *= e;
        }
    // ---- phase 2: S = C @ B^T (all 8 waves; 32x64 tiles)
    const int sm0 = (wid >> 1) * 32, sn0 = (wid & 1) * 64;
    f32x4 sacc[2][4];
    #pragma unroll
    for (int i = 0; i < 2; i++)
        #pragma unroll
        for (int j = 0; j < 4; j++) sacc[i][j] = f32x4{0.f, 0.f, 0.f, 0.f};
    #pragma unroll
    for (int ks = 0; ks < 4; ks++) {
        f16x8 cs[2], bs[4];
        int kc = ks * 4 + quad;
        #pragma unroll
        for (int i2 = 0; i2 < 2; i2++) {
            int r = sm0 + i2 * 16 + cl;
            cs[i2] = *(const f16x8*)&bufCW[0][r * 128 + ((kc ^ (r & 15)) << 3)];
        }
        #pragma unroll
        for (int j = 0; j < 4; j++) {
            int r = sn0 + j * 16 + cl;
            bs[j] = *(const f16x8*)&bufCW[1][r * 128 + ((kc ^ (r & 15)) << 3)];
        }
        #pragma unroll
        for (int i2 = 0; i2 < 2; i2++)
            #pragma unroll
            for (int j = 0; j < 4; j++)
                if (sm0 + i2 * 16 + 15 >= sn0 + j * 16)
                    sacc[i2][j] = __builtin_amdgcn_mfma_f32_16x16x32_f16(
                        cs[i2], bs[j], sacc[i2][j], 0, 0, 0);
    }
    __syncthreads();
    // stage X0, X1 over bufH while computing/writing G
    #pragma unroll
    for (int i = 0; i < 4; i++) {
        int ck = i * 512 + tid;
        int r = ck >> 4, cc = ck & 15;
        int csw = (cc ^ (r & 15)) << 3;
        int ldst = (i * 512 + (tid & ~63)) * 8;
        async_lds16(xT + blk0 + (size_t)r * 128 + csw, (void*)(&bufH[0][0] + ldst));
        async_lds16(xT + blk1 + (size_t)r * 128 + csw, (void*)(&bufH[1][0] + ldst));
    }
    #pragma unroll
    for (int hh = 0; hh < 2; hh++)
        #pragma unroll
        for (int i2 = 0; i2 < 2; i2++)
            #pragma unroll
            for (int r = 0; r < 4; r++) {
                int t = sm0 + i2 * 16 + quad * 4 + r;
                float Stv = sS[hh][t];
                #pragma unroll
                for (int j = 0; j < 4; j++) {
                    int s = sn0 + j * 16 + cl;
                    float gv = 0.f;
                    if (s <= t)
                        gv = sacc[i2][j][r] * __expf(Stv - sS[hh][s]) * sdt[hh][s];
                    bufCW[hh][t * 128 + (((s >> 3) ^ (t & 15)) << 3) + (s & 7)] = f2h(gv);
                }
            }
    __syncthreads();
    // ---- phase 3: Y_h += G_h @ X_h
    #pragma unroll
    for (int ks = 0; ks < 4; ks++) {
        f16x8 ga[4], xb[4];
        int kc = ks * 4 + quad;
        #pragma unroll
        for (int i = 0; i < 4; i++) {
            int r = wm + i * 16 + cl;
            ga[i] = *(const f16x8*)&bufCW[h][r * 128 + ((kc ^ (r & 15)) << 3)];
        }
        #pragma unroll
        for (int j = 0; j < 4; j++) {
            int r = wn + j * 16 + cl;
            xb[j] = *(const f16x8*)&bufH[h][r * 128 + ((kc ^ (r & 15)) << 3)];
        }
        #pragma unroll
        for (int i = 0; i < 4; i++)
            #pragma unroll
            for (int j = 0; j < 4; j++)
                acc[i][j] = __builtin_amdgcn_mfma_f32_16x16x32_f16(
                    ga[i], xb[j], acc[i][j], 0, 0, 0);
    }
    // ---- epilogue: D-skip + silu gate + 256-ch RMS -> y16
    const float dco = Dp[h];
    #pragma unroll
    for (int i = 0; i < 4; i++)
        #pragma unroll
        for (int r = 0; r < 4; r++) {
            int t = wm + i * 16 + quad * 4 + r;
            float ssp = 0.f;
            #pragma unroll
            for (int j = 0; j < 4; j++) {
                int p = wn + j * 16 + cl;
                float xv = h2f(bufH[h][p * 128 + (((t >> 3) ^ (p & 15)) << 3) + (t & 7)]);
                float zv = h2f(zx16[(size_t)(tok0 + t) * 768 + h * 128 + p]);
                float g = (acc[i][j][r] + dco * xv) * silu_f(zv);
                acc[i][j][r] = g;
                ssp += g * g;
            }
            ssp += __shfl_xor(ssp, 1);
            ssp += __shfl_xor(ssp, 2);
            ssp += __shfl_xor(ssp, 4);
            ssp += __shfl_xor(ssp, 8);
            if (cl == 0) red[t][h * 2 + (wn >> 6)] = ssp;
        }
    __syncthreads();
    if (tid < 128)
        srstd[tid] = rsqrtf((red[tid][0] + red[tid][1] + red[tid][2] + red[tid][3])
                            * (1.f / 256.f) + 1e-5f);
    __syncthreads();
    #pragma unroll
    for (int i = 0; i < 4; i++)
        #pragma unroll
        for (int r = 0; r < 4; r++) {
            int t = wm + i * 16 + quad * 4 + r;
            float rstd = srstd[t];
            u16* row = y16 + (size_t)(tok0 + t) * 256;
            #pragma unroll
            for (int j = 0; j < 4; j++) {
                int p = wn + j * 16 + cl;
                int e = h * 128 + p;
                row[e] = f2h(acc[i][j][r] * rstd * gnw[e]);
            }
        }
}

// ---------------------------------------------------------------------------
// out-proj GEMM (K=256, N=128, BM=64) + residual + RMS. W inline-cvt fp32.
// mode 1: v=acc+hbuf; hbuf=v; hn16 = fp16(rms(v)*rmsw)
// mode 3: v=acc+hbuf; val = xp + rms(v)*rmsw; then FUSED final projection:
//         dout(64 cols) = val @ out_w^T + out_b  (out_w fp32 inline-cvt)
// ---------------------------------------------------------------------------
__global__ __launch_bounds__(256) void gemm_outrms_kernel(
    const u16* __restrict__ A, const float* __restrict__ Wf,
    const float* __restrict__ rmsw, u16* __restrict__ xp16,
    u16* __restrict__ hbuf16, u16* __restrict__ hn16,
    const float* __restrict__ out_wf, const float* __restrict__ out_b,
    float* __restrict__ dout, int mode)
{
    __shared__ u16 sA[64 * 64];
    __shared__ u16 sW[128 * 64];
    __shared__ float red[64][33];
    __shared__ float srstd[64];
    __shared__ u16 hn2[64 * 128];
    __shared__ u16 ow[64 * 128];
    const int K = 256;
    const int m0 = blockIdx.y * 64;
    const int tid = threadIdx.x, wid = tid >> 6, lane = tid & 63;
    const int wm = (wid >> 1) * 32, wn = (wid & 1) * 64;
    const int quad = lane >> 4, cl = lane & 15;
    f32x4 acc[2][4];
    #pragma unroll
    for (int i = 0; i < 2; i++)
        #pragma unroll
        for (int j = 0; j < 4; j++) acc[i][j] = f32x4{0.f, 0.f, 0.f, 0.f};

    for (int k0 = 0; k0 < K; k0 += 64) {
        #pragma unroll
        for (int i = 0; i < 2; i++) {
            int ck = i * 256 + tid;
            int r = ck >> 3, cc = ck & 7;
            int csw = (cc ^ (r & 7)) << 3;
            async_lds16(A + (size_t)(m0 + r) * K + k0 + csw,
                        (void*)(sA + (i * 256 + (tid & ~63)) * 8));
        }
        #pragma unroll
        for (int i = 0; i < 4; i++) {
            int ck = i * 256 + tid;
            int r = ck >> 3, cc = ck & 7;
            int csw = (cc ^ (r & 7)) << 3;
            *(uint4*)&sW[ck * 8] = cvt8(Wf + (size_t)r * K + k0 + csw);
        }
        __syncthreads();
        #pragma unroll
        for (int ks = 0; ks < 2; ks++) {
            f16x8 af[2], wv[4];
            int kc = ks * 4 + quad;
            #pragma unroll
            for (int i = 0; i < 2; i++) {
                int r = wm + i * 16 + cl;
                af[i] = *(const f16x8*)&sA[r * 64 + ((kc ^ (r & 7)) << 3)];
            }
            #pragma unroll
            for (int j = 0; j < 4; j++) {
                int r = wn + j * 16 + cl;
                wv[j] = *(const f16x8*)&sW[r * 64 + ((kc ^ (r & 7)) << 3)];
            }
            #pragma unroll
            for (int i = 0; i < 2; i++)
                #pragma unroll
                for (int j = 0; j < 4; j++)
                    acc[i][j] = __builtin_amdgcn_mfma_f32_16x16x32_f16(
                        af[i], wv[j], acc[i][j], 0, 0, 0);
        }
        __syncthreads();
    }
    const int slot = (wid & 1) * 16 + cl;
    #pragma unroll
    for (int i = 0; i < 2; i++)
        #pragma unroll
        for (int r = 0; r < 4; r++) {
            int t = wm + i * 16 + quad * 4 + r;
            size_t ob = (size_t)(m0 + t) * 128;
            float ssp = 0.f;
            #pragma unroll
            for (int j = 0; j < 4; j++) {
                int n = wn + j * 16 + cl;
                float v = acc[i][j][r] + h2f(hbuf16[ob + n]);
                acc[i][j][r] = v;
                ssp += v * v;
            }
            red[t][slot] = ssp;
        }
    __syncthreads();
    if (tid < 64) {
        float s = 0.f;
        #pragma unroll
        for (int sl = 0; sl < 32; sl++) s += red[tid][sl];
        srstd[tid] = rsqrtf(s * (1.f / 128.f) + 1e-5f);
    }
    __syncthreads();
    #pragma unroll
    for (int i = 0; i < 2; i++)
        #pragma unroll
        for (int r = 0; r < 4; r++) {
            int t = wm + i * 16 + quad * 4 + r;
            size_t ob = (size_t)(m0 + t) * 128;
            float rstd = srstd[t];
            #pragma unroll
            for (int j = 0; j < 4; j++) {
                int n = wn + j * 16 + cl;
                float v = acc[i][j][r];
                float val = v * rstd * rmsw[n];
                if (mode == 1) {
                    hbuf16[ob + n] = f2h(v);
                    hn16[ob + n] = f2h(val);
                } else {
                    val += h2f(xp16[ob + n]);
                    hn2[t * 128 + (((n >> 3) ^ (t & 15)) << 3) + (n & 7)] = f2h(val);
                }
            }
        }
    if (mode == 1) return;
    // ---- fused final projection: dout = hn2 @ out_w^T + out_b
    #pragma unroll
    for (int i = 0; i < 4; i++) {
        int ck = i * 256 + tid;
        int rr = ck >> 4, cc = ck & 15;
        int csw = (cc ^ (rr & 15)) << 3;
        *(uint4*)&ow[ck * 8] = cvt8(out_wf + (size_t)rr * 128 + csw);
    }
    __syncthreads();
    const int wm4 = (wid >> 1) * 32, wn4 = (wid & 1) * 32;
    f32x4 acc2[2][2];
    #pragma unroll
    for (int i = 0; i < 2; i++)
        #pragma unroll
        for (int j = 0; j < 2; j++) acc2[i][j] = f32x4{0.f, 0.f, 0.f, 0.f};
    #pragma unroll
    for (int ks = 0; ks < 4; ks++) {
        f16x8 af2[2], wf2[2];
        int kc = ks * 4 + quad;
        #pragma unroll
        for (int i = 0; i < 2; i++) {
            int r = wm4 + i * 16 + cl;
            af2[i] = *(const f16x8*)&hn2[r * 128 + ((kc ^ (r & 15)) << 3)];
        }
        #pragma unroll
        for (int j = 0; j < 2; j++) {
            int rr = wn4 + j * 16 + cl;
            wf2[j] = *(const f16x8*)&ow[rr * 128 + ((kc ^ (rr & 15)) << 3)];
        }
        #pragma unroll
        for (int i = 0; i < 2; i++)
            #pragma unroll
            for (int j = 0; j < 2; j++)
                acc2[i][j] = __builtin_amdgcn_mfma_f32_16x16x32_f16(
                    af2[i], wf2[j], acc2[i][j], 0, 0, 0);
    }
    #pragma unroll
    for (int i = 0; i < 2; i++) {
        int m = m0 + wm4 + i * 16 + quad * 4;
        #pragma unroll
        for (int j = 0; j < 2; j++) {
            int n = wn4 + j * 16 + cl;
            float bv = out_b[n];
            #pragma unroll
            for (int r = 0; r < 4; r++)
                dout[(size_t)(m + r) * 64 + n] = acc2[i][j][r] + bv;
        }
    }
}

// ---------------------------------------------------------------------------
extern "C" void kernel_launch(void* const* d_in, const int* in_sizes, int n_in,
                              void* d_out, int out_size, void* d_ws, size_t ws_size,
                              hipStream_t stream)
{
    (void)in_sizes; (void)n_in; (void)out_size; (void)ws_size;
    const float* x       = (const float*)d_in[0];
    const float* in_w    = (const float*)d_in[1];
    const float* in_b    = (const float*)d_in[2];
    const float* out_w   = (const float*)d_in[3];
    const float* out_b   = (const float*)d_in[4];
    const float* l_rms_w = (const float*)d_in[5];
    const float* l_in_w  = (const float*)d_in[6];
    const float* conv_w  = (const float*)d_in[7];
    const float* conv_b  = (const float*)d_in[8];
    const float* dt_bias = (const float*)d_in[9];
    const float* A_log   = (const float*)d_in[10];
    const float* D_p     = (const float*)d_in[11];
    const float* gnorm_w = (const float*)d_in[12];
    const float* l_out_w = (const float*)d_in[13];
    const float* fnorm_w = (const float*)d_in[14];

    char* w = (char*)d_ws;
    u16*   xp16   = (u16*)(w);                  // 4.19 MB
    u16*   hbuf16 = (u16*)(w + 4194304);        // 4.19 MB
    u16*   hn16   = (u16*)(w + 8388608);        // 4.19 MB
    u16*   zx16   = (u16*)(w + 12582912);       // 25.17 MB
    float* dtb    = (float*)(w + 37748736);     // 131 KB
    float* Sb     = (float*)(w + 37879808);     // 131 KB
    u16*   Hb     = (u16*)(w + 38010880);       // 8.39 MB
    u16*   Hbf    = (u16*)(w + 46399488);       // 8.39 MB
    u16*   xT     = (u16*)(w + 54788096);       // 8.39 MB
    u16*   y16    = (u16*)(w + 63176704);       // 8.39 MB

    gemm_rms0_kernel<<<dim3(1, 256), 256, 0, stream>>>(
        x, in_w, in_b, l_rms_w, xp16, hbuf16, hn16);

    for (int i = 0; i < 2; i++) {
        gemm_inproj_kernel<<<dim3(7, 128), 256, 0, stream>>>(
            hn16, l_in_w + (size_t)i * 770 * 128, zx16, dtb, Sb,
            dt_bias + i * 2, A_log + i * 2);
        chunkstate_conv_kernel<<<dim3(32, 2, 4), 512, 0, stream>>>(
            zx16, conv_w + i * 2048, conv_b + i * 512, dtb, Sb, xT, Hb);
        statecombine_kernel<<<dim3(64, 2, 4), 256, 0, stream>>>(Sb, Hb, Hbf);
        ssd_fused_conv_kernel<<<dim3(32, 4), 512, 0, stream>>>(
            zx16, xT, Hbf, dtb, Sb, conv_w + i * 2048, conv_b + i * 512,
            gnorm_w + i * 256, D_p + i * 2, y16);
        gemm_outrms_kernel<<<dim3(1, 256), 256, 0, stream>>>(
            y16, l_out_w + (size_t)i * 128 * 256,
            (i == 0) ? (l_rms_w + 128) : fnorm_w, xp16, hbuf16, hn16,
            out_w, out_b, (float*)d_out, (i == 0) ? 1 : 3);
    }
}

// Round 9
// 231.433 us; speedup vs baseline: 3.0598x; 1.0638x over previous
//
#include <hip/hip_runtime.h>
#include <cstddef>
#include <cstdint>

// MambaDoc — round 9: per-head SSD (256 blocks, full CU coverage).
// Gated 256-ch RMS decoupled from SSD via linearity: ssd writes raw
// g=(Y+Dx)*silu(z); out-proj computes rstd[t] in a prologue, folds gnw into
// the weight cvt, and scales its GEMM term by rstd[t]. X^T stays LDS-resident
// in ssd (xT global buffer deleted); X/B/C conv'd in-kernel per head.

#define LSEQ 4096
#define MTOK 16384

typedef unsigned short u16;
typedef _Float16 f16x8 __attribute__((ext_vector_type(8)));
typedef float f32x4 __attribute__((ext_vector_type(4)));

__device__ __forceinline__ u16 f2h(float x) {
    return __builtin_bit_cast(u16, (_Float16)x);
}
__device__ __forceinline__ float h2f(u16 u) {
    return (float)__builtin_bit_cast(_Float16, u);
}
__device__ __forceinline__ float silu_f(float x) { return x / (1.f + __expf(-x)); }

__device__ __forceinline__ void async_lds16(const void* g, void* l) {
    __builtin_amdgcn_global_load_lds(
        (const __attribute__((address_space(1))) unsigned int*)g,
        (__attribute__((address_space(3))) unsigned int*)l, 16, 0, 0);
}

__device__ __forceinline__ uint4 cvt8(const float* __restrict__ src) {
    float4 a = *(const float4*)src;
    float4 b = *(const float4*)(src + 4);
    union { u16 u[8]; uint4 q; } pk;
    pk.u[0] = f2h(a.x); pk.u[1] = f2h(a.y); pk.u[2] = f2h(a.z); pk.u[3] = f2h(a.w);
    pk.u[4] = f2h(b.x); pk.u[5] = f2h(b.y); pk.u[6] = f2h(b.z); pk.u[7] = f2h(b.w);
    return pk.q;
}

// weight cvt with gnw column-fold
__device__ __forceinline__ uint4 cvt8g(const float* __restrict__ src,
                                       const float* __restrict__ gw) {
    float4 a = *(const float4*)src;
    float4 b = *(const float4*)(src + 4);
    float4 ga = *(const float4*)gw;
    float4 gb = *(const float4*)(gw + 4);
    union { u16 u[8]; uint4 q; } pk;
    pk.u[0] = f2h(a.x * ga.x); pk.u[1] = f2h(a.y * ga.y);
    pk.u[2] = f2h(a.z * ga.z); pk.u[3] = f2h(a.w * ga.w);
    pk.u[4] = f2h(b.x * gb.x); pk.u[5] = f2h(b.y * gb.y);
    pk.u[6] = f2h(b.z * gb.z); pk.u[7] = f2h(b.w * gb.w);
    return pk.q;
}

// ---------------------------------------------------------------------------
// Initial projection + fused RMSNorm. BM=64, grid (1,256). (unchanged R8)
// ---------------------------------------------------------------------------
__global__ __launch_bounds__(256) void gemm_rms0_kernel(
    const float* __restrict__ xf, const float* __restrict__ wf,
    const float* __restrict__ bias, const float* __restrict__ rmsw,
    u16* __restrict__ xp16, u16* __restrict__ hbuf16, u16* __restrict__ hn16)
{
    __shared__ u16 sA[64 * 64];
    __shared__ u16 sW[128 * 64];
    __shared__ float red[64][33];
    __shared__ float srstd[64];
    const int m0 = blockIdx.y * 64;
    const int tid = threadIdx.x, wid = tid >> 6, lane = tid & 63;
    const int wm = (wid >> 1) * 32, wn = (wid & 1) * 64;
    const int quad = lane >> 4, cl = lane & 15;
    #pragma unroll
    for (int i = 0; i < 2; i++) {
        int ck = i * 256 + tid;
        int r = ck >> 3, cc = ck & 7;
        int csw = (cc ^ (r & 7)) << 3;
        *(uint4*)&sA[ck * 8] = cvt8(xf + (size_t)(m0 + r) * 64 + csw);
    }
    #pragma unroll
    for (int i = 0; i < 4; i++) {
        int ck = i * 256 + tid;
        int r = ck >> 3, cc = ck & 7;
        int csw = (cc ^ (r & 7)) << 3;
        *(uint4*)&sW[ck * 8] = cvt8(wf + (size_t)r * 64 + csw);
    }
    __syncthreads();
    f32x4 acc[2][4];
    #pragma unroll
    for (int i = 0; i < 2; i++)
        #pragma unroll
        for (int j = 0; j < 4; j++) acc[i][j] = f32x4{0.f, 0.f, 0.f, 0.f};
    #pragma unroll
    for (int ks = 0; ks < 2; ks++) {
        f16x8 af[2], wv[4];
        int kc = ks * 4 + quad;
        #pragma unroll
        for (int i = 0; i < 2; i++) {
            int r = wm + i * 16 + cl;
            af[i] = *(const f16x8*)&sA[r * 64 + ((kc ^ (r & 7)) << 3)];
        }
        #pragma unroll
        for (int j = 0; j < 4; j++) {
            int r = wn + j * 16 + cl;
            wv[j] = *(const f16x8*)&sW[r * 64 + ((kc ^ (r & 7)) << 3)];
        }
        #pragma unroll
        for (int i = 0; i < 2; i++)
            #pragma unroll
            for (int j = 0; j < 4; j++)
                acc[i][j] = __builtin_amdgcn_mfma_f32_16x16x32_f16(
                    af[i], wv[j], acc[i][j], 0, 0, 0);
    }
    const int slot = (wid & 1) * 16 + cl;
    #pragma unroll
    for (int i = 0; i < 2; i++)
        #pragma unroll
        for (int r = 0; r < 4; r++) {
            int t = wm + i * 16 + quad * 4 + r;
            float ssp = 0.f;
            #pragma unroll
            for (int j = 0; j < 4; j++) {
                int n = wn + j * 16 + cl;
                float v = acc[i][j][r] + bias[n];
                acc[i][j][r] = v;
                ssp += v * v;
            }
            red[t][slot] = ssp;
        }
    __syncthreads();
    if (tid < 64) {
        float s = 0.f;
        #pragma unroll
        for (int sl = 0; sl < 32; sl++) s += red[tid][sl];
        srstd[tid] = rsqrtf(s * (1.f / 128.f) + 1e-5f);
    }
    __syncthreads();
    #pragma unroll
    for (int i = 0; i < 2; i++)
        #pragma unroll
        for (int r = 0; r < 4; r++) {
            int t = wm + i * 16 + quad * 4 + r;
            size_t ob = (size_t)(m0 + t) * 128;
            float rstd = srstd[t];
            #pragma unroll
            for (int j = 0; j < 4; j++) {
                int n = wn + j * 16 + cl;
                float v = acc[i][j][r];
                u16 vh = f2h(v);
                xp16[ob + n] = vh;
                hbuf16[ob + n] = vh;
                hn16[ob + n] = f2h(v * rstd * rmsw[n]);
            }
        }
}

// ---------------------------------------------------------------------------
// in_proj GEMM fp16 (K=128). Grid (7, 128). (unchanged R8)
// ---------------------------------------------------------------------------
__global__ __launch_bounds__(256) void gemm_inproj_kernel(
    const u16* __restrict__ A, const float* __restrict__ Wf,
    u16* __restrict__ zx16, float* __restrict__ dtb, float* __restrict__ Sb,
    const float* __restrict__ dt_bias, const float* __restrict__ A_log)
{
    __shared__ u16 sA[128 * 64];
    __shared__ u16 sW[128 * 64];
    __shared__ float sdt[2][128];
    const int K = 128, N = 770;
    const int n0 = blockIdx.x * 128, m0 = blockIdx.y * 128;
    const int tid = threadIdx.x, wid = tid >> 6, lane = tid & 63;
    const int wm = (wid >> 1) * 64, wn = (wid & 1) * 64;
    const int quad = lane >> 4, cl = lane & 15;
    f32x4 acc[4][4];
    #pragma unroll
    for (int i = 0; i < 4; i++)
        #pragma unroll
        for (int j = 0; j < 4; j++) acc[i][j] = f32x4{0.f, 0.f, 0.f, 0.f};

    for (int k0 = 0; k0 < K; k0 += 64) {
        #pragma unroll
        for (int i = 0; i < 4; i++) {
            int ck = i * 256 + tid;
            int r = ck >> 3, cc = ck & 7;
            int csw = (cc ^ (r & 7)) << 3;
            async_lds16(A + (size_t)(m0 + r) * K + k0 + csw,
                        (void*)(sA + (i * 256 + (tid & ~63)) * 8));
        }
        #pragma unroll
        for (int i = 0; i < 4; i++) {
            int ck = i * 256 + tid;
            int r = ck >> 3, cc = ck & 7;
            int csw = (cc ^ (r & 7)) << 3;
            int rr = n0 + r; if (rr >= N) rr = N - 1;
            *(uint4*)&sW[ck * 8] = cvt8(Wf + (size_t)rr * K + k0 + csw);
        }
        __syncthreads();
        #pragma unroll
        for (int ks = 0; ks < 2; ks++) {
            f16x8 af[4], wv[4];
            int kc = ks * 4 + quad;
            #pragma unroll
            for (int i = 0; i < 4; i++) {
                int r = wm + i * 16 + cl;
                af[i] = *(const f16x8*)&sA[r * 64 + ((kc ^ (r & 7)) << 3)];
            }
            #pragma unroll
            for (int j = 0; j < 4; j++) {
                int r = wn + j * 16 + cl;
                wv[j] = *(const f16x8*)&sW[r * 64 + ((kc ^ (r & 7)) << 3)];
            }
            #pragma unroll
            for (int i = 0; i < 4; i++)
                #pragma unroll
                for (int j = 0; j < 4; j++)
                    acc[i][j] = __builtin_amdgcn_mfma_f32_16x16x32_f16(
                        af[i], wv[j], acc[i][j], 0, 0, 0);
        }
        __syncthreads();
    }
    if (blockIdx.x < 6) {
        #pragma unroll
        for (int i = 0; i < 4; i++) {
            int m = m0 + wm + i * 16 + quad * 4;
            #pragma unroll
            for (int j = 0; j < 4; j++) {
                int n = n0 + wn + j * 16 + cl;
                #pragma unroll
                for (int r = 0; r < 4; r++)
                    zx16[(size_t)(m + r) * 768 + n] = f2h(acc[i][j][r]);
            }
        }
    } else {
        if ((wid & 1) == 0 && cl < 2) {
            #pragma unroll
            for (int i = 0; i < 4; i++)
                #pragma unroll
                for (int r = 0; r < 4; r++)
                    sdt[cl][wm + i * 16 + quad * 4 + r] = acc[i][0][r];
        }
        __syncthreads();
        const int hh = tid >> 7, t = tid & 127;
        float raw = sdt[hh][t] + dt_bias[hh];
        float dt = fmaxf(raw, 0.f) + log1pf(__expf(-fabsf(raw)));
        dtb[(size_t)(m0 + t) * 2 + hh] = dt;
        float ad = -__expf(A_log[hh]) * dt;
        __syncthreads();
        sdt[hh][t] = ad;
        __syncthreads();
        for (int off = 1; off < 128; off <<= 1) {
            float add = (t >= off) ? sdt[hh][t - off] : 0.f;
            __syncthreads();
            sdt[hh][t] += add;
            __syncthreads();
        }
        Sb[(size_t)(m0 + t) * 2 + hh] = sdt[hh][t];
    }
}

// ---------------------------------------------------------------------------
// chunkstate + inlined conv (no xT dump). Grid (32,2,4), 512 thr.
// ---------------------------------------------------------------------------
__global__ __launch_bounds__(512) void chunkstate_conv_kernel(
    const u16* __restrict__ zx16, const float* __restrict__ cw,
    const float* __restrict__ cb, const float* __restrict__ dtb,
    const float* __restrict__ Sb, u16* __restrict__ Hb)
{
    __shared__ u16 raw[2560 * 8];
    __shared__ u16 XT[128 * 128];
    __shared__ u16 BT[128 * 128];
    __shared__ float scw[2][128][4];
    __shared__ float scb[2][128];
    __shared__ float ssw[128];
    const int c = blockIdx.x, h = blockIdx.y, b = blockIdx.z;
    const int tid = threadIdx.x, wid = tid >> 6, lane = tid & 63;
    const int quad = lane >> 4, cl = lane & 15;
    const int tok0 = b * LSEQ + c * 128;
    for (int idx = tid; idx < 256; idx += 512) {
        int grp = idx >> 7, j = idx & 127;
        int ch = grp ? (256 + j) : (128 * h + j);
        float4 w4 = *(const float4*)&cw[ch * 4];
        scw[grp][j][0] = w4.x; scw[grp][j][1] = w4.y;
        scw[grp][j][2] = w4.z; scw[grp][j][3] = w4.w;
        scb[grp][j] = cb[ch];
    }
    if (tid < 128) {
        float Sl = Sb[(size_t)(tok0 + 127) * 2 + h];
        ssw[tid] = __expf(Sl - Sb[(size_t)(tok0 + tid) * 2 + h])
                   * dtb[(size_t)(tok0 + tid) * 2 + h];
    }
    #pragma unroll
    for (int i = 0; i < 5; i++) {
        int ck = i * 512 + tid;
        int r = ck >> 4; if (r > 130) r = 130;
        int cc = ck & 15;
        int tok = tok0 - 3 + r; if (tok < 0) tok = 0;
        async_lds16(zx16 + (size_t)tok * 768 + 256 + 128 * h + ((cc ^ (r & 15)) << 3),
                    (void*)(raw + (i * 512 + (tid & ~63)) * 8));
    }
    __syncthreads();
    if (c == 0 && tid < 48) *(uint4*)&raw[tid * 8] = make_uint4(0, 0, 0, 0);
    __syncthreads();
    #pragma unroll
    for (int it = 0; it < 4; it++) {
        int idx = it * 512 + tid;
        int s = idx & 127, pg = idx >> 7;
        f16x8 v[4];
        #pragma unroll
        for (int k = 0; k < 4; k++) {
            int rr = s + k;
            v[k] = *(const f16x8*)&raw[rr * 128 + ((pg ^ (rr & 15)) << 3)];
        }
        #pragma unroll
        for (int j = 0; j < 8; j++) {
            int p = pg * 8 + j;
            float o = scb[0][p] + (float)v[0][j] * scw[0][p][0]
                    + (float)v[1][j] * scw[0][p][1]
                    + (float)v[2][j] * scw[0][p][2]
                    + (float)v[3][j] * scw[0][p][3];
            o = silu_f(o);
            XT[p * 128 + (((s >> 3) ^ (p & 15)) << 3) + (s & 7)] = f2h(o);
        }
    }
    __syncthreads();
    #pragma unroll
    for (int i = 0; i < 5; i++) {
        int ck = i * 512 + tid;
        int r = ck >> 4; if (r > 130) r = 130;
        int cc = ck & 15;
        int tok = tok0 - 3 + r; if (tok < 0) tok = 0;
        async_lds16(zx16 + (size_t)tok * 768 + 512 + ((cc ^ (r & 15)) << 3),
                    (void*)(raw + (i * 512 + (tid & ~63)) * 8));
    }
    __syncthreads();
    if (c == 0 && tid < 48) *(uint4*)&raw[tid * 8] = make_uint4(0, 0, 0, 0);
    __syncthreads();
    #pragma unroll
    for (int it = 0; it < 4; it++) {
        int idx = it * 512 + tid;
        int s = idx & 127, ng = idx >> 7;
        f16x8 v[4];
        #pragma unroll
        for (int k = 0; k < 4; k++) {
            int rr = s + k;
            v[k] = *(const f16x8*)&raw[rr * 128 + ((ng ^ (rr & 15)) << 3)];
        }
        float wsv = ssw[s];
        #pragma unroll
        for (int j = 0; j < 8; j++) {
            int n = ng * 8 + j;
            float o = scb[1][n] + (float)v[0][j] * scw[1][n][0]
                    + (float)v[1][j] * scw[1][n][1]
                    + (float)v[2][j] * scw[1][n][2]
                    + (float)v[3][j] * scw[1][n][3];
            o = silu_f(o) * wsv;
            BT[n * 128 + (((s >> 3) ^ (n & 15)) << 3) + (s & 7)] = f2h(o);
        }
    }
    __syncthreads();
    const size_t blk = ((size_t)((b * 2 + h) * 32 + c)) << 14;
    const int wm = (wid >> 1) * 32, wn = (wid & 1) * 64;
    f32x4 acc[2][4];
    #pragma unroll
    for (int i = 0; i < 2; i++)
        #pragma unroll
        for (int j = 0; j < 4; j++) acc[i][j] = f32x4{0.f, 0.f, 0.f, 0.f};
    #pragma unroll
    for (int ks = 0; ks < 4; ks++) {
        f16x8 xa[2], bb[4];
        int kc = ks * 4 + quad;
        #pragma unroll
        for (int i = 0; i < 2; i++) {
            int r = wm + i * 16 + cl;
            xa[i] = *(const f16x8*)&XT[r * 128 + ((kc ^ (r & 15)) << 3)];
        }
        #pragma unroll
        for (int j = 0; j < 4; j++) {
            int r = wn + j * 16 + cl;
            bb[j] = *(const f16x8*)&BT[r * 128 + ((kc ^ (r & 15)) << 3)];
        }
        #pragma unroll
        for (int i = 0; i < 2; i++)
            #pragma unroll
            for (int j = 0; j < 4; j++)
                acc[i][j] = __builtin_amdgcn_mfma_f32_16x16x32_f16(
                    xa[i], bb[j], acc[i][j], 0, 0, 0);
    }
    u16* out = Hb + blk;
    #pragma unroll
    for (int i = 0; i < 2; i++)
        #pragma unroll
        for (int j = 0; j < 4; j++)
            #pragma unroll
            for (int r = 0; r < 4; r++)
                out[(size_t)(wm + i * 16 + quad * 4 + r) * 128 + wn + j * 16 + cl]
                    = f2h(acc[i][j][r]);
}

// ---------------------------------------------------------------------------
// Inter-chunk combine. (unchanged R8)
// ---------------------------------------------------------------------------
__global__ __launch_bounds__(256) void statecombine_kernel(
    const float* __restrict__ Sb, const u16* __restrict__ Hb,
    u16* __restrict__ Hbf)
{
    const int e = blockIdx.x * 256 + threadIdx.x;
    const int h = blockIdx.y, b = blockIdx.z;
    const size_t base = ((size_t)((b * 2 + h) * 32)) << 14;
    float state = 0.f;
    for (int c = 0; c < 32; c++) {
        size_t idx = base + ((size_t)c << 14) + e;
        float v = h2f(Hb[idx]);
        Hbf[idx] = f2h(state);
        float dec = __expf(Sb[(size_t)(b * LSEQ + c * 128 + 127) * 2 + h]);
        state = dec * state + v;
    }
}

// ---------------------------------------------------------------------------
// Per-head fused SSD: conv X/B/C in-kernel, X^T LDS-resident, 3 MFMA phases,
// epilogue g = (Y + D*x)*silu(z) (NO rms — handled in out-proj).
// Grid (32,2,4) = 256 blocks, 512 thr, ~145 KB LDS.
// ---------------------------------------------------------------------------
__global__ __launch_bounds__(512) void ssd_ph_kernel(
    const u16* __restrict__ zx16, const u16* __restrict__ Hbf,
    const float* __restrict__ dtb, const float* __restrict__ Sb,
    const float* __restrict__ cw, const float* __restrict__ cb,
    const float* __restrict__ Dp, u16* __restrict__ g16)
{
    __shared__ u16 raw[2560 * 8];     // staging -> Hin -> G
    __shared__ u16 XT[128 * 128];     // X^T [p][s], resident
    __shared__ u16 Btok[128 * 128];   // B [s][n]
    __shared__ u16 Ctok[128 * 128];   // C [t][n]
    __shared__ float sS[128], sdt[128];
    __shared__ float scw[3][128][4];
    __shared__ float scb[3][128];
    const int c = blockIdx.x, h = blockIdx.y, b = blockIdx.z;
    const int tid = threadIdx.x, wid = tid >> 6, lane = tid & 63;
    const int quad = lane >> 4, cl = lane & 15;
    const int tok0 = b * LSEQ + c * 128;
    const size_t blk = ((size_t)((b * 2 + h) * 32 + c)) << 14;
    // conv weights: 0=x(head h), 1=B, 2=C
    for (int idx = tid; idx < 384; idx += 512) {
        int grp = idx >> 7, j = idx & 127;
        int ch = (grp == 0) ? (128 * h + j) : (grp == 1 ? 256 + j : 384 + j);
        float4 w4 = *(const float4*)&cw[ch * 4];
        scw[grp][j][0] = w4.x; scw[grp][j][1] = w4.y;
        scw[grp][j][2] = w4.z; scw[grp][j][3] = w4.w;
        scb[grp][j] = cb[ch];
    }
    if (tid < 128) {
        sS[tid] = Sb[(size_t)(tok0 + tid) * 2 + h];
        sdt[tid] = dtb[(size_t)(tok0 + tid) * 2 + h];
    }
    // ---- conv X -> XT
    #pragma unroll
    for (int i = 0; i < 5; i++) {
        int ck = i * 512 + tid;
        int r = ck >> 4; if (r > 130) r = 130;
        int cc = ck & 15;
        int tok = tok0 - 3 + r; if (tok < 0) tok = 0;
        async_lds16(zx16 + (size_t)tok * 768 + 256 + 128 * h + ((cc ^ (r & 15)) << 3),
                    (void*)(raw + (i * 512 + (tid & ~63)) * 8));
    }
    __syncthreads();
    if (c == 0 && tid < 48) *(uint4*)&raw[tid * 8] = make_uint4(0, 0, 0, 0);
    __syncthreads();
    #pragma unroll
    for (int it = 0; it < 4; it++) {
        int idx = it * 512 + tid;
        int s = idx & 127, pg = idx >> 7;
        f16x8 v[4];
        #pragma unroll
        for (int k = 0; k < 4; k++) {
            int rr = s + k;
            v[k] = *(const f16x8*)&raw[rr * 128 + ((pg ^ (rr & 15)) << 3)];
        }
        #pragma unroll
        for (int j = 0; j < 8; j++) {
            int p = pg * 8 + j;
            float o = scb[0][p] + (float)v[0][j] * scw[0][p][0]
                    + (float)v[1][j] * scw[0][p][1]
                    + (float)v[2][j] * scw[0][p][2]
                    + (float)v[3][j] * scw[0][p][3];
            XT[p * 128 + (((s >> 3) ^ (p & 15)) << 3) + (s & 7)] = f2h(silu_f(o));
        }
    }
    __syncthreads();
    // ---- conv B -> Btok (token-major)
    #pragma unroll
    for (int i = 0; i < 5; i++) {
        int ck = i * 512 + tid;
        int r = ck >> 4; if (r > 130) r = 130;
        int cc = ck & 15;
        int tok = tok0 - 3 + r; if (tok < 0) tok = 0;
        async_lds16(zx16 + (size_t)tok * 768 + 512 + ((cc ^ (r & 15)) << 3),
                    (void*)(raw + (i * 512 + (tid & ~63)) * 8));
    }
    __syncthreads();
    if (c == 0 && tid < 48) *(uint4*)&raw[tid * 8] = make_uint4(0, 0, 0, 0);
    __syncthreads();
    #pragma unroll
    for (int it = 0; it < 4; it++) {
        int idx = it * 512 + tid;
        int t = idx & 127, ng = idx >> 7;
        f16x8 v[4];
        #pragma unroll
        for (int k = 0; k < 4; k++) {
            int rr = t + k;
            v[k] = *(const f16x8*)&raw[rr * 128 + ((ng ^ (rr & 15)) << 3)];
        }
        union { u16 u[8]; uint4 q; } pk;
        #pragma unroll
        for (int j = 0; j < 8; j++) {
            int n = ng * 8 + j;
            float o = scb[1][n] + (float)v[0][j] * scw[1][n][0]
                    + (float)v[1][j] * scw[1][n][1]
                    + (float)v[2][j] * scw[1][n][2]
                    + (float)v[3][j] * scw[1][n][3];
            pk.u[j] = f2h(silu_f(o));
        }
        *(uint4*)&Btok[t * 128 + ((ng ^ (t & 15)) << 3)] = pk.q;
    }
    __syncthreads();
    // ---- conv C -> Ctok (token-major)
    #pragma unroll
    for (int i = 0; i < 5; i++) {
        int ck = i * 512 + tid;
        int r = ck >> 4; if (r > 130) r = 130;
        int cc = ck & 15;
        int tok = tok0 - 3 + r; if (tok < 0) tok = 0;
        async_lds16(zx16 + (size_t)tok * 768 + 640 + ((cc ^ (r & 15)) << 3),
                    (void*)(raw + (i * 512 + (tid & ~63)) * 8));
    }
    __syncthreads();
    if (c == 0 && tid < 48) *(uint4*)&raw[tid * 8] = make_uint4(0, 0, 0, 0);
    __syncthreads();
    #pragma unroll
    for (int it = 0; it < 4; it++) {
        int idx = it * 512 + tid;
        int t = idx & 127, ng = idx >> 7;
        f16x8 v[4];
        #pragma unroll
        for (int k = 0; k < 4; k++) {
            int rr = t + k;
            v[k] = *(const f16x8*)&raw[rr * 128 + ((ng ^ (rr & 15)) << 3)];
        }
        union { u16 u[8]; uint4 q; } pk;
        #pragma unroll
        for (int j = 0; j < 8; j++) {
            int n = ng * 8 + j;
            float o = scb[2][n] + (float)v[0][j] * scw[2][n][0]
                    + (float)v[1][j] * scw[2][n][1]
                    + (float)v[2][j] * scw[2][n][2]
                    + (float)v[3][j] * scw[2][n][3];
            pk.u[j] = f2h(silu_f(o));
        }
        *(uint4*)&Ctok[t * 128 + ((ng ^ (t & 15)) << 3)] = pk.q;
    }
    __syncthreads();   // raw free -> stage Hin
    #pragma unroll
    for (int i = 0; i < 4; i++) {
        int ck = i * 512 + tid;
        int r = ck >> 4, cc = ck & 15;
        async_lds16(Hbf + blk + (size_t)r * 128 + ((cc ^ (r & 15)) << 3),
                    (void*)(raw + (i * 512 + (tid & ~63)) * 8));
    }
    __syncthreads();
    // ---- phase 1: Y = C @ Hin^T ; scale by exp(S_t)
    const int wm = (wid >> 1) * 32, wn = (wid & 1) * 64;
    f32x4 acc[2][4];
    #pragma unroll
    for (int i = 0; i < 2; i++)
        #pragma unroll
        for (int j = 0; j < 4; j++) acc[i][j] = f32x4{0.f, 0.f, 0.f, 0.f};
    #pragma unroll
    for (int ks = 0; ks < 4; ks++) {
        f16x8 ca[2], hb[4];
        int kc = ks * 4 + quad;
        #pragma unroll
        for (int i = 0; i < 2; i++) {
            int r = wm + i * 16 + cl;
            ca[i] = *(const f16x8*)&Ctok[r * 128 + ((kc ^ (r & 15)) << 3)];
        }
        #pragma unroll
        for (int j = 0; j < 4; j++) {
            int r = wn + j * 16 + cl;
            hb[j] = *(const f16x8*)&raw[r * 128 + ((kc ^ (r & 15)) << 3)];
        }
        #pragma unroll
        for (int i = 0; i < 2; i++)
            #pragma unroll
            for (int j = 0; j < 4; j++)
                acc[i][j] = __builtin_amdgcn_mfma_f32_16x16x32_f16(
                    ca[i], hb[j], acc[i][j], 0, 0, 0);
    }
    #pragma unroll
    for (int i = 0; i < 2; i++)
        #pragma unroll
        for (int r = 0; r < 4; r++) {
            float e = __expf(sS[wm + i * 16 + quad * 4 + r]);
            #pragma unroll
            for (int j = 0; j < 4; j++) acc[i][j][r] *= e;
        }
    // ---- phase 2: S = C @ B^T (triangular skip)
    f32x4 sacc[2][4];
    #pragma unroll
    for (int i = 0; i < 2; i++)
        #pragma unroll
        for (int j = 0; j < 4; j++) sacc[i][j] = f32x4{0.f, 0.f, 0.f, 0.f};
    #pragma unroll
    for (int ks = 0; ks < 4; ks++) {
        f16x8 cs[2], bs[4];
        int kc = ks * 4 + quad;
        #pragma unroll
        for (int i2 = 0; i2 < 2; i2++) {
            int r = wm + i2 * 16 + cl;
            cs[i2] = *(const f16x8*)&Ctok[r * 128 + ((kc ^ (r & 15)) << 3)];
        }
        #pragma unroll
        for (int j = 0; j < 4; j++) {
            int r = wn + j * 16 + cl;
            bs[j] = *(const f16x8*)&Btok[r * 128 + ((kc ^ (r & 15)) << 3)];
        }
        #pragma unroll
        for (int i2 = 0; i2 < 2; i2++)
            #pragma unroll
            for (int j = 0; j < 4; j++)
                if (wm + i2 * 16 + 15 >= wn + j * 16)
                    sacc[i2][j] = __builtin_amdgcn_mfma_f32_16x16x32_f16(
                        cs[i2], bs[j], sacc[i2][j], 0, 0, 0);
    }
    __syncthreads();   // all reads of raw(Hin) done
    // ---- G = mask ∘ S ∘ exp(St-Ss) ∘ dt_s  -> raw (over Hin)
    #pragma unroll
    for (int i2 = 0; i2 < 2; i2++)
        #pragma unroll
        for (int r = 0; r < 4; r++) {
            int t = wm + i2 * 16 + quad * 4 + r;
            float Stv = sS[t];
            #pragma unroll
            for (int j = 0; j < 4; j++) {
                int s = wn + j * 16 + cl;
                float gv = 0.f;
                if (s <= t) gv = sacc[i2][j][r] * __expf(Stv - sS[s]) * sdt[s];
                raw[t * 128 + (((s >> 3) ^ (t & 15)) << 3) + (s & 7)] = f2h(gv);
            }
        }
    __syncthreads();
    // ---- phase 3: Y += G @ X
    #pragma unroll
    for (int ks = 0; ks < 4; ks++) {
        f16x8 ga[2], xb[4];
        int kc = ks * 4 + quad;
        #pragma unroll
        for (int i = 0; i < 2; i++) {
            int r = wm + i * 16 + cl;
            ga[i] = *(const f16x8*)&raw[r * 128 + ((kc ^ (r & 15)) << 3)];
        }
        #pragma unroll
        for (int j = 0; j < 4; j++) {
            int r = wn + j * 16 + cl;
            xb[j] = *(const f16x8*)&XT[r * 128 + ((kc ^ (r & 15)) << 3)];
        }
        #pragma unroll
        for (int i = 0; i < 2; i++)
            #pragma unroll
            for (int j = 0; j < 4; j++)
                acc[i][j] = __builtin_amdgcn_mfma_f32_16x16x32_f16(
                    ga[i], xb[j], acc[i][j], 0, 0, 0);
    }
    // ---- epilogue: g = (Y + D*x)*silu(z)  (raw, no rms)
    const float dco = Dp[h];
    #pragma unroll
    for (int i = 0; i < 2; i++)
        #pragma unroll
        for (int r = 0; r < 4; r++) {
            int t = wm + i * 16 + quad * 4 + r;
            u16* row = g16 + (size_t)(tok0 + t) * 256 + h * 128;
            #pragma unroll
            for (int j = 0; j < 4; j++) {
                int p = wn + j * 16 + cl;
                float xv = h2f(XT[p * 128 + (((t >> 3) ^ (p & 15)) << 3) + (t & 7)]);
                float zv = h2f(zx16[(size_t)(tok0 + t) * 768 + h * 128 + p]);
                row[p] = f2h((acc[i][j][r] + dco * xv) * silu_f(zv));
            }
        }
}

// ---------------------------------------------------------------------------
// out-proj GEMM (K=256, N=128, BM=64) with: rstd prologue over raw g,
// gnw folded into W cvt, rstd applied to GEMM term; + residual + RMS.
// mode 1: v=rstd_g*acc+hbuf; hbuf=v; hn16 = fp16(rms(v)*rmsw)
// mode 3: v=rstd_g*acc+hbuf; val = xp + rms(v)*rmsw; fused final projection.
// ---------------------------------------------------------------------------
__global__ __launch_bounds__(256) void gemm_outrms_kernel(
    const u16* __restrict__ A, const float* __restrict__ Wf,
    const float* __restrict__ gnw, const float* __restrict__ rmsw,
    u16* __restrict__ xp16, u16* __restrict__ hbuf16, u16* __restrict__ hn16,
    const float* __restrict__ out_wf, const float* __restrict__ out_b,
    float* __restrict__ dout, int mode)
{
    __shared__ u16 sA[64 * 64];
    __shared__ u16 sW[128 * 64];
    __shared__ float red[64][33];
    __shared__ float srstd[64];
    __shared__ float redp[64][5];
    __shared__ float rstdg[64];
    __shared__ u16 hn2[64 * 128];
    __shared__ u16 ow[64 * 128];
    const int K = 256;
    const int m0 = blockIdx.y * 64;
    const int tid = threadIdx.x, wid = tid >> 6, lane = tid & 63;
    const int wm = (wid >> 1) * 32, wn = (wid & 1) * 64;
    const int quad = lane >> 4, cl = lane & 15;
    // ---- prologue: rstd_g[t] from raw gated values
    {
        int t = tid >> 2, q = tid & 3;
        const u16* row = A + (size_t)(m0 + t) * 256 + q * 64;
        float ss = 0.f;
        #pragma unroll
        for (int u = 0; u < 8; u++) {
            f16x8 v = *(const f16x8*)&row[u * 8];
            #pragma unroll
            for (int j = 0; j < 8; j++) { float f = (float)v[j]; ss += f * f; }
        }
        redp[t][q] = ss;
    }
    __syncthreads();
    if (tid < 64)
        rstdg[tid] = rsqrtf((redp[tid][0] + redp[tid][1] + redp[tid][2]
                             + redp[tid][3]) * (1.f / 256.f) + 1e-5f);
    f32x4 acc[2][4];
    #pragma unroll
    for (int i = 0; i < 2; i++)
        #pragma unroll
        for (int j = 0; j < 4; j++) acc[i][j] = f32x4{0.f, 0.f, 0.f, 0.f};

    for (int k0 = 0; k0 < K; k0 += 64) {
        #pragma unroll
        for (int i = 0; i < 2; i++) {
            int ck = i * 256 + tid;
            int r = ck >> 3, cc = ck & 7;
            int csw = (cc ^ (r & 7)) << 3;
            async_lds16(A + (size_t)(m0 + r) * K + k0 + csw,
                        (void*)(sA + (i * 256 + (tid & ~63)) * 8));
        }
        #pragma unroll
        for (int i = 0; i < 4; i++) {
            int ck = i * 256 + tid;
            int r = ck >> 3, cc = ck & 7;
            int csw = (cc ^ (r & 7)) << 3;
            *(uint4*)&sW[ck * 8] = cvt8g(Wf + (size_t)r * K + k0 + csw,
                                         gnw + k0 + csw);
        }
        __syncthreads();
        #pragma unroll
        for (int ks = 0; ks < 2; ks++) {
            f16x8 af[2], wv[4];
            int kc = ks * 4 + quad;
            #pragma unroll
            for (int i = 0; i < 2; i++) {
                int r = wm + i * 16 + cl;
                af[i] = *(const f16x8*)&sA[r * 64 + ((kc ^ (r & 7)) << 3)];
            }
            #pragma unroll
            for (int j = 0; j < 4; j++) {
                int r = wn + j * 16 + cl;
                wv[j] = *(const f16x8*)&sW[r * 64 + ((kc ^ (r & 7)) << 3)];
            }
            #pragma unroll
            for (int i = 0; i < 2; i++)
                #pragma unroll
                for (int j = 0; j < 4; j++)
                    acc[i][j] = __builtin_amdgcn_mfma_f32_16x16x32_f16(
                        af[i], wv[j], acc[i][j], 0, 0, 0);
        }
        __syncthreads();
    }
    const int slot = (wid & 1) * 16 + cl;
    #pragma unroll
    for (int i = 0; i < 2; i++)
        #pragma unroll
        for (int r = 0; r < 4; r++) {
            int t = wm + i * 16 + quad * 4 + r;
            size_t ob = (size_t)(m0 + t) * 128;
            float rg = rstdg[t];
            float ssp = 0.f;
            #pragma unroll
            for (int j = 0; j < 4; j++) {
                int n = wn + j * 16 + cl;
                float v = acc[i][j][r] * rg + h2f(hbuf16[ob + n]);
                acc[i][j][r] = v;
                ssp += v * v;
            }
            red[t][slot] = ssp;
        }
    __syncthreads();
    if (tid < 64) {
        float s = 0.f;
        #pragma unroll
        for (int sl = 0; sl < 32; sl++) s += red[tid][sl];
        srstd[tid] = rsqrtf(s * (1.f / 128.f) + 1e-5f);
    }
    __syncthreads();
    #pragma unroll
    for (int i = 0; i < 2; i++)
        #pragma unroll
        for (int r = 0; r < 4; r++) {
            int t = wm + i * 16 + quad * 4 + r;
            size_t ob = (size_t)(m0 + t) * 128;
            float rstd = srstd[t];
            #pragma unroll
            for (int j = 0; j < 4; j++) {
                int n = wn + j * 16 + cl;
                float v = acc[i][j][r];
                float val = v * rstd * rmsw[n];
                if (mode == 1) {
                    hbuf16[ob + n] = f2h(v);
                    hn16[ob + n] = f2h(val);
                } else {
                    val += h2f(xp16[ob + n]);
                    hn2[t * 128 + (((n >> 3) ^ (t & 15)) << 3) + (n & 7)] = f2h(val);
                }
            }
        }
    if (mode == 1) return;
    // ---- fused final projection
    #pragma unroll
    for (int i = 0; i < 4; i++) {
        int ck = i * 256 + tid;
        int rr = ck >> 4, cc = ck & 15;
        int csw = (cc ^ (rr & 15)) << 3;
        *(uint4*)&ow[ck * 8] = cvt8(out_wf + (size_t)rr * 128 + csw);
    }
    __syncthreads();
    const int wm4 = (wid >> 1) * 32, wn4 = (wid & 1) * 32;
    f32x4 acc2[2][2];
    #pragma unroll
    for (int i = 0; i < 2; i++)
        #pragma unroll
        for (int j = 0; j < 2; j++) acc2[i][j] = f32x4{0.f, 0.f, 0.f, 0.f};
    #pragma unroll
    for (int ks = 0; ks < 4; ks++) {
        f16x8 af2[2], wf2[2];
        int kc = ks * 4 + quad;
        #pragma unroll
        for (int i = 0; i < 2; i++) {
            int r = wm4 + i * 16 + cl;
            af2[i] = *(const f16x8*)&hn2[r * 128 + ((kc ^ (r & 15)) << 3)];
        }
        #pragma unroll
        for (int j = 0; j < 2; j++) {
            int rr = wn4 + j * 16 + cl;
            wf2[j] = *(const f16x8*)&ow[rr * 128 + ((kc ^ (rr & 15)) << 3)];
        }
        #pragma unroll
        for (int i = 0; i < 2; i++)
            #pragma unroll
            for (int j = 0; j < 2; j++)
                acc2[i][j] = __builtin_amdgcn_mfma_f32_16x16x32_f16(
                    af2[i], wf2[j], acc2[i][j], 0, 0, 0);
    }
    #pragma unroll
    for (int i = 0; i < 2; i++) {
        int m = m0 + wm4 + i * 16 + quad * 4;
        #pragma unroll
        for (int j = 0; j < 2; j++) {
            int n = wn4 + j * 16 + cl;
            float bv = out_b[n];
            #pragma unroll
            for (int r = 0; r < 4; r++)
                dout[(size_t)(m + r) * 64 + n] = acc2[i][j][r] + bv;
        }
    }
}

// ---------------------------------------------------------------------------
extern "C" void kernel_launch(void* const* d_in, const int* in_sizes, int n_in,
                              void* d_out, int out_size, void* d_ws, size_t ws_size,
                              hipStream_t stream)
{
    (void)in_sizes; (void)n_in; (void)out_size; (void)ws_size;
    const float* x       = (const float*)d_in[0];
    const float* in_w    = (const float*)d_in[1];
    const float* in_b    = (const float*)d_in[2];
    const float* out_w   = (const float*)d_in[3];
    const float* out_b   = (const float*)d_in[4];
    const float* l_rms_w = (const float*)d_in[5];
    const float* l_in_w  = (const float*)d_in[6];
    const float* conv_w  = (const float*)d_in[7];
    const float* conv_b  = (const float*)d_in[8];
    const float* dt_bias = (const float*)d_in[9];
    const float* A_log   = (const float*)d_in[10];
    const float* D_p     = (const float*)d_in[11];
    const float* gnorm_w = (const float*)d_in[12];
    const float* l_out_w = (const float*)d_in[13];
    const float* fnorm_w = (const float*)d_in[14];

    char* w = (char*)d_ws;
    u16*   xp16   = (u16*)(w);                  // 4.19 MB
    u16*   hbuf16 = (u16*)(w + 4194304);        // 4.19 MB
    u16*   hn16   = (u16*)(w + 8388608);        // 4.19 MB
    u16*   zx16   = (u16*)(w + 12582912);       // 25.17 MB
    float* dtb    = (float*)(w + 37748736);     // 131 KB
    float* Sb     = (float*)(w + 37879808);     // 131 KB
    u16*   Hb     = (u16*)(w + 38010880);       // 8.39 MB
    u16*   Hbf    = (u16*)(w + 46399488);       // 8.39 MB
    u16*   g16    = (u16*)(w + 54788096);       // 8.39 MB (raw gated, 16384x256)

    gemm_rms0_kernel<<<dim3(1, 256), 256, 0, stream>>>(
        x, in_w, in_b, l_rms_w, xp16, hbuf16, hn16);

    for (int i = 0; i < 2; i++) {
        gemm_inproj_kernel<<<dim3(7, 128), 256, 0, stream>>>(
            hn16, l_in_w + (size_t)i * 770 * 128, zx16, dtb, Sb,
            dt_bias + i * 2, A_log + i * 2);
        chunkstate_conv_kernel<<<dim3(32, 2, 4), 512, 0, stream>>>(
            zx16, conv_w + i * 2048, conv_b + i * 512, dtb, Sb, Hb);
        statecombine_kernel<<<dim3(64, 2, 4), 256, 0, stream>>>(Sb, Hb, Hbf);
        ssd_ph_kernel<<<dim3(32, 2, 4), 512, 0, stream>>>(
            zx16, Hbf, dtb, Sb, conv_w + i * 2048, conv_b + i * 512,
            D_p + i * 2, g16);
        gemm_outrms_kernel<<<dim3(1, 256), 256, 0, stream>>>(
            g16, l_out_w + (size_t)i * 128 * 256, gnorm_w + i * 256,
            (i == 0) ? (l_rms_w + 128) : fnorm_w, xp16, hbuf16, hn16,
            out_w, out_b, (float*)d_out, (i == 0) ? 1 : 3);
    }
}